// Round 2
// baseline (638.046 us; speedup 1.0000x reference)
//
#include <hip/hip_runtime.h>
#include <hip/hip_bf16.h>

#define Bc   4
#define Cc   32
#define Hc   192
#define Wc   192
#define HWc  (Hc * Wc)          // 36864
#define NPIX (Bc * HWc)         // 147456

// ---- workspace layout ----
// float region (weights, transposed) at offset 0:
#define OFF_W1T   0            // [64][32]       2048
#define OFF_B1    2048         // 32
#define OFF_W2AT  2080         // [288][32]      9216
#define OFF_B2A   11296        // 32
#define OFF_W2BT  11328        // 9216
#define OFF_B2B   20544        // 32
#define OFF_WOFFT 20576        // [288][216]     62208
#define OFF_BOFF  82784        // 216
#define OFF_WDT   83000        // [288][32]      9216
#define OFF_BD    92216        // 32
#define WS_WEIGHT_FLOATS 92248
// bf16 region after the weights:
//   t0 [4][32][HW] bf16, t1 [4][32][HW] bf16, co [4][216][HW] bf16

typedef __hip_bfloat16 bf16;

__device__ __forceinline__ float tof(bf16 v) { return __bfloat162float(v); }

// ---------------- weight prep: f32 OIK -> f32 [ik][o] ----------------
__global__ __launch_bounds__(256) void prep_k(
    const float* __restrict__ w1,  const float* __restrict__ b1,
    const float* __restrict__ w2a, const float* __restrict__ b2a,
    const float* __restrict__ w2b, const float* __restrict__ b2b,
    const float* __restrict__ wo,  const float* __restrict__ bo,
    const float* __restrict__ wd,  const float* __restrict__ bd,
    float* __restrict__ ws)
{
    int i = blockIdx.x * 256 + threadIdx.x;
    auto scat = [&](const float* src, float* dst, int local, int Cout, int CinK) {
        int o = local / CinK;
        int ik = local - o * CinK;
        dst[ik * Cout + o] = src[local];
    };
    if      (i < 2048)  scat(w1,  ws + OFF_W1T,   i,         32, 64);
    else if (i < 2080)  scat(b1,  ws + OFF_B1,    i - 2048,  32, 1);
    else if (i < 11296) scat(w2a, ws + OFF_W2AT,  i - 2080,  32, 288);
    else if (i < 11328) scat(b2a, ws + OFF_B2A,   i - 11296, 32, 1);
    else if (i < 20544) scat(w2b, ws + OFF_W2BT,  i - 11328, 32, 288);
    else if (i < 20576) scat(b2b, ws + OFF_B2B,   i - 20544, 32, 1);
    else if (i < 82784) scat(wo,  ws + OFF_WOFFT, i - 20576, 216, 288);
    else if (i < 83000) scat(bo,  ws + OFF_BOFF,  i - 82784, 216, 1);
    else if (i < 92216) scat(wd,  ws + OFF_WDT,   i - 83000, 32, 288);
    else if (i < 92248) scat(bd,  ws + OFF_BD,    i - 92216, 32, 1);
}

// ---------------- 1x1 conv: cat(img_ref, img) [64ch f32] -> t0 [32ch bf16] ----------------
__global__ __launch_bounds__(256) void conv1x1_k(
    const float* __restrict__ a,   // img_ref [4][32][HW]
    const float* __restrict__ b,   // img     [4][32][HW]
    const float* __restrict__ wT,  // [64][32]
    const float* __restrict__ bias,
    bf16* __restrict__ y)          // [4][32][HW]
{
    int pix = blockIdx.x * 256 + threadIdx.x;
    if (pix >= NPIX) return;
    int bb = pix / HWc;
    int hw = pix - bb * HWc;

    float acc[32];
#pragma unroll
    for (int o = 0; o < 32; ++o) acc[o] = bias[o];

    const float* pa = a + (size_t)bb * Cc * HWc + hw;
    const float* pb = b + (size_t)bb * Cc * HWc + hw;
    for (int c = 0; c < 64; ++c) {
        float v = (c < 32) ? pa[c * HWc] : pb[(c - 32) * HWc];
        const float* wr = wT + c * 32;
#pragma unroll
        for (int o = 0; o < 32; ++o) acc[o] = fmaf(v, wr[o], acc[o]);
    }
    bf16* yp = y + (size_t)bb * Cc * HWc + hw;
#pragma unroll
    for (int o = 0; o < 32; ++o) yp[(size_t)o * HWc] = __float2bfloat16(acc[o]);
}

// ---------------- generic 3x3 conv, pad 1, CIN=32, bf16 in, OC_TILE out-ch per block ----------------
template <int OC_TILE, bool SIGMOID_TAIL>
__global__ __launch_bounds__(256) void conv3x3_k(
    const bf16* __restrict__ x,    // [4][32][HW]
    const float* __restrict__ wT,  // [(c*9+t)][COUT]
    const float* __restrict__ bias,
    bf16* __restrict__ y,          // [4][COUT][HW]
    int COUT)
{
    int pix = blockIdx.x * 256 + threadIdx.x;
    int oc0 = blockIdx.y * OC_TILE;
    if (pix >= NPIX) return;
    int bb = pix / HWc;
    int hw = pix - bb * HWc;
    int hh = hw / Wc;
    int wwp = hw - hh * Wc;

    float acc[OC_TILE];
#pragma unroll
    for (int o = 0; o < OC_TILE; ++o) acc[o] = bias[oc0 + o];

    bool hv0 = hh > 0, hv2 = hh < Hc - 1, wv0 = wwp > 0, wv2 = wwp < Wc - 1;
    const bf16* xb = x + (size_t)bb * Cc * HWc + hw;

    for (int c = 0; c < Cc; ++c) {
        const bf16* xc = xb + (size_t)c * HWc;
        float v[9];
        v[0] = (hv0 && wv0) ? tof(xc[-Wc - 1]) : 0.f;
        v[1] = hv0          ? tof(xc[-Wc])     : 0.f;
        v[2] = (hv0 && wv2) ? tof(xc[-Wc + 1]) : 0.f;
        v[3] = wv0          ? tof(xc[-1])      : 0.f;
        v[4] =                tof(xc[0]);
        v[5] = wv2          ? tof(xc[1])       : 0.f;
        v[6] = (hv2 && wv0) ? tof(xc[Wc - 1])  : 0.f;
        v[7] = hv2          ? tof(xc[Wc])      : 0.f;
        v[8] = (hv2 && wv2) ? tof(xc[Wc + 1])  : 0.f;
        const float* wrow = wT + (size_t)(c * 9) * COUT + oc0;
#pragma unroll
        for (int t = 0; t < 9; ++t) {
#pragma unroll
            for (int o = 0; o < OC_TILE; ++o)
                acc[o] = fmaf(v[t], wrow[t * COUT + o], acc[o]);
        }
    }

    size_t ybase = (size_t)bb * COUT * HWc + (size_t)oc0 * HWc + hw;
#pragma unroll
    for (int o = 0; o < OC_TILE; ++o) {
        float r = acc[o];
        if (SIGMOID_TAIL && (oc0 + o) >= 144) r = 1.f / (1.f + expf(-r));
        y[ybase + (size_t)o * HWc] = __float2bfloat16(r);
    }
}

// ---------------- modulated deformable conv (DCNv2), 3x3, DG=8, Cg=4 ----------------
__global__ __launch_bounds__(256) void dcn_k(
    const float* __restrict__ img, // [4][32][HW] f32
    const bf16* __restrict__ co,   // [4][216][HW]: [0:72)=dy, [72:144)=dx, [144:216)=mask(sigmoided)
    const float* __restrict__ wT,  // [(ch*9+k)][32]
    const float* __restrict__ bias,
    float* __restrict__ out)       // [4][32][HW] f32
{
    int pix = blockIdx.x * 256 + threadIdx.x;
    if (pix >= NPIX) return;
    int bb = pix / HWc;
    int hw = pix - bb * HWc;
    int hh = hw / Wc;
    int wwp = hw - hh * Wc;

    float acc[32];
#pragma unroll
    for (int o = 0; o < 32; ++o) acc[o] = 0.f;

    const float* xb = img + (size_t)bb * Cc * HWc;
    const bf16* cob = co + (size_t)bb * 216 * HWc + hw;

    for (int dg = 0; dg < 8; ++dg) {
        for (int kyi = 0; kyi < 3; ++kyi) {
            for (int kxi = 0; kxi < 3; ++kxi) {
                int k = kyi * 3 + kxi;
                int offch = dg * 9 + k;
                float dy = tof(cob[(size_t)offch * HWc]);
                float dx = tof(cob[(size_t)(72 + offch) * HWc]);
                float m  = tof(cob[(size_t)(144 + offch) * HWc]);

                float py = dy + (float)(hh + kyi - 1);
                float px = dx + (float)(wwp + kxi - 1);
                float y0f = floorf(py), x0f = floorf(px);
                float wy = py - y0f, wx = px - x0f;
                int y0 = (int)y0f, x0 = (int)x0f;
                int y1 = y0 + 1, x1 = x0 + 1;

                bool vy0 = (y0 >= 0) && (y0 < Hc);
                bool vy1 = (y1 >= 0) && (y1 < Hc);
                bool vx0 = (x0 >= 0) && (x0 < Wc);
                bool vx1 = (x1 >= 0) && (x1 < Wc);

                int y0c = min(max(y0, 0), Hc - 1);
                int y1c = min(max(y1, 0), Hc - 1);
                int x0c = min(max(x0, 0), Wc - 1);
                int x1c = min(max(x1, 0), Wc - 1);

                float w00 = (1.f - wy) * (1.f - wx);
                float w01 = (1.f - wy) * wx;
                float w10 = wy * (1.f - wx);
                float w11 = wy * wx;
                if (!(vy0 && vx0)) w00 = 0.f;
                if (!(vy0 && vx1)) w01 = 0.f;
                if (!(vy1 && vx0)) w10 = 0.f;
                if (!(vy1 && vx1)) w11 = 0.f;

                int i00 = y0c * Wc + x0c;
                int i01 = y0c * Wc + x1c;
                int i10 = y1c * Wc + x0c;
                int i11 = y1c * Wc + x1c;

                const float* xg = xb + (size_t)dg * 4 * HWc;
#pragma unroll
                for (int cg = 0; cg < 4; ++cg) {
                    const float* xc = xg + (size_t)cg * HWc;
                    float s = w00 * xc[i00] + w01 * xc[i01]
                            + w10 * xc[i10] + w11 * xc[i11];
                    s *= m;
                    int ch = dg * 4 + cg;
                    const float* wr = wT + (size_t)(ch * 9 + k) * 32;
#pragma unroll
                    for (int o = 0; o < 32; ++o) acc[o] = fmaf(s, wr[o], acc[o]);
                }
            }
        }
    }

    float* op = out + (size_t)bb * Cc * HWc + hw;
#pragma unroll
    for (int o = 0; o < 32; ++o)
        op[(size_t)o * HWc] = acc[o] + bias[o];
}

extern "C" void kernel_launch(void* const* d_in, const int* in_sizes, int n_in,
                              void* d_out, int out_size, void* d_ws, size_t ws_size,
                              hipStream_t stream) {
    const float* img_ref  = (const float*)d_in[0];
    const float* img      = (const float*)d_in[1];
    const float* conv1_w  = (const float*)d_in[2];
    const float* conv1_b  = (const float*)d_in[3];
    const float* conv2a_w = (const float*)d_in[4];
    const float* conv2a_b = (const float*)d_in[5];
    const float* conv2b_w = (const float*)d_in[6];
    const float* conv2b_b = (const float*)d_in[7];
    const float* off_w    = (const float*)d_in[8];
    const float* off_b    = (const float*)d_in[9];
    const float* dcn_w    = (const float*)d_in[10];
    const float* dcn_b    = (const float*)d_in[11];

    float* ws = (float*)d_ws;
    bf16* t0 = (bf16*)((char*)d_ws + (size_t)WS_WEIGHT_FLOATS * 4);
    bf16* t1 = t0 + (size_t)NPIX * Cc;
    bf16* co = t1 + (size_t)NPIX * Cc;
    float* out = (float*)d_out;

    prep_k<<<361, 256, 0, stream>>>(conv1_w, conv1_b, conv2a_w, conv2a_b,
                                    conv2b_w, conv2b_b, off_w, off_b,
                                    dcn_w, dcn_b, ws);

    conv1x1_k<<<576, 256, 0, stream>>>(img_ref, img, ws + OFF_W1T, ws + OFF_B1, t0);

    conv3x3_k<32, false><<<dim3(576, 1), 256, 0, stream>>>(
        t0, ws + OFF_W2AT, ws + OFF_B2A, t1, 32);

    conv3x3_k<32, false><<<dim3(576, 1), 256, 0, stream>>>(
        t1, ws + OFF_W2BT, ws + OFF_B2B, t0, 32);

    conv3x3_k<24, true><<<dim3(576, 9), 256, 0, stream>>>(
        t0, ws + OFF_WOFFT, ws + OFF_BOFF, co, 216);

    dcn_k<<<576, 256, 0, stream>>>(img, co, ws + OFF_WDT, ws + OFF_BD, out);
}

// Round 4
// 264.353 us; speedup vs baseline: 2.4136x; 2.4136x over previous
//
#include <hip/hip_runtime.h>

#define Hc   192
#define Wc   192
#define HWc  (Hc * Wc)          // 36864
#define NPIX (4 * HWc)          // 147456

typedef float f32x4 __attribute__((ext_vector_type(4)));
typedef __bf16 bf16x8 __attribute__((ext_vector_type(8)));
typedef unsigned short u16;
typedef unsigned int u32;

// ---- workspace layout ----
// f32 region (element offsets):
#define WF_BO    0      // 224 (offset-conv bias, padded 216->224)
#define WF_B1    224
#define WF_B2A   256
#define WF_B2B   288
#define WF_BD    320
#define WF_WDT   352    // 9216: dcn weights [(ci*9+k)][32]
#define WF_END   9568
// bf16 fragment region (u16 offsets from byte 38272):
#define FR1_U    0      // conv1   [2][2][64][8]   2048
#define FRA_U    2048   // conv2a  [9][2][64][8]   9216
#define FRB_U    11264  // conv2b  [9][2][64][8]   9216
#define FRO_U    20480  // offset  [9][14][64][8]  64512
#define FRAG_BYTE 38272
// buffers (byte offsets):
#define T0_BYTE  208384                       // [NPIX][32] bf16 ch-last
#define T1_BYTE  (T0_BYTE + NPIX * 32 * 2)
#define CO_BYTE  (T1_BYTE + NPIX * 32 * 2)    // [4][216][HW] bf16 ch-major

__device__ __forceinline__ u16 f2bf(float f) {
    u32 u = __float_as_uint(f);
    u32 r = u + 0x7fffu + ((u >> 16) & 1u);
    return (u16)(r >> 16);
}
__device__ __forceinline__ float bf2f(u16 v) {
    return __uint_as_float(((u32)v) << 16);
}

// ---------------- prep: biases + dcn weights (f32) + MFMA weight fragments (bf16) ----------------
__global__ __launch_bounds__(256) void prep_k(
    const float* __restrict__ w1,  const float* __restrict__ b1,
    const float* __restrict__ w2a, const float* __restrict__ b2a,
    const float* __restrict__ w2b, const float* __restrict__ b2b,
    const float* __restrict__ wo,  const float* __restrict__ bo,
    const float* __restrict__ wd,  const float* __restrict__ bd,
    float* __restrict__ wsf, u16* __restrict__ frag)
{
    int i = blockIdx.x * 256 + threadIdx.x;
    if (i < 224)      { wsf[WF_BO + i]  = (i < 216) ? bo[i] : 0.f; return; }
    if (i < 256)      { wsf[WF_B1  + i - 224] = b1[i - 224];  return; }
    if (i < 288)      { wsf[WF_B2A + i - 256] = b2a[i - 256]; return; }
    if (i < 320)      { wsf[WF_B2B + i - 288] = b2b[i - 288]; return; }
    if (i < 352)      { wsf[WF_BD  + i - 320] = bd[i - 320];  return; }
    if (i < 9568) {           // dcn weights: [o][ik] -> [ik][o]
        int local = i - 352;
        int o = local / 288, ik = local - o * 288;
        wsf[WF_WDT + ik * 32 + o] = wd[local];
        return;
    }
    int fi = i - 9568;
    if (fi < 2048) {          // conv1 frags: [s][nt][l][j], ci = s*32 + (l>>4)*8 + j
        int s = fi >> 10, nt = (fi >> 9) & 1, l = (fi >> 3) & 63, j = fi & 7;
        int o = nt * 16 + (l & 15);
        int ci = s * 32 + ((l >> 4) << 3) + j;
        frag[FR1_U + fi] = f2bf(w1[o * 64 + ci]);
        return;
    }
    fi -= 2048;
    if (fi < 9216) {          // conv2a frags: tap = s, ci = (l>>4)*8+j
        int s = fi / 1024, r = fi - s * 1024;
        int nt = r >> 9, l = (r >> 3) & 63, j = r & 7;
        int o = nt * 16 + (l & 15);
        int ci = ((l >> 4) << 3) + j;
        frag[FRA_U + fi] = f2bf(w2a[(o * 32 + ci) * 9 + s]);
        return;
    }
    fi -= 9216;
    if (fi < 9216) {          // conv2b frags
        int s = fi / 1024, r = fi - s * 1024;
        int nt = r >> 9, l = (r >> 3) & 63, j = r & 7;
        int o = nt * 16 + (l & 15);
        int ci = ((l >> 4) << 3) + j;
        frag[FRB_U + fi] = f2bf(w2b[(o * 32 + ci) * 9 + s]);
        return;
    }
    fi -= 9216;
    if (fi < 64512) {         // offset-conv frags, COUT padded to 224
        int s = fi / 7168, r = fi - s * 7168;
        int nt = r >> 9, l = (r >> 3) & 63, j = r & 7;
        int o = nt * 16 + (l & 15);
        int ci = ((l >> 4) << 3) + j;
        frag[FRO_U + fi] = f2bf((o < 216) ? wo[(o * 32 + ci) * 9 + s] : 0.f);
        return;
    }
}

// ---------------- implicit-GEMM conv via MFMA ----------------
// MODE 0: 1x1 conv, K=64 from two f32 ch-major sources (s==0 -> s0, s==1 -> s1)
// MODE 1: 3x3 conv pad 1, CIN=32, bf16 ch-last source [NPIX][32]
// Output: CHL ? ch-last bf16 [NPIX][32] : ch-major bf16 [4][COUT][HW]
template <int WM, int WN, int MF, int NF, int COUT, int NTILES, int KS, int MODE, bool SIG, bool CHL>
__global__ __launch_bounds__(256) void conv_mfma_k(
    const void* __restrict__ s0v, const void* __restrict__ s1v,
    const u16* __restrict__ wfrag, const float* __restrict__ bias,
    u16* __restrict__ y)
{
    constexpr int M_BLK = WM * MF * 16;
    constexpr int ITERS = M_BLK / 64;
    const int tid = threadIdx.x, lane = tid & 63, wv = tid >> 6;
    const int wm = wv / WN, wn = wv % WN;
    const int m0 = blockIdx.x * M_BLK;
    const int b = m0 / HWc, hwb = m0 - b * HWc;
    const int rm = wm * MF * 16, cn = wn * NF * 16;

    __shared__ uint4 At4[M_BLK * 4];

    int pxA[ITERS], hA[ITERS], wA[ITERS], kgA[ITERS];
#pragma unroll
    for (int it = 0; it < ITERS; ++it) {
        int st = it * 256 + tid;
        int rowl = ((st >> 6) << 4) | (st & 15);
        kgA[it] = (st >> 4) & 3;
        pxA[it] = rowl;
        int hwp = hwb + rowl;
        hA[it] = hwp / Wc;
        wA[it] = hwp - hA[it] * Wc;
    }

    f32x4 acc[MF][NF];
#pragma unroll
    for (int mf = 0; mf < MF; ++mf)
#pragma unroll
        for (int nf = 0; nf < NF; ++nf)
            acc[mf][nf] = f32x4{0.f, 0.f, 0.f, 0.f};

    const u16* srcB = (const u16*)s0v;
    const float* f0 = (const float*)s0v;
    const float* f1 = (const float*)s1v;

    for (int s = 0; s < KS; ++s) {
        // ---- stage A tile ----
        if (MODE == 1) {
            int dy = s / 3 - 1, dx = s - (s / 3) * 3 - 1;
            int d = dy * Wc + dx;
#pragma unroll
            for (int it = 0; it < ITERS; ++it) {
                bool valid = ((unsigned)(hA[it] + dy) < (unsigned)Hc) &&
                             ((unsigned)(wA[it] + dx) < (unsigned)Wc);
                uint4 v = {0u, 0u, 0u, 0u};
                if (valid)
                    v = *(const uint4*)(srcB + ((size_t)(m0 + pxA[it] + d)) * 32 + kgA[it] * 8);
                At4[it * 256 + tid] = v;
            }
        } else {
            const float* fs = (s == 0) ? f0 : f1;
#pragma unroll
            for (int it = 0; it < ITERS; ++it) {
                const float* pl = fs + ((size_t)b * 32 + kgA[it] * 8) * HWc + (hwb + pxA[it]);
                u32 p0, p1, p2, p3;
                {
                    u32 a0 = f2bf(pl[0 * HWc]), a1 = f2bf(pl[1 * HWc]);
                    u32 a2 = f2bf(pl[2 * HWc]), a3 = f2bf(pl[3 * HWc]);
                    u32 a4 = f2bf(pl[4 * HWc]), a5 = f2bf(pl[5 * HWc]);
                    u32 a6 = f2bf(pl[6 * HWc]), a7 = f2bf(pl[7 * HWc]);
                    p0 = a0 | (a1 << 16); p1 = a2 | (a3 << 16);
                    p2 = a4 | (a5 << 16); p3 = a6 | (a7 << 16);
                }
                uint4 v = {p0, p1, p2, p3};
                At4[it * 256 + tid] = v;
            }
        }
        __syncthreads();

        // ---- fragments + MFMA ----
        bf16x8 aF[MF];
#pragma unroll
        for (int mf = 0; mf < MF; ++mf)
            aF[mf] = __builtin_bit_cast(bf16x8, At4[((rm >> 4) + mf) * 64 + lane]);
#pragma unroll
        for (int nf = 0; nf < NF; ++nf) {
            bf16x8 bF = __builtin_bit_cast(
                bf16x8,
                *(const uint4*)(wfrag + (((size_t)s * NTILES + wn * NF + nf) * 64 + lane) * 8));
#pragma unroll
            for (int mf = 0; mf < MF; ++mf)
                acc[mf][nf] = __builtin_amdgcn_mfma_f32_16x16x32_bf16(aF[mf], bF, acc[mf][nf], 0, 0, 0);
        }
        __syncthreads();
    }

    // ---- epilogue: bias (+sigmoid) + store ----
#pragma unroll
    for (int nf = 0; nf < NF; ++nf) {
        int o = cn + nf * 16 + (lane & 15);
        float bs = bias[o];
#pragma unroll
        for (int mf = 0; mf < MF; ++mf) {
#pragma unroll
            for (int r = 0; r < 4; ++r) {
                int m = m0 + rm + mf * 16 + ((lane >> 4) << 2) + r;
                float val = acc[mf][nf][r] + bs;
                if (SIG && o >= 144) val = 1.f / (1.f + expf(-val));
                if (CHL) {
                    y[(size_t)m * COUT + o] = f2bf(val);
                } else {
                    if (o < COUT)
                        y[((size_t)(b * COUT + o)) * HWc + (m - b * HWc)] = f2bf(val);
                }
            }
        }
    }
}

// ---------------- modulated deformable conv (DCNv2), 3x3, DG=8, Cg=4 ----------------
__global__ __launch_bounds__(256) void dcn_k(
    const float* __restrict__ img, // [4][32][HW] f32
    const u16* __restrict__ co,    // [4][216][HW] bf16: dy | dx | mask
    const float* __restrict__ wT,  // [(ci*9+k)][32]
    const float* __restrict__ bias,
    float* __restrict__ out)       // [4][32][HW] f32
{
    int pix = blockIdx.x * 256 + threadIdx.x;
    if (pix >= NPIX) return;
    int bb = pix / HWc;
    int hw = pix - bb * HWc;
    int hh = hw / Wc;
    int wwp = hw - hh * Wc;

    float acc[32];
#pragma unroll
    for (int o = 0; o < 32; ++o) acc[o] = 0.f;

    const float* xb = img + (size_t)bb * 32 * HWc;
    const u16* cob = co + (size_t)bb * 216 * HWc + hw;

    for (int dg = 0; dg < 8; ++dg) {
        for (int kyi = 0; kyi < 3; ++kyi) {
            for (int kxi = 0; kxi < 3; ++kxi) {
                int k = kyi * 3 + kxi;
                int offch = dg * 9 + k;
                float dy = bf2f(cob[(size_t)offch * HWc]);
                float dx = bf2f(cob[(size_t)(72 + offch) * HWc]);
                float m  = bf2f(cob[(size_t)(144 + offch) * HWc]);

                float py = dy + (float)(hh + kyi - 1);
                float px = dx + (float)(wwp + kxi - 1);
                float y0f = floorf(py), x0f = floorf(px);
                float wy = py - y0f, wx = px - x0f;
                int y0 = (int)y0f, x0 = (int)x0f;
                int y1 = y0 + 1, x1 = x0 + 1;

                bool vy0 = (y0 >= 0) && (y0 < Hc);
                bool vy1 = (y1 >= 0) && (y1 < Hc);
                bool vx0 = (x0 >= 0) && (x0 < Wc);
                bool vx1 = (x1 >= 0) && (x1 < Wc);

                int y0c = min(max(y0, 0), Hc - 1);
                int y1c = min(max(y1, 0), Hc - 1);
                int x0c = min(max(x0, 0), Wc - 1);
                int x1c = min(max(x1, 0), Wc - 1);

                float w00 = (1.f - wy) * (1.f - wx);
                float w01 = (1.f - wy) * wx;
                float w10 = wy * (1.f - wx);
                float w11 = wy * wx;
                if (!(vy0 && vx0)) w00 = 0.f;
                if (!(vy0 && vx1)) w01 = 0.f;
                if (!(vy1 && vx0)) w10 = 0.f;
                if (!(vy1 && vx1)) w11 = 0.f;

                int i00 = y0c * Wc + x0c;
                int i01 = y0c * Wc + x1c;
                int i10 = y1c * Wc + x0c;
                int i11 = y1c * Wc + x1c;

                const float* xg = xb + (size_t)dg * 4 * HWc;
#pragma unroll
                for (int cg = 0; cg < 4; ++cg) {
                    const float* xc = xg + (size_t)cg * HWc;
                    float sv = w00 * xc[i00] + w01 * xc[i01]
                             + w10 * xc[i10] + w11 * xc[i11];
                    sv *= m;
                    int ch = dg * 4 + cg;
                    const float* wr = wT + (size_t)(ch * 9 + k) * 32;
#pragma unroll
                    for (int o = 0; o < 32; ++o) acc[o] = fmaf(sv, wr[o], acc[o]);
                }
            }
        }
    }

    float* op = out + (size_t)bb * 32 * HWc + hw;
#pragma unroll
    for (int o = 0; o < 32; ++o)
        op[(size_t)o * HWc] = acc[o] + bias[o];
}

extern "C" void kernel_launch(void* const* d_in, const int* in_sizes, int n_in,
                              void* d_out, int out_size, void* d_ws, size_t ws_size,
                              hipStream_t stream) {
    const float* img_ref  = (const float*)d_in[0];
    const float* img      = (const float*)d_in[1];
    const float* conv1_w  = (const float*)d_in[2];
    const float* conv1_b  = (const float*)d_in[3];
    const float* conv2a_w = (const float*)d_in[4];
    const float* conv2a_b = (const float*)d_in[5];
    const float* conv2b_w = (const float*)d_in[6];
    const float* conv2b_b = (const float*)d_in[7];
    const float* off_w    = (const float*)d_in[8];
    const float* off_b    = (const float*)d_in[9];
    const float* dcn_w    = (const float*)d_in[10];
    const float* dcn_b    = (const float*)d_in[11];

    float* wsf = (float*)d_ws;
    u16* frag = (u16*)((char*)d_ws + FRAG_BYTE);
    u16* t0   = (u16*)((char*)d_ws + T0_BYTE);
    u16* t1   = (u16*)((char*)d_ws + T1_BYTE);
    u16* co   = (u16*)((char*)d_ws + CO_BYTE);
    float* out = (float*)d_out;

    prep_k<<<370, 256, 0, stream>>>(conv1_w, conv1_b, conv2a_w, conv2a_b,
                                    conv2b_w, conv2b_b, off_w, off_b,
                                    dcn_w, dcn_b, wsf, frag);

    // conv1x1: [NPIX x 64] @ [64 x 32] -> t0 (ch-last)
    conv_mfma_k<4, 1, 2, 2, 32, 2, 2, 0, false, true>
        <<<NPIX / 128, 256, 0, stream>>>(img_ref, img, frag + FR1_U, wsf + WF_B1, t0);

    // conv2a: t0 -> t1
    conv_mfma_k<4, 1, 2, 2, 32, 2, 9, 1, false, true>
        <<<NPIX / 128, 256, 0, stream>>>(t0, nullptr, frag + FRA_U, wsf + WF_B2A, t1);

    // conv2b: t1 -> t0
    conv_mfma_k<4, 1, 2, 2, 32, 2, 9, 1, false, true>
        <<<NPIX / 128, 256, 0, stream>>>(t1, nullptr, frag + FRB_U, wsf + WF_B2B, t0);

    // offset conv: t0 -> co (ch-major, sigmoid on mask channels)
    conv_mfma_k<2, 2, 2, 7, 216, 14, 9, 1, true, false>
        <<<NPIX / 64, 256, 0, stream>>>(t0, nullptr, frag + FRO_U, wsf + WF_BO, co);

    dcn_k<<<576, 256, 0, stream>>>(img, co, wsf + WF_WDT, wsf + WF_BD, out);
}

// Round 5
// 203.756 us; speedup vs baseline: 3.1314x; 1.2974x over previous
//
#include <hip/hip_runtime.h>

#define Hc   192
#define Wc   192
#define HWc  (Hc * Wc)          // 36864
#define NPIX (4 * HWc)          // 147456

typedef float f32x4 __attribute__((ext_vector_type(4)));
typedef __bf16 bf16x8 __attribute__((ext_vector_type(8)));
typedef unsigned short u16;
typedef unsigned int u32;

// ---- workspace layout ----
// f32 region (element offsets):
#define WF_BO    0      // 224 (offset-conv bias, padded 216->224)
#define WF_B1    224
#define WF_B2A   256
#define WF_B2B   288
#define WF_BD    320
#define WF_WDT   352    // 9216: dcn weights [(ci*9+k)][32]
#define WF_END   9568
// bf16 fragment region (u16 offsets from byte 38272):
#define FR1_U    0      // conv1   [2][2][64][8]   2048
#define FRA_U    2048   // conv2a  [9][2][64][8]   9216
#define FRB_U    11264  // conv2b  [9][2][64][8]   9216
#define FRO_U    20480  // offset  [9][14][64][8]  64512
#define FRAG_BYTE 38272
// buffers (byte offsets):
#define T0_BYTE  208384                       // [NPIX][32] bf16 ch-last
#define T1_BYTE  (T0_BYTE + NPIX * 32 * 2)
#define CO_BYTE  (T1_BYTE + NPIX * 32 * 2)    // [4][216][HW] bf16 ch-major
#define IMG_BYTE (CO_BYTE + 4 * 216 * HWc * 2) // [NPIX][32] bf16 ch-last copy of img

__device__ __forceinline__ u16 f2bf(float f) {
    u32 u = __float_as_uint(f);
    u32 r = u + 0x7fffu + ((u >> 16) & 1u);
    return (u16)(r >> 16);
}
__device__ __forceinline__ float bf2f(u16 v) {
    return __uint_as_float(((u32)v) << 16);
}

// ---------------- prep: biases + dcn weights (f32) + MFMA weight fragments (bf16) ----------------
__global__ __launch_bounds__(256) void prep_k(
    const float* __restrict__ w1,  const float* __restrict__ b1,
    const float* __restrict__ w2a, const float* __restrict__ b2a,
    const float* __restrict__ w2b, const float* __restrict__ b2b,
    const float* __restrict__ wo,  const float* __restrict__ bo,
    const float* __restrict__ wd,  const float* __restrict__ bd,
    float* __restrict__ wsf, u16* __restrict__ frag)
{
    int i = blockIdx.x * 256 + threadIdx.x;
    if (i < 224)      { wsf[WF_BO + i]  = (i < 216) ? bo[i] : 0.f; return; }
    if (i < 256)      { wsf[WF_B1  + i - 224] = b1[i - 224];  return; }
    if (i < 288)      { wsf[WF_B2A + i - 256] = b2a[i - 256]; return; }
    if (i < 320)      { wsf[WF_B2B + i - 288] = b2b[i - 288]; return; }
    if (i < 352)      { wsf[WF_BD  + i - 320] = bd[i - 320];  return; }
    if (i < 9568) {           // dcn weights: [o][ik] -> [ik][o]
        int local = i - 352;
        int o = local / 288, ik = local - o * 288;
        wsf[WF_WDT + ik * 32 + o] = wd[local];
        return;
    }
    int fi = i - 9568;
    if (fi < 2048) {          // conv1 frags: [s][nt][l][j], ci = s*32 + (l>>4)*8 + j
        int s = fi >> 10, nt = (fi >> 9) & 1, l = (fi >> 3) & 63, j = fi & 7;
        int o = nt * 16 + (l & 15);
        int ci = s * 32 + ((l >> 4) << 3) + j;
        frag[FR1_U + fi] = f2bf(w1[o * 64 + ci]);
        return;
    }
    fi -= 2048;
    if (fi < 9216) {          // conv2a frags: tap = s, ci = (l>>4)*8+j
        int s = fi / 1024, r = fi - s * 1024;
        int nt = r >> 9, l = (r >> 3) & 63, j = r & 7;
        int o = nt * 16 + (l & 15);
        int ci = ((l >> 4) << 3) + j;
        frag[FRA_U + fi] = f2bf(w2a[(o * 32 + ci) * 9 + s]);
        return;
    }
    fi -= 9216;
    if (fi < 9216) {          // conv2b frags
        int s = fi / 1024, r = fi - s * 1024;
        int nt = r >> 9, l = (r >> 3) & 63, j = r & 7;
        int o = nt * 16 + (l & 15);
        int ci = ((l >> 4) << 3) + j;
        frag[FRB_U + fi] = f2bf(w2b[(o * 32 + ci) * 9 + s]);
        return;
    }
    fi -= 9216;
    if (fi < 64512) {         // offset-conv frags, COUT padded to 224
        int s = fi / 7168, r = fi - s * 7168;
        int nt = r >> 9, l = (r >> 3) & 63, j = r & 7;
        int o = nt * 16 + (l & 15);
        int ci = ((l >> 4) << 3) + j;
        frag[FRO_U + fi] = f2bf((o < 216) ? wo[(o * 32 + ci) * 9 + s] : 0.f);
        return;
    }
}

// ---------------- implicit-GEMM conv via MFMA ----------------
// MODE 0: 1x1 conv, K=64 from two f32 ch-major sources (s==0 -> s0, s==1 -> s1)
// MODE 1: 3x3 conv pad 1, CIN=32, bf16 ch-last source [NPIX][32]
// Output: CHL ? ch-last bf16 [NPIX][32] : ch-major bf16 [4][COUT][HW]
// DUMP: in MODE 0, also write the s==1 (img) bf16 ch-last tile to `dump`.
template <int WM, int WN, int MF, int NF, int COUT, int NTILES, int KS, int MODE, bool SIG, bool CHL, bool DUMP>
__global__ __launch_bounds__(256) void conv_mfma_k(
    const void* __restrict__ s0v, const void* __restrict__ s1v,
    const u16* __restrict__ wfrag, const float* __restrict__ bias,
    u16* __restrict__ y, u16* __restrict__ dump)
{
    constexpr int M_BLK = WM * MF * 16;
    constexpr int ITERS = M_BLK / 64;
    const int tid = threadIdx.x, lane = tid & 63, wv = tid >> 6;
    const int wm = wv / WN, wn = wv % WN;
    const int m0 = blockIdx.x * M_BLK;
    const int b = m0 / HWc, hwb = m0 - b * HWc;
    const int rm = wm * MF * 16, cn = wn * NF * 16;

    __shared__ uint4 At4[M_BLK * 4];

    int pxA[ITERS], hA[ITERS], wA[ITERS], kgA[ITERS];
#pragma unroll
    for (int it = 0; it < ITERS; ++it) {
        int st = it * 256 + tid;
        int rowl = ((st >> 6) << 4) | (st & 15);
        kgA[it] = (st >> 4) & 3;
        pxA[it] = rowl;
        int hwp = hwb + rowl;
        hA[it] = hwp / Wc;
        wA[it] = hwp - hA[it] * Wc;
    }

    f32x4 acc[MF][NF];
#pragma unroll
    for (int mf = 0; mf < MF; ++mf)
#pragma unroll
        for (int nf = 0; nf < NF; ++nf)
            acc[mf][nf] = f32x4{0.f, 0.f, 0.f, 0.f};

    const u16* srcB = (const u16*)s0v;
    const float* f0 = (const float*)s0v;
    const float* f1 = (const float*)s1v;

    for (int s = 0; s < KS; ++s) {
        // ---- stage A tile ----
        if (MODE == 1) {
            int dy = s / 3 - 1, dx = s - (s / 3) * 3 - 1;
            int d = dy * Wc + dx;
#pragma unroll
            for (int it = 0; it < ITERS; ++it) {
                bool valid = ((unsigned)(hA[it] + dy) < (unsigned)Hc) &&
                             ((unsigned)(wA[it] + dx) < (unsigned)Wc);
                uint4 v = {0u, 0u, 0u, 0u};
                if (valid)
                    v = *(const uint4*)(srcB + ((size_t)(m0 + pxA[it] + d)) * 32 + kgA[it] * 8);
                At4[it * 256 + tid] = v;
            }
        } else {
            const float* fs = (s == 0) ? f0 : f1;
#pragma unroll
            for (int it = 0; it < ITERS; ++it) {
                const float* pl = fs + ((size_t)b * 32 + kgA[it] * 8) * HWc + (hwb + pxA[it]);
                u32 p0, p1, p2, p3;
                {
                    u32 a0 = f2bf(pl[0 * HWc]), a1 = f2bf(pl[1 * HWc]);
                    u32 a2 = f2bf(pl[2 * HWc]), a3 = f2bf(pl[3 * HWc]);
                    u32 a4 = f2bf(pl[4 * HWc]), a5 = f2bf(pl[5 * HWc]);
                    u32 a6 = f2bf(pl[6 * HWc]), a7 = f2bf(pl[7 * HWc]);
                    p0 = a0 | (a1 << 16); p1 = a2 | (a3 << 16);
                    p2 = a4 | (a5 << 16); p3 = a6 | (a7 << 16);
                }
                uint4 v = {p0, p1, p2, p3};
                if (DUMP && s == 1)
                    *(uint4*)(dump + ((size_t)(m0 + pxA[it])) * 32 + kgA[it] * 8) = v;
                At4[it * 256 + tid] = v;
            }
        }
        __syncthreads();

        // ---- fragments + MFMA ----
        bf16x8 aF[MF];
#pragma unroll
        for (int mf = 0; mf < MF; ++mf)
            aF[mf] = __builtin_bit_cast(bf16x8, At4[((rm >> 4) + mf) * 64 + lane]);
#pragma unroll
        for (int nf = 0; nf < NF; ++nf) {
            bf16x8 bF = __builtin_bit_cast(
                bf16x8,
                *(const uint4*)(wfrag + (((size_t)s * NTILES + wn * NF + nf) * 64 + lane) * 8));
#pragma unroll
            for (int mf = 0; mf < MF; ++mf)
                acc[mf][nf] = __builtin_amdgcn_mfma_f32_16x16x32_bf16(aF[mf], bF, acc[mf][nf], 0, 0, 0);
        }
        __syncthreads();
    }

    // ---- epilogue: bias (+sigmoid) + store ----
#pragma unroll
    for (int nf = 0; nf < NF; ++nf) {
        int o = cn + nf * 16 + (lane & 15);
        float bs = bias[o];
#pragma unroll
        for (int mf = 0; mf < MF; ++mf) {
#pragma unroll
            for (int r = 0; r < 4; ++r) {
                int m = m0 + rm + mf * 16 + ((lane >> 4) << 2) + r;
                float val = acc[mf][nf][r] + bs;
                if (SIG && o >= 144) val = 1.f / (1.f + expf(-val));
                if (CHL) {
                    y[(size_t)m * COUT + o] = f2bf(val);
                } else {
                    if (o < COUT)
                        y[((size_t)(b * COUT + o)) * HWc + (m - b * HWc)] = f2bf(val);
                }
            }
        }
    }
}

// ---------------- modulated deformable conv (DCNv2), 3x3, DG=8, Cg=4 ----------------
// Block: 4 waves over the SAME 64 pixels; wave wv handles dg {2wv, 2wv+1}.
// Partial acc[32] per lane; 2-stage LDS tree reduction; wave 0 stores.
__global__ __launch_bounds__(256) void dcn_k(
    const u16* __restrict__ imgc,  // [NPIX][32] bf16 ch-last
    const u16* __restrict__ co,    // [4][216][HW] bf16: dy | dx | mask
    const float* __restrict__ wT,  // [(ci*9+k)][32]
    const float* __restrict__ bias,
    float* __restrict__ out)       // [4][32][HW] f32
{
    const int tid = threadIdx.x;
    const int lane = tid & 63;
    const int wv = __builtin_amdgcn_readfirstlane(tid >> 6);  // SGPR: keeps weight loads scalar

    const int pix = blockIdx.x * 64 + lane;
    const int bb = pix / HWc;
    const int hw = pix - bb * HWc;
    const int hh = hw / Wc;
    const int wwp = hw - hh * Wc;

    __shared__ float red[2][64][33];

    float acc[32];
#pragma unroll
    for (int o = 0; o < 32; ++o) acc[o] = 0.f;

    const u16* xb = imgc + (size_t)bb * HWc * 32;
    const u16* cob = co + (size_t)bb * 216 * HWc + hw;

    for (int dgi = 0; dgi < 2; ++dgi) {
        const int dg = wv * 2 + dgi;
        for (int kyi = 0; kyi < 3; ++kyi) {
            for (int kxi = 0; kxi < 3; ++kxi) {
                int k = kyi * 3 + kxi;
                int offch = dg * 9 + k;
                float dy = bf2f(cob[(size_t)offch * HWc]);
                float dx = bf2f(cob[(size_t)(72 + offch) * HWc]);
                float m  = bf2f(cob[(size_t)(144 + offch) * HWc]);

                float py = dy + (float)(hh + kyi - 1);
                float px = dx + (float)(wwp + kxi - 1);
                float y0f = floorf(py), x0f = floorf(px);
                float wy = py - y0f, wx = px - x0f;
                int y0 = (int)y0f, x0 = (int)x0f;
                int y1 = y0 + 1, x1 = x0 + 1;

                bool vy0 = (y0 >= 0) && (y0 < Hc);
                bool vy1 = (y1 >= 0) && (y1 < Hc);
                bool vx0 = (x0 >= 0) && (x0 < Wc);
                bool vx1 = (x1 >= 0) && (x1 < Wc);

                int y0c = min(max(y0, 0), Hc - 1);
                int y1c = min(max(y1, 0), Hc - 1);
                int x0c = min(max(x0, 0), Wc - 1);
                int x1c = min(max(x1, 0), Wc - 1);

                float w00 = (1.f - wy) * (1.f - wx);
                float w01 = (1.f - wy) * wx;
                float w10 = wy * (1.f - wx);
                float w11 = wy * wx;
                if (!(vy0 && vx0)) w00 = 0.f;
                if (!(vy0 && vx1)) w01 = 0.f;
                if (!(vy1 && vx0)) w10 = 0.f;
                if (!(vy1 && vx1)) w11 = 0.f;

                // 4-channel ch-last gathers: one 8B load per corner
                uint2 c00 = *(const uint2*)(xb + (size_t)(y0c * Wc + x0c) * 32 + dg * 4);
                uint2 c01 = *(const uint2*)(xb + (size_t)(y0c * Wc + x1c) * 32 + dg * 4);
                uint2 c10 = *(const uint2*)(xb + (size_t)(y1c * Wc + x0c) * 32 + dg * 4);
                uint2 c11 = *(const uint2*)(xb + (size_t)(y1c * Wc + x1c) * 32 + dg * 4);

#pragma unroll
                for (int cg = 0; cg < 4; ++cg) {
                    u32 h00 = (cg < 2) ? c00.x : c00.y;
                    u32 h01 = (cg < 2) ? c01.x : c01.y;
                    u32 h10 = (cg < 2) ? c10.x : c10.y;
                    u32 h11 = (cg < 2) ? c11.x : c11.y;
                    int sh = (cg & 1) ? 16 : 0;
                    float v00 = bf2f((u16)(h00 >> sh));
                    float v01 = bf2f((u16)(h01 >> sh));
                    float v10 = bf2f((u16)(h10 >> sh));
                    float v11 = bf2f((u16)(h11 >> sh));
                    float sv = w00 * v00 + w01 * v01 + w10 * v10 + w11 * v11;
                    sv *= m;
                    const float* wr = wT + (size_t)((dg * 4 + cg) * 9 + k) * 32;
#pragma unroll
                    for (int o = 0; o < 32; ++o) acc[o] = fmaf(sv, wr[o], acc[o]);
                }
            }
        }
    }

    // ---- cross-wave reduction: w1->red0, w3->red1; {w0+=red0, w2+=red1->red1}; w0+=red1 ----
    if (wv & 1) {
        float* r = &red[wv >> 1][lane][0];
#pragma unroll
        for (int o = 0; o < 32; ++o) r[o] = acc[o];
    }
    __syncthreads();
    if (wv == 0) {
        const float* r = &red[0][lane][0];
#pragma unroll
        for (int o = 0; o < 32; ++o) acc[o] += r[o];
    }
    if (wv == 2) {
        float* r = &red[1][lane][0];
#pragma unroll
        for (int o = 0; o < 32; ++o) { acc[o] += r[o]; r[o] = acc[o]; }
    }
    __syncthreads();
    if (wv == 0) {
        const float* r = &red[1][lane][0];
        float* op = out + (size_t)bb * 32 * HWc + hw;
#pragma unroll
        for (int o = 0; o < 32; ++o)
            op[(size_t)o * HWc] = acc[o] + r[o] + bias[o];
    }
}

extern "C" void kernel_launch(void* const* d_in, const int* in_sizes, int n_in,
                              void* d_out, int out_size, void* d_ws, size_t ws_size,
                              hipStream_t stream) {
    const float* img_ref  = (const float*)d_in[0];
    const float* img      = (const float*)d_in[1];
    const float* conv1_w  = (const float*)d_in[2];
    const float* conv1_b  = (const float*)d_in[3];
    const float* conv2a_w = (const float*)d_in[4];
    const float* conv2a_b = (const float*)d_in[5];
    const float* conv2b_w = (const float*)d_in[6];
    const float* conv2b_b = (const float*)d_in[7];
    const float* off_w    = (const float*)d_in[8];
    const float* off_b    = (const float*)d_in[9];
    const float* dcn_w    = (const float*)d_in[10];
    const float* dcn_b    = (const float*)d_in[11];

    float* wsf = (float*)d_ws;
    u16* frag = (u16*)((char*)d_ws + FRAG_BYTE);
    u16* t0   = (u16*)((char*)d_ws + T0_BYTE);
    u16* t1   = (u16*)((char*)d_ws + T1_BYTE);
    u16* co   = (u16*)((char*)d_ws + CO_BYTE);
    u16* imgc = (u16*)((char*)d_ws + IMG_BYTE);
    float* out = (float*)d_out;

    prep_k<<<370, 256, 0, stream>>>(conv1_w, conv1_b, conv2a_w, conv2a_b,
                                    conv2b_w, conv2b_b, off_w, off_b,
                                    dcn_w, dcn_b, wsf, frag);

    // conv1x1: [NPIX x 64] @ [64 x 32] -> t0 (ch-last); also dumps img as bf16 ch-last
    conv_mfma_k<4, 1, 2, 2, 32, 2, 2, 0, false, true, true>
        <<<NPIX / 128, 256, 0, stream>>>(img_ref, img, frag + FR1_U, wsf + WF_B1, t0, imgc);

    // conv2a: t0 -> t1
    conv_mfma_k<4, 1, 2, 2, 32, 2, 9, 1, false, true, false>
        <<<NPIX / 128, 256, 0, stream>>>(t0, nullptr, frag + FRA_U, wsf + WF_B2A, t1, nullptr);

    // conv2b: t1 -> t0
    conv_mfma_k<4, 1, 2, 2, 32, 2, 9, 1, false, true, false>
        <<<NPIX / 128, 256, 0, stream>>>(t1, nullptr, frag + FRB_U, wsf + WF_B2B, t0, nullptr);

    // offset conv: t0 -> co (ch-major, sigmoid on mask channels)
    conv_mfma_k<2, 2, 2, 7, 216, 14, 9, 1, true, false, false>
        <<<NPIX / 64, 256, 0, stream>>>(t0, nullptr, frag + FRO_U, wsf + WF_BO, co, nullptr);

    dcn_k<<<NPIX / 64, 256, 0, stream>>>(imgc, co, wsf + WF_WDT, wsf + WF_BD, out);
}

// Round 6
// 189.165 us; speedup vs baseline: 3.3730x; 1.0771x over previous
//
#include <hip/hip_runtime.h>

#define Hc   192
#define Wc   192
#define HWc  (Hc * Wc)          // 36864
#define NPIX (4 * HWc)          // 147456

typedef float f32x4 __attribute__((ext_vector_type(4)));
typedef __bf16 bf16x8 __attribute__((ext_vector_type(8)));
typedef unsigned short u16;
typedef unsigned int u32;

// ---- workspace layout ----
// f32 region (element offsets):
#define WF_BO    0      // 224 (offset-conv bias, padded 216->224)
#define WF_B1    224
#define WF_B2A   256
#define WF_B2B   288
#define WF_BD    320    // end 352 floats = 1408 B
// bf16 fragment region (u16 offsets from FRAG_BYTE):
#define FR1_U    0      // conv1   [2][2][64][8]   2048
#define FRA_U    2048   // conv2a  [9][2][64][8]   9216
#define FRB_U    11264  // conv2b  [9][2][64][8]   9216
#define FRO_U    20480  // offset  [9][14][64][8]  64512
#define FRD_U    84992  // dcn     [9][2][64][8]   9216  (K-within-32 = dg*4+cg)
#define FRAG_U_TOT 94208
#define FRAG_BYTE 1408
// buffers (byte offsets):
#define T0_BYTE  (FRAG_BYTE + FRAG_U_TOT * 2)        // 189824: [NPIX][32] bf16 ch-last
#define T1_BYTE  (T0_BYTE + NPIX * 32 * 2)
#define CO_BYTE  (T1_BYTE + NPIX * 32 * 2)           // [4][216][HW] bf16 ch-major
#define IMG_BYTE (CO_BYTE + 4 * 216 * HWc * 2)       // [NPIX][32] bf16 ch-last copy of img

__device__ __forceinline__ u16 f2bf(float f) {
    u32 u = __float_as_uint(f);
    u32 r = u + 0x7fffu + ((u >> 16) & 1u);
    return (u16)(r >> 16);
}
__device__ __forceinline__ float bf2f(u16 v) {
    return __uint_as_float(((u32)v) << 16);
}

// ---------------- prep: biases (f32) + MFMA weight fragments (bf16) ----------------
__global__ __launch_bounds__(256) void prep_k(
    const float* __restrict__ w1,  const float* __restrict__ b1,
    const float* __restrict__ w2a, const float* __restrict__ b2a,
    const float* __restrict__ w2b, const float* __restrict__ b2b,
    const float* __restrict__ wo,  const float* __restrict__ bo,
    const float* __restrict__ wd,  const float* __restrict__ bd,
    float* __restrict__ wsf, u16* __restrict__ frag)
{
    int i = blockIdx.x * 256 + threadIdx.x;
    if (i < 224)      { wsf[WF_BO + i]  = (i < 216) ? bo[i] : 0.f; return; }
    if (i < 256)      { wsf[WF_B1  + i - 224] = b1[i - 224];  return; }
    if (i < 288)      { wsf[WF_B2A + i - 256] = b2a[i - 256]; return; }
    if (i < 320)      { wsf[WF_B2B + i - 288] = b2b[i - 288]; return; }
    if (i < 352)      { wsf[WF_BD  + i - 320] = bd[i - 320];  return; }
    int fi = i - 352;
    if (fi < 2048) {          // conv1 frags: [s][nt][l][j], ci = s*32 + (l>>4)*8 + j
        int s = fi >> 10, l = (fi >> 3) & 63, j = fi & 7;
        int nt = (fi >> 9) & 1;
        int o = nt * 16 + (l & 15);
        int ci = s * 32 + ((l >> 4) << 3) + j;
        frag[FR1_U + fi] = f2bf(w1[o * 64 + ci]);
        return;
    }
    fi -= 2048;
    if (fi < 9216) {          // conv2a frags: tap = s, ci = (l>>4)*8+j
        int s = fi / 1024, r = fi - s * 1024;
        int nt = r >> 9, l = (r >> 3) & 63, j = r & 7;
        int o = nt * 16 + (l & 15);
        int ci = ((l >> 4) << 3) + j;
        frag[FRA_U + fi] = f2bf(w2a[(o * 32 + ci) * 9 + s]);
        return;
    }
    fi -= 9216;
    if (fi < 9216) {          // conv2b frags
        int s = fi / 1024, r = fi - s * 1024;
        int nt = r >> 9, l = (r >> 3) & 63, j = r & 7;
        int o = nt * 16 + (l & 15);
        int ci = ((l >> 4) << 3) + j;
        frag[FRB_U + fi] = f2bf(w2b[(o * 32 + ci) * 9 + s]);
        return;
    }
    fi -= 9216;
    if (fi < 64512) {         // offset-conv frags, COUT padded to 224
        int s = fi / 7168, r = fi - s * 7168;
        int nt = r >> 9, l = (r >> 3) & 63, j = r & 7;
        int o = nt * 16 + (l & 15);
        int ci = ((l >> 4) << 3) + j;
        frag[FRO_U + fi] = f2bf((o < 216) ? wo[(o * 32 + ci) * 9 + s] : 0.f);
        return;
    }
    fi -= 64512;
    if (fi < 9216) {          // dcn frags: [k][nt][l][j], K-within = (l>>4)*8+j = ci = dg*4+cg
        int k = fi / 1024, r = fi - k * 1024;
        int nt = r >> 9, l = (r >> 3) & 63, j = r & 7;
        int o = nt * 16 + (l & 15);
        int ci = ((l >> 4) << 3) + j;
        frag[FRD_U + fi] = f2bf(wd[o * 288 + ci * 9 + k]);
        return;
    }
}

// ---------------- implicit-GEMM conv via MFMA ----------------
// MODE 0: 1x1 conv, K=64 from two f32 ch-major sources (s==0 -> s0, s==1 -> s1)
// MODE 1: 3x3 conv pad 1, CIN=32, bf16 ch-last source [NPIX][32]
// Output: CHL ? ch-last bf16 [NPIX][32] : ch-major bf16 [4][COUT][HW]
// DUMP: in MODE 0, also write the s==1 (img) bf16 ch-last tile to `dump`.
template <int WM, int WN, int MF, int NF, int COUT, int NTILES, int KS, int MODE, bool SIG, bool CHL, bool DUMP>
__global__ __launch_bounds__(256) void conv_mfma_k(
    const void* __restrict__ s0v, const void* __restrict__ s1v,
    const u16* __restrict__ wfrag, const float* __restrict__ bias,
    u16* __restrict__ y, u16* __restrict__ dump)
{
    constexpr int M_BLK = WM * MF * 16;
    constexpr int ITERS = M_BLK / 64;
    const int tid = threadIdx.x, lane = tid & 63, wv = tid >> 6;
    const int wm = wv / WN, wn = wv % WN;
    const int m0 = blockIdx.x * M_BLK;
    const int b = m0 / HWc, hwb = m0 - b * HWc;
    const int rm = wm * MF * 16, cn = wn * NF * 16;

    __shared__ uint4 At4[M_BLK * 4];

    int pxA[ITERS], hA[ITERS], wA[ITERS], kgA[ITERS];
#pragma unroll
    for (int it = 0; it < ITERS; ++it) {
        int st = it * 256 + tid;
        int rowl = ((st >> 6) << 4) | (st & 15);
        kgA[it] = (st >> 4) & 3;
        pxA[it] = rowl;
        int hwp = hwb + rowl;
        hA[it] = hwp / Wc;
        wA[it] = hwp - hA[it] * Wc;
    }

    f32x4 acc[MF][NF];
#pragma unroll
    for (int mf = 0; mf < MF; ++mf)
#pragma unroll
        for (int nf = 0; nf < NF; ++nf)
            acc[mf][nf] = f32x4{0.f, 0.f, 0.f, 0.f};

    const u16* srcB = (const u16*)s0v;
    const float* f0 = (const float*)s0v;
    const float* f1 = (const float*)s1v;

    for (int s = 0; s < KS; ++s) {
        // ---- stage A tile ----
        if (MODE == 1) {
            int dy = s / 3 - 1, dx = s - (s / 3) * 3 - 1;
            int d = dy * Wc + dx;
#pragma unroll
            for (int it = 0; it < ITERS; ++it) {
                bool valid = ((unsigned)(hA[it] + dy) < (unsigned)Hc) &&
                             ((unsigned)(wA[it] + dx) < (unsigned)Wc);
                uint4 v = {0u, 0u, 0u, 0u};
                if (valid)
                    v = *(const uint4*)(srcB + ((size_t)(m0 + pxA[it] + d)) * 32 + kgA[it] * 8);
                At4[it * 256 + tid] = v;
            }
        } else {
            const float* fs = (s == 0) ? f0 : f1;
#pragma unroll
            for (int it = 0; it < ITERS; ++it) {
                const float* pl = fs + ((size_t)b * 32 + kgA[it] * 8) * HWc + (hwb + pxA[it]);
                u32 p0, p1, p2, p3;
                {
                    u32 a0 = f2bf(pl[0 * HWc]), a1 = f2bf(pl[1 * HWc]);
                    u32 a2 = f2bf(pl[2 * HWc]), a3 = f2bf(pl[3 * HWc]);
                    u32 a4 = f2bf(pl[4 * HWc]), a5 = f2bf(pl[5 * HWc]);
                    u32 a6 = f2bf(pl[6 * HWc]), a7 = f2bf(pl[7 * HWc]);
                    p0 = a0 | (a1 << 16); p1 = a2 | (a3 << 16);
                    p2 = a4 | (a5 << 16); p3 = a6 | (a7 << 16);
                }
                uint4 v = {p0, p1, p2, p3};
                if (DUMP && s == 1)
                    *(uint4*)(dump + ((size_t)(m0 + pxA[it])) * 32 + kgA[it] * 8) = v;
                At4[it * 256 + tid] = v;
            }
        }
        __syncthreads();

        // ---- fragments + MFMA ----
        bf16x8 aF[MF];
#pragma unroll
        for (int mf = 0; mf < MF; ++mf)
            aF[mf] = __builtin_bit_cast(bf16x8, At4[((rm >> 4) + mf) * 64 + lane]);
#pragma unroll
        for (int nf = 0; nf < NF; ++nf) {
            bf16x8 bF = __builtin_bit_cast(
                bf16x8,
                *(const uint4*)(wfrag + (((size_t)s * NTILES + wn * NF + nf) * 64 + lane) * 8));
#pragma unroll
            for (int mf = 0; mf < MF; ++mf)
                acc[mf][nf] = __builtin_amdgcn_mfma_f32_16x16x32_bf16(aF[mf], bF, acc[mf][nf], 0, 0, 0);
        }
        __syncthreads();
    }

    // ---- epilogue: bias (+sigmoid) + store ----
#pragma unroll
    for (int nf = 0; nf < NF; ++nf) {
        int o = cn + nf * 16 + (lane & 15);
        float bs = bias[o];
#pragma unroll
        for (int mf = 0; mf < MF; ++mf) {
#pragma unroll
            for (int r = 0; r < 4; ++r) {
                int m = m0 + rm + mf * 16 + ((lane >> 4) << 2) + r;
                float val = acc[mf][nf][r] + bs;
                if (SIG && o >= 144) val = 1.f / (1.f + expf(-val));
                if (CHL) {
                    y[(size_t)m * COUT + o] = f2bf(val);
                } else {
                    if (o < COUT)
                        y[((size_t)(b * COUT + o)) * HWc + (m - b * HWc)] = f2bf(val);
                }
            }
        }
    }
}

// ---------------- modulated deformable conv (DCNv2) via MFMA ----------------
// Block: 4 waves, 64 pixels. Per tap k: each lane samples 8 K-values
// (its wave's dg pair {2wv,2wv+1} x 4 cg) for its pixel, packs to bf16,
// stages the [64][32] A-tile in LDS (double-buffered, 1 barrier/tap),
// then each wave MFMAs its 16-row m-tile against the [32][32] weight slice.
__global__ __launch_bounds__(256) void dcn_k(
    const u16* __restrict__ imgc,  // [NPIX][32] bf16 ch-last
    const u16* __restrict__ co,    // [4][216][HW] bf16: dy | dx | mask
    const u16* __restrict__ wfrag, // [9][2][64][8] bf16, K-within-32 = dg*4+cg
    const float* __restrict__ bias,
    float* __restrict__ out)       // [4][32][HW] f32
{
    const int tid = threadIdx.x, lane = tid & 63, wv = tid >> 6;
    const int pix = blockIdx.x * 64 + lane;
    const int bb = pix / HWc;
    const int hw = pix - bb * HWc;
    const int hh = hw / Wc;
    const int wwp = hw - hh * Wc;

    __shared__ uint4 At[2][256];

    const u16* xb = imgc + (size_t)bb * HWc * 32;
    const u16* cob = co + (size_t)bb * 216 * HWc + hw;

    // lane p (pixel), wave wv (k-group): A-frag read At[f*64+l] wants
    // row = f*16 + (l&15), kg = l>>4  =>  slot = (p>>4)*64 + wv*16 + (p&15)
    const int slot = ((lane >> 4) << 6) | (wv << 4) | (lane & 15);

    f32x4 acc0 = {0.f, 0.f, 0.f, 0.f};
    f32x4 acc1 = {0.f, 0.f, 0.f, 0.f};

    for (int k = 0; k < 9; ++k) {
        const int kyi = k / 3, kxi = k - kyi * 3;
        u32 pk[4];
#pragma unroll
        for (int dgi = 0; dgi < 2; ++dgi) {
            const int dg = wv * 2 + dgi;
            const int offch = dg * 9 + k;
            float dy = bf2f(cob[(size_t)offch * HWc]);
            float dx = bf2f(cob[(size_t)(72 + offch) * HWc]);
            float m  = bf2f(cob[(size_t)(144 + offch) * HWc]);

            float py = dy + (float)(hh + kyi - 1);
            float px = dx + (float)(wwp + kxi - 1);
            float y0f = floorf(py), x0f = floorf(px);
            float wy = py - y0f, wx = px - x0f;
            int y0 = (int)y0f, x0 = (int)x0f;
            int y1 = y0 + 1, x1 = x0 + 1;

            bool vy0 = (unsigned)y0 < (unsigned)Hc;
            bool vy1 = (unsigned)y1 < (unsigned)Hc;
            bool vx0 = (unsigned)x0 < (unsigned)Wc;
            bool vx1 = (unsigned)x1 < (unsigned)Wc;

            int y0c = min(max(y0, 0), Hc - 1);
            int y1c = min(max(y1, 0), Hc - 1);
            int x0c = min(max(x0, 0), Wc - 1);
            int x1c = min(max(x1, 0), Wc - 1);

            float w00 = (1.f - wy) * (1.f - wx);
            float w01 = (1.f - wy) * wx;
            float w10 = wy * (1.f - wx);
            float w11 = wy * wx;
            if (!(vy0 && vx0)) w00 = 0.f;
            if (!(vy0 && vx1)) w01 = 0.f;
            if (!(vy1 && vx0)) w10 = 0.f;
            if (!(vy1 && vx1)) w11 = 0.f;
            w00 *= m; w01 *= m; w10 *= m; w11 *= m;   // fold mask into bilinear weights

            uint2 c00 = *(const uint2*)(xb + (size_t)(y0c * Wc + x0c) * 32 + dg * 4);
            uint2 c01 = *(const uint2*)(xb + (size_t)(y0c * Wc + x1c) * 32 + dg * 4);
            uint2 c10 = *(const uint2*)(xb + (size_t)(y1c * Wc + x0c) * 32 + dg * 4);
            uint2 c11 = *(const uint2*)(xb + (size_t)(y1c * Wc + x1c) * 32 + dg * 4);

            float s[4];
#pragma unroll
            for (int cg = 0; cg < 4; ++cg) {
                u32 h00 = (cg < 2) ? c00.x : c00.y;
                u32 h01 = (cg < 2) ? c01.x : c01.y;
                u32 h10 = (cg < 2) ? c10.x : c10.y;
                u32 h11 = (cg < 2) ? c11.x : c11.y;
                int sh = (cg & 1) ? 16 : 0;
                s[cg] = w00 * bf2f((u16)(h00 >> sh)) + w01 * bf2f((u16)(h01 >> sh))
                      + w10 * bf2f((u16)(h10 >> sh)) + w11 * bf2f((u16)(h11 >> sh));
            }
            pk[dgi * 2 + 0] = (u32)f2bf(s[0]) | ((u32)f2bf(s[1]) << 16);
            pk[dgi * 2 + 1] = (u32)f2bf(s[2]) | ((u32)f2bf(s[3]) << 16);
        }

        const int sel = k & 1;
        At[sel][slot] = uint4{pk[0], pk[1], pk[2], pk[3]};
        __syncthreads();   // single barrier/tap: dbuf protects prior tap's reads

        bf16x8 aF = __builtin_bit_cast(bf16x8, At[sel][wv * 64 + lane]);
        bf16x8 bF0 = __builtin_bit_cast(bf16x8,
            *(const uint4*)(wfrag + ((size_t)(k * 2 + 0) * 64 + lane) * 8));
        bf16x8 bF1 = __builtin_bit_cast(bf16x8,
            *(const uint4*)(wfrag + ((size_t)(k * 2 + 1) * 64 + lane) * 8));
        acc0 = __builtin_amdgcn_mfma_f32_16x16x32_bf16(aF, bF0, acc0, 0, 0, 0);
        acc1 = __builtin_amdgcn_mfma_f32_16x16x32_bf16(aF, bF1, acc1, 0, 0, 0);
    }

    // ---- epilogue: wave wv owns rows [16wv,16wv+16) of this 64-pixel block ----
    const int rbase = blockIdx.x * 64 + wv * 16 + ((lane >> 4) << 2);
    const int hw0 = rbase - bb * HWc;
    float* ob = out + (size_t)bb * 32 * HWc;
    const int oL = lane & 15;
    const float bs0 = bias[oL], bs1 = bias[16 + oL];
#pragma unroll
    for (int r = 0; r < 4; ++r) {
        ob[(size_t)oL * HWc + hw0 + r] = acc0[r] + bs0;
        ob[(size_t)(16 + oL) * HWc + hw0 + r] = acc1[r] + bs1;
    }
}

extern "C" void kernel_launch(void* const* d_in, const int* in_sizes, int n_in,
                              void* d_out, int out_size, void* d_ws, size_t ws_size,
                              hipStream_t stream) {
    const float* img_ref  = (const float*)d_in[0];
    const float* img      = (const float*)d_in[1];
    const float* conv1_w  = (const float*)d_in[2];
    const float* conv1_b  = (const float*)d_in[3];
    const float* conv2a_w = (const float*)d_in[4];
    const float* conv2a_b = (const float*)d_in[5];
    const float* conv2b_w = (const float*)d_in[6];
    const float* conv2b_b = (const float*)d_in[7];
    const float* off_w    = (const float*)d_in[8];
    const float* off_b    = (const float*)d_in[9];
    const float* dcn_w    = (const float*)d_in[10];
    const float* dcn_b    = (const float*)d_in[11];

    float* wsf = (float*)d_ws;
    u16* frag = (u16*)((char*)d_ws + FRAG_BYTE);
    u16* t0   = (u16*)((char*)d_ws + T0_BYTE);
    u16* t1   = (u16*)((char*)d_ws + T1_BYTE);
    u16* co   = (u16*)((char*)d_ws + CO_BYTE);
    u16* imgc = (u16*)((char*)d_ws + IMG_BYTE);
    float* out = (float*)d_out;

    prep_k<<<370, 256, 0, stream>>>(conv1_w, conv1_b, conv2a_w, conv2a_b,
                                    conv2b_w, conv2b_b, off_w, off_b,
                                    dcn_w, dcn_b, wsf, frag);

    // conv1x1: [NPIX x 64] @ [64 x 32] -> t0 (ch-last); also dumps img as bf16 ch-last
    conv_mfma_k<4, 1, 2, 2, 32, 2, 2, 0, false, true, true>
        <<<NPIX / 128, 256, 0, stream>>>(img_ref, img, frag + FR1_U, wsf + WF_B1, t0, imgc);

    // conv2a: t0 -> t1
    conv_mfma_k<4, 1, 2, 2, 32, 2, 9, 1, false, true, false>
        <<<NPIX / 128, 256, 0, stream>>>(t0, nullptr, frag + FRA_U, wsf + WF_B2A, t1, nullptr);

    // conv2b: t1 -> t0
    conv_mfma_k<4, 1, 2, 2, 32, 2, 9, 1, false, true, false>
        <<<NPIX / 128, 256, 0, stream>>>(t1, nullptr, frag + FRB_U, wsf + WF_B2B, t0, nullptr);

    // offset conv: t0 -> co (ch-major, sigmoid on mask channels)
    conv_mfma_k<2, 2, 2, 7, 216, 14, 9, 1, true, false, false>
        <<<NPIX / 64, 256, 0, stream>>>(t0, nullptr, frag + FRO_U, wsf + WF_BO, co, nullptr);

    dcn_k<<<NPIX / 64, 256, 0, stream>>>(imgc, co, frag + FRD_U, wsf + WF_BD, out);
}

// Round 7
// 150.486 us; speedup vs baseline: 4.2399x; 1.2570x over previous
//
#include <hip/hip_runtime.h>

#define Hc   192
#define Wc   192
#define HWc  (Hc * Wc)          // 36864
#define NPIX (4 * HWc)          // 147456

typedef float f32x4 __attribute__((ext_vector_type(4)));
typedef __bf16 bf16x8 __attribute__((ext_vector_type(8)));
typedef unsigned short u16;
typedef unsigned int u32;

// ---- workspace layout ----
// f32 region (element offsets):
#define WF_BO    0      // 224 (offset-conv bias, padded 216->224)
#define WF_B1    224
#define WF_B2A   256
#define WF_B2B   288
#define WF_BD    320    // end 352 floats = 1408 B
// bf16 fragment region (u16 offsets from FRAG_BYTE):
#define FR1_U    0      // conv1   [2][2][64][8]   2048
#define FRA_U    2048   // conv2a  [9][2][64][8]   9216
#define FRB_U    11264  // conv2b  [9][2][64][8]   9216
#define FRO_U    20480  // offset  [9][14][64][8]  64512
#define FRD_U    84992  // dcn     [9][2][64][8]   9216  (K-within-32 = dg*4+cg)
#define FRAG_U_TOT 94208
#define FRAG_BYTE 1408
// buffers (byte offsets):
#define T0_BYTE  (FRAG_BYTE + FRAG_U_TOT * 2)        // [NPIX][32] bf16 ch-last
#define T1_BYTE  (T0_BYTE + NPIX * 32 * 2)
#define IMG_BYTE (T1_BYTE + NPIX * 32 * 2)           // [NPIX][32] bf16 ch-last copy of img

__device__ __forceinline__ u16 f2bf(float f) {
    u32 u = __float_as_uint(f);
    u32 r = u + 0x7fffu + ((u >> 16) & 1u);
    return (u16)(r >> 16);
}
__device__ __forceinline__ float bf2f(u16 v) {
    return __uint_as_float(((u32)v) << 16);
}

// ---------------- prep: biases (f32) + MFMA weight fragments (bf16) ----------------
__global__ __launch_bounds__(256) void prep_k(
    const float* __restrict__ w1,  const float* __restrict__ b1,
    const float* __restrict__ w2a, const float* __restrict__ b2a,
    const float* __restrict__ w2b, const float* __restrict__ b2b,
    const float* __restrict__ wo,  const float* __restrict__ bo,
    const float* __restrict__ wd,  const float* __restrict__ bd,
    float* __restrict__ wsf, u16* __restrict__ frag)
{
    int i = blockIdx.x * 256 + threadIdx.x;
    if (i < 224)      { wsf[WF_BO + i]  = (i < 216) ? bo[i] : 0.f; return; }
    if (i < 256)      { wsf[WF_B1  + i - 224] = b1[i - 224];  return; }
    if (i < 288)      { wsf[WF_B2A + i - 256] = b2a[i - 256]; return; }
    if (i < 320)      { wsf[WF_B2B + i - 288] = b2b[i - 288]; return; }
    if (i < 352)      { wsf[WF_BD  + i - 320] = bd[i - 320];  return; }
    int fi = i - 352;
    if (fi < 2048) {          // conv1 frags: [s][nt][l][j], ci = s*32 + (l>>4)*8 + j
        int s = fi >> 10, l = (fi >> 3) & 63, j = fi & 7;
        int nt = (fi >> 9) & 1;
        int o = nt * 16 + (l & 15);
        int ci = s * 32 + ((l >> 4) << 3) + j;
        frag[FR1_U + fi] = f2bf(w1[o * 64 + ci]);
        return;
    }
    fi -= 2048;
    if (fi < 9216) {          // conv2a frags: tap = s, ci = (l>>4)*8+j
        int s = fi / 1024, r = fi - s * 1024;
        int nt = r >> 9, l = (r >> 3) & 63, j = r & 7;
        int o = nt * 16 + (l & 15);
        int ci = ((l >> 4) << 3) + j;
        frag[FRA_U + fi] = f2bf(w2a[(o * 32 + ci) * 9 + s]);
        return;
    }
    fi -= 9216;
    if (fi < 9216) {          // conv2b frags
        int s = fi / 1024, r = fi - s * 1024;
        int nt = r >> 9, l = (r >> 3) & 63, j = r & 7;
        int o = nt * 16 + (l & 15);
        int ci = ((l >> 4) << 3) + j;
        frag[FRB_U + fi] = f2bf(w2b[(o * 32 + ci) * 9 + s]);
        return;
    }
    fi -= 9216;
    if (fi < 64512) {         // offset-conv frags, COUT padded to 224
        int s = fi / 7168, r = fi - s * 7168;
        int nt = r >> 9, l = (r >> 3) & 63, j = r & 7;
        int o = nt * 16 + (l & 15);
        int ci = ((l >> 4) << 3) + j;
        frag[FRO_U + fi] = f2bf((o < 216) ? wo[(o * 32 + ci) * 9 + s] : 0.f);
        return;
    }
    fi -= 64512;
    if (fi < 9216) {          // dcn frags: [k][nt][l][j], K-within = (l>>4)*8+j = ci = dg*4+cg
        int k = fi / 1024, r = fi - k * 1024;
        int nt = r >> 9, l = (r >> 3) & 63, j = r & 7;
        int o = nt * 16 + (l & 15);
        int ci = ((l >> 4) << 3) + j;
        frag[FRD_U + fi] = f2bf(wd[o * 288 + ci * 9 + k]);
        return;
    }
}

// ---------------- implicit-GEMM conv via MFMA (small convs) ----------------
// MODE 0: 1x1 conv, K=64 from two f32 ch-major sources (s==0 -> s0, s==1 -> s1)
// MODE 1: 3x3 conv pad 1, CIN=32, bf16 ch-last source [NPIX][32]
// Output: ch-last bf16 [NPIX][32]
// DUMP: in MODE 0, also write the s==1 (img) bf16 ch-last tile to `dump`.
template <int WM, int WN, int MF, int NF, int COUT, int NTILES, int KS, int MODE, bool CHL, bool DUMP>
__global__ __launch_bounds__(256) void conv_mfma_k(
    const void* __restrict__ s0v, const void* __restrict__ s1v,
    const u16* __restrict__ wfrag, const float* __restrict__ bias,
    u16* __restrict__ y, u16* __restrict__ dump)
{
    constexpr int M_BLK = WM * MF * 16;
    constexpr int ITERS = M_BLK / 64;
    const int tid = threadIdx.x, lane = tid & 63, wv = tid >> 6;
    const int wm = wv / WN, wn = wv % WN;
    const int m0 = blockIdx.x * M_BLK;
    const int b = m0 / HWc, hwb = m0 - b * HWc;
    const int rm = wm * MF * 16, cn = wn * NF * 16;

    __shared__ uint4 At4[M_BLK * 4];

    int pxA[ITERS], hA[ITERS], wA[ITERS], kgA[ITERS];
#pragma unroll
    for (int it = 0; it < ITERS; ++it) {
        int st = it * 256 + tid;
        int rowl = ((st >> 6) << 4) | (st & 15);
        kgA[it] = (st >> 4) & 3;
        pxA[it] = rowl;
        int hwp = hwb + rowl;
        hA[it] = hwp / Wc;
        wA[it] = hwp - hA[it] * Wc;
    }

    f32x4 acc[MF][NF];
#pragma unroll
    for (int mf = 0; mf < MF; ++mf)
#pragma unroll
        for (int nf = 0; nf < NF; ++nf)
            acc[mf][nf] = f32x4{0.f, 0.f, 0.f, 0.f};

    const u16* srcB = (const u16*)s0v;
    const float* f0 = (const float*)s0v;
    const float* f1 = (const float*)s1v;

    for (int s = 0; s < KS; ++s) {
        // ---- stage A tile ----
        if (MODE == 1) {
            int dy = s / 3 - 1, dx = s - (s / 3) * 3 - 1;
            int d = dy * Wc + dx;
#pragma unroll
            for (int it = 0; it < ITERS; ++it) {
                bool valid = ((unsigned)(hA[it] + dy) < (unsigned)Hc) &&
                             ((unsigned)(wA[it] + dx) < (unsigned)Wc);
                uint4 v = {0u, 0u, 0u, 0u};
                if (valid)
                    v = *(const uint4*)(srcB + ((size_t)(m0 + pxA[it] + d)) * 32 + kgA[it] * 8);
                At4[it * 256 + tid] = v;
            }
        } else {
            const float* fs = (s == 0) ? f0 : f1;
#pragma unroll
            for (int it = 0; it < ITERS; ++it) {
                const float* pl = fs + ((size_t)b * 32 + kgA[it] * 8) * HWc + (hwb + pxA[it]);
                u32 p0, p1, p2, p3;
                {
                    u32 a0 = f2bf(pl[0 * HWc]), a1 = f2bf(pl[1 * HWc]);
                    u32 a2 = f2bf(pl[2 * HWc]), a3 = f2bf(pl[3 * HWc]);
                    u32 a4 = f2bf(pl[4 * HWc]), a5 = f2bf(pl[5 * HWc]);
                    u32 a6 = f2bf(pl[6 * HWc]), a7 = f2bf(pl[7 * HWc]);
                    p0 = a0 | (a1 << 16); p1 = a2 | (a3 << 16);
                    p2 = a4 | (a5 << 16); p3 = a6 | (a7 << 16);
                }
                uint4 v = {p0, p1, p2, p3};
                if (DUMP && s == 1)
                    *(uint4*)(dump + ((size_t)(m0 + pxA[it])) * 32 + kgA[it] * 8) = v;
                At4[it * 256 + tid] = v;
            }
        }
        __syncthreads();

        // ---- fragments + MFMA ----
        bf16x8 aF[MF];
#pragma unroll
        for (int mf = 0; mf < MF; ++mf)
            aF[mf] = __builtin_bit_cast(bf16x8, At4[((rm >> 4) + mf) * 64 + lane]);
#pragma unroll
        for (int nf = 0; nf < NF; ++nf) {
            bf16x8 bF = __builtin_bit_cast(
                bf16x8,
                *(const uint4*)(wfrag + (((size_t)s * NTILES + wn * NF + nf) * 64 + lane) * 8));
#pragma unroll
            for (int mf = 0; mf < MF; ++mf)
                acc[mf][nf] = __builtin_amdgcn_mfma_f32_16x16x32_bf16(aF[mf], bF, acc[mf][nf], 0, 0, 0);
        }
        __syncthreads();
    }

    // ---- epilogue: bias + store ch-last ----
#pragma unroll
    for (int nf = 0; nf < NF; ++nf) {
        int o = cn + nf * 16 + (lane & 15);
        float bs = bias[o];
#pragma unroll
        for (int mf = 0; mf < MF; ++mf) {
#pragma unroll
            for (int r = 0; r < 4; ++r) {
                int m = m0 + rm + mf * 16 + ((lane >> 4) << 2) + r;
                float val = acc[mf][nf][r] + bs;
                y[(size_t)m * COUT + o] = f2bf(val);
            }
        }
    }
}

// ---------------- FUSED: offset conv (216ch -> LDS) + modulated deformable conv ----------------
// Block: 4 waves, 64 pixels.
// Phase 1: implicit-GEMM offset conv (9 taps, 2x2 waves, MF=2/NF=7) -> co_s[224][66] bf16 in LDS
//          (sigmoid fused on ch>=144). 1 barrier/tap via double-buffered A staging.
// Phase 2: DCNv2 — each lane samples 8 K-values/tap from imgc (wave's dg pair x 4 cg),
//          reading dy/dx/mask from co_s; A-tile staged in the same LDS dbuf; 2 MFMAs/tap.
__global__ __launch_bounds__(256) void offdcn_k(
    const u16* __restrict__ t0,     // [NPIX][32] bf16 ch-last (feat)
    const u16* __restrict__ imgc,   // [NPIX][32] bf16 ch-last
    const u16* __restrict__ wfragO, // [9][14][64][8]
    const u16* __restrict__ wfragD, // [9][2][64][8]
    const float* __restrict__ biasO,// 224
    const float* __restrict__ biasD,// 32
    float* __restrict__ out)        // [4][32][HW] f32
{
    const int tid = threadIdx.x, lane = tid & 63, wv = tid >> 6;
    const int m0 = blockIdx.x * 64;
    const int b = m0 / HWc, hwb = m0 - b * HWc;

    __shared__ uint4 At[2][256];      // 8 KB, time-shared between phases
    __shared__ u16 co_s[224 * 66];    // 29.5 KB, [o][m] with +2 row pad

    // ===== phase 1: offset conv =====
    {
        const int wm = wv >> 1, wn = wv & 1;
        const int rm = wm * 32, cn = wn * 112;

        const int rowl = ((tid >> 6) << 4) | (tid & 15);
        const int kg = (tid >> 4) & 3;
        const int hwp = hwb + rowl;
        const int hh = hwp / Wc, ww = hwp - hh * Wc;

        f32x4 acc[2][7];
#pragma unroll
        for (int mf = 0; mf < 2; ++mf)
#pragma unroll
            for (int nf = 0; nf < 7; ++nf)
                acc[mf][nf] = f32x4{0.f, 0.f, 0.f, 0.f};

        for (int s = 0; s < 9; ++s) {
            const int dy = s / 3 - 1, dx = s - (s / 3) * 3 - 1;
            const int d = dy * Wc + dx;
            bool valid = ((unsigned)(hh + dy) < (unsigned)Hc) &&
                         ((unsigned)(ww + dx) < (unsigned)Wc);
            uint4 v = {0u, 0u, 0u, 0u};
            if (valid)
                v = *(const uint4*)(t0 + ((size_t)(m0 + rowl + d)) * 32 + kg * 8);
            At[s & 1][tid] = v;
            __syncthreads();

            bf16x8 aF0 = __builtin_bit_cast(bf16x8, At[s & 1][(wm * 2 + 0) * 64 + lane]);
            bf16x8 aF1 = __builtin_bit_cast(bf16x8, At[s & 1][(wm * 2 + 1) * 64 + lane]);
#pragma unroll
            for (int nf = 0; nf < 7; ++nf) {
                bf16x8 bF = __builtin_bit_cast(
                    bf16x8,
                    *(const uint4*)(wfragO + (((size_t)s * 14 + wn * 7 + nf) * 64 + lane) * 8));
                acc[0][nf] = __builtin_amdgcn_mfma_f32_16x16x32_bf16(aF0, bF, acc[0][nf], 0, 0, 0);
                acc[1][nf] = __builtin_amdgcn_mfma_f32_16x16x32_bf16(aF1, bF, acc[1][nf], 0, 0, 0);
            }
        }

        // epilogue -> LDS co_s[o][m], sigmoid on mask channels
#pragma unroll
        for (int nf = 0; nf < 7; ++nf) {
            const int o = cn + nf * 16 + (lane & 15);
            const float bs = biasO[o];
            const bool sig = (o >= 144);
#pragma unroll
            for (int mf = 0; mf < 2; ++mf) {
                const int mb = rm + mf * 16 + ((lane >> 4) << 2);
                float v0 = acc[mf][nf][0] + bs, v1 = acc[mf][nf][1] + bs;
                float v2 = acc[mf][nf][2] + bs, v3 = acc[mf][nf][3] + bs;
                if (sig) {
                    v0 = 1.f / (1.f + expf(-v0)); v1 = 1.f / (1.f + expf(-v1));
                    v2 = 1.f / (1.f + expf(-v2)); v3 = 1.f / (1.f + expf(-v3));
                }
                u32 lo = (u32)f2bf(v0) | ((u32)f2bf(v1) << 16);
                u32 hi = (u32)f2bf(v2) | ((u32)f2bf(v3) << 16);
                *(u32*)&co_s[o * 66 + mb]     = lo;
                *(u32*)&co_s[o * 66 + mb + 2] = hi;
            }
        }
        __syncthreads();
    }

    // ===== phase 2: DCN =====
    {
        const int pix = m0 + lane;
        const int hw = pix - b * HWc;
        const int hh = hw / Wc;
        const int wwp = hw - hh * Wc;

        const u16* xb = imgc + (size_t)b * HWc * 32;
        const int slot = ((lane >> 4) << 6) | (wv << 4) | (lane & 15);

        f32x4 acc0 = {0.f, 0.f, 0.f, 0.f};
        f32x4 acc1 = {0.f, 0.f, 0.f, 0.f};

        for (int k = 0; k < 9; ++k) {
            const int kyi = k / 3, kxi = k - kyi * 3;
            u32 pk[4];
#pragma unroll
            for (int dgi = 0; dgi < 2; ++dgi) {
                const int dg = wv * 2 + dgi;
                const int offch = dg * 9 + k;
                float dy = bf2f(co_s[offch * 66 + lane]);
                float dx = bf2f(co_s[(72 + offch) * 66 + lane]);
                float m  = bf2f(co_s[(144 + offch) * 66 + lane]);

                float py = dy + (float)(hh + kyi - 1);
                float px = dx + (float)(wwp + kxi - 1);
                float y0f = floorf(py), x0f = floorf(px);
                float wy = py - y0f, wx = px - x0f;
                int y0 = (int)y0f, x0 = (int)x0f;
                int y1 = y0 + 1, x1 = x0 + 1;

                bool vy0 = (unsigned)y0 < (unsigned)Hc;
                bool vy1 = (unsigned)y1 < (unsigned)Hc;
                bool vx0 = (unsigned)x0 < (unsigned)Wc;
                bool vx1 = (unsigned)x1 < (unsigned)Wc;

                int y0c = min(max(y0, 0), Hc - 1);
                int y1c = min(max(y1, 0), Hc - 1);
                int x0c = min(max(x0, 0), Wc - 1);
                int x1c = min(max(x1, 0), Wc - 1);

                float w00 = (1.f - wy) * (1.f - wx);
                float w01 = (1.f - wy) * wx;
                float w10 = wy * (1.f - wx);
                float w11 = wy * wx;
                if (!(vy0 && vx0)) w00 = 0.f;
                if (!(vy0 && vx1)) w01 = 0.f;
                if (!(vy1 && vx0)) w10 = 0.f;
                if (!(vy1 && vx1)) w11 = 0.f;
                w00 *= m; w01 *= m; w10 *= m; w11 *= m;

                uint2 c00 = *(const uint2*)(xb + (size_t)(y0c * Wc + x0c) * 32 + dg * 4);
                uint2 c01 = *(const uint2*)(xb + (size_t)(y0c * Wc + x1c) * 32 + dg * 4);
                uint2 c10 = *(const uint2*)(xb + (size_t)(y1c * Wc + x0c) * 32 + dg * 4);
                uint2 c11 = *(const uint2*)(xb + (size_t)(y1c * Wc + x1c) * 32 + dg * 4);

                float s[4];
#pragma unroll
                for (int cg = 0; cg < 4; ++cg) {
                    u32 h00 = (cg < 2) ? c00.x : c00.y;
                    u32 h01 = (cg < 2) ? c01.x : c01.y;
                    u32 h10 = (cg < 2) ? c10.x : c10.y;
                    u32 h11 = (cg < 2) ? c11.x : c11.y;
                    int sh = (cg & 1) ? 16 : 0;
                    s[cg] = w00 * bf2f((u16)(h00 >> sh)) + w01 * bf2f((u16)(h01 >> sh))
                          + w10 * bf2f((u16)(h10 >> sh)) + w11 * bf2f((u16)(h11 >> sh));
                }
                pk[dgi * 2 + 0] = (u32)f2bf(s[0]) | ((u32)f2bf(s[1]) << 16);
                pk[dgi * 2 + 1] = (u32)f2bf(s[2]) | ((u32)f2bf(s[3]) << 16);
            }

            const int sel = k & 1;
            At[sel][slot] = uint4{pk[0], pk[1], pk[2], pk[3]};
            __syncthreads();

            bf16x8 aF = __builtin_bit_cast(bf16x8, At[sel][wv * 64 + lane]);
            bf16x8 bF0 = __builtin_bit_cast(bf16x8,
                *(const uint4*)(wfragD + ((size_t)(k * 2 + 0) * 64 + lane) * 8));
            bf16x8 bF1 = __builtin_bit_cast(bf16x8,
                *(const uint4*)(wfragD + ((size_t)(k * 2 + 1) * 64 + lane) * 8));
            acc0 = __builtin_amdgcn_mfma_f32_16x16x32_bf16(aF, bF0, acc0, 0, 0, 0);
            acc1 = __builtin_amdgcn_mfma_f32_16x16x32_bf16(aF, bF1, acc1, 0, 0, 0);
        }

        // epilogue: wave wv owns pixel rows [16wv,16wv+16)
        const int rbase = m0 + wv * 16 + ((lane >> 4) << 2);
        const int hw0 = rbase - b * HWc;
        float* ob = out + (size_t)b * 32 * HWc;
        const int oL = lane & 15;
        const float bs0 = biasD[oL], bs1 = biasD[16 + oL];
#pragma unroll
        for (int r = 0; r < 4; ++r) {
            ob[(size_t)oL * HWc + hw0 + r] = acc0[r] + bs0;
            ob[(size_t)(16 + oL) * HWc + hw0 + r] = acc1[r] + bs1;
        }
    }
}

extern "C" void kernel_launch(void* const* d_in, const int* in_sizes, int n_in,
                              void* d_out, int out_size, void* d_ws, size_t ws_size,
                              hipStream_t stream) {
    const float* img_ref  = (const float*)d_in[0];
    const float* img      = (const float*)d_in[1];
    const float* conv1_w  = (const float*)d_in[2];
    const float* conv1_b  = (const float*)d_in[3];
    const float* conv2a_w = (const float*)d_in[4];
    const float* conv2a_b = (const float*)d_in[5];
    const float* conv2b_w = (const float*)d_in[6];
    const float* conv2b_b = (const float*)d_in[7];
    const float* off_w    = (const float*)d_in[8];
    const float* off_b    = (const float*)d_in[9];
    const float* dcn_w    = (const float*)d_in[10];
    const float* dcn_b    = (const float*)d_in[11];

    float* wsf = (float*)d_ws;
    u16* frag = (u16*)((char*)d_ws + FRAG_BYTE);
    u16* t0   = (u16*)((char*)d_ws + T0_BYTE);
    u16* t1   = (u16*)((char*)d_ws + T1_BYTE);
    u16* imgc = (u16*)((char*)d_ws + IMG_BYTE);
    float* out = (float*)d_out;

    prep_k<<<370, 256, 0, stream>>>(conv1_w, conv1_b, conv2a_w, conv2a_b,
                                    conv2b_w, conv2b_b, off_w, off_b,
                                    dcn_w, dcn_b, wsf, frag);

    // conv1x1: [NPIX x 64] @ [64 x 32] -> t0 (ch-last); also dumps img as bf16 ch-last
    conv_mfma_k<4, 1, 2, 2, 32, 2, 2, 0, true, true>
        <<<NPIX / 128, 256, 0, stream>>>(img_ref, img, frag + FR1_U, wsf + WF_B1, t0, imgc);

    // conv2a: t0 -> t1
    conv_mfma_k<4, 1, 2, 2, 32, 2, 9, 1, true, false>
        <<<NPIX / 128, 256, 0, stream>>>(t0, nullptr, frag + FRA_U, wsf + WF_B2A, t1, nullptr);

    // conv2b: t1 -> t0
    conv_mfma_k<4, 1, 2, 2, 32, 2, 9, 1, true, false>
        <<<NPIX / 128, 256, 0, stream>>>(t1, nullptr, frag + FRB_U, wsf + WF_B2B, t0, nullptr);

    // fused offset conv + DCN
    offdcn_k<<<NPIX / 64, 256, 0, stream>>>(t0, imgc, frag + FRO_U, frag + FRD_U,
                                            wsf + WF_BO, wsf + WF_BD, out);
}

// Round 8
// 144.851 us; speedup vs baseline: 4.4049x; 1.0389x over previous
//
#include <hip/hip_runtime.h>

#define Hc   192
#define Wc   192
#define HWc  (Hc * Wc)          // 36864
#define NPIX (4 * HWc)          // 147456

typedef float f32x4 __attribute__((ext_vector_type(4)));
typedef __bf16 bf16x8 __attribute__((ext_vector_type(8)));
typedef unsigned short u16;
typedef unsigned int u32;

// ---- workspace layout ----
// f32 region (element offsets):
#define WF_BO    0      // 224 (offset-conv bias, padded 216->224)
#define WF_B1    224
#define WF_B2A   256
#define WF_B2B   288
#define WF_BD    320    // end 352 floats = 1408 B
// bf16 fragment region (u16 offsets from FRAG_BYTE):
#define FR1_U    0      // conv1   [2][2][64][8]   2048
#define FRA_U    2048   // conv2a  [9][2][64][8]   9216
#define FRB_U    11264  // conv2b  [9][2][64][8]   9216
#define FRO_U    20480  // offset  [9][14][64][8]  64512
#define FRD_U    84992  // dcn     [9][2][64][8]   9216  (K-within-32 = dg*4+cg)
#define FRAG_U_TOT 94208
#define FRAG_BYTE 1408
// buffers (byte offsets):
#define T0_BYTE  (FRAG_BYTE + FRAG_U_TOT * 2)        // [NPIX][32] bf16 ch-last
#define T1_BYTE  (T0_BYTE + NPIX * 32 * 2)
#define IMG_BYTE (T1_BYTE + NPIX * 32 * 2)           // [NPIX][32] bf16 ch-last copy of img

__device__ __forceinline__ u16 f2bf(float f) {
    u32 u = __float_as_uint(f);
    u32 r = u + 0x7fffu + ((u >> 16) & 1u);
    return (u16)(r >> 16);
}
__device__ __forceinline__ float bf2f(u16 v) {
    return __uint_as_float(((u32)v) << 16);
}

// ---------------- prep: biases (f32) + MFMA weight fragments (bf16) ----------------
__global__ __launch_bounds__(256) void prep_k(
    const float* __restrict__ w1,  const float* __restrict__ b1,
    const float* __restrict__ w2a, const float* __restrict__ b2a,
    const float* __restrict__ w2b, const float* __restrict__ b2b,
    const float* __restrict__ wo,  const float* __restrict__ bo,
    const float* __restrict__ wd,  const float* __restrict__ bd,
    float* __restrict__ wsf, u16* __restrict__ frag)
{
    int i = blockIdx.x * 256 + threadIdx.x;
    if (i < 224)      { wsf[WF_BO + i]  = (i < 216) ? bo[i] : 0.f; return; }
    if (i < 256)      { wsf[WF_B1  + i - 224] = b1[i - 224];  return; }
    if (i < 288)      { wsf[WF_B2A + i - 256] = b2a[i - 256]; return; }
    if (i < 320)      { wsf[WF_B2B + i - 288] = b2b[i - 288]; return; }
    if (i < 352)      { wsf[WF_BD  + i - 320] = bd[i - 320];  return; }
    int fi = i - 352;
    if (fi < 2048) {          // conv1 frags: [s][nt][l][j], ci = s*32 + (l>>4)*8 + j
        int s = fi >> 10, l = (fi >> 3) & 63, j = fi & 7;
        int nt = (fi >> 9) & 1;
        int o = nt * 16 + (l & 15);
        int ci = s * 32 + ((l >> 4) << 3) + j;
        frag[FR1_U + fi] = f2bf(w1[o * 64 + ci]);
        return;
    }
    fi -= 2048;
    if (fi < 9216) {          // conv2a frags: tap = s, ci = (l>>4)*8+j
        int s = fi / 1024, r = fi - s * 1024;
        int nt = r >> 9, l = (r >> 3) & 63, j = r & 7;
        int o = nt * 16 + (l & 15);
        int ci = ((l >> 4) << 3) + j;
        frag[FRA_U + fi] = f2bf(w2a[(o * 32 + ci) * 9 + s]);
        return;
    }
    fi -= 9216;
    if (fi < 9216) {          // conv2b frags
        int s = fi / 1024, r = fi - s * 1024;
        int nt = r >> 9, l = (r >> 3) & 63, j = r & 7;
        int o = nt * 16 + (l & 15);
        int ci = ((l >> 4) << 3) + j;
        frag[FRB_U + fi] = f2bf(w2b[(o * 32 + ci) * 9 + s]);
        return;
    }
    fi -= 9216;
    if (fi < 64512) {         // offset-conv frags, COUT padded to 224
        int s = fi / 7168, r = fi - s * 7168;
        int nt = r >> 9, l = (r >> 3) & 63, j = r & 7;
        int o = nt * 16 + (l & 15);
        int ci = ((l >> 4) << 3) + j;
        frag[FRO_U + fi] = f2bf((o < 216) ? wo[(o * 32 + ci) * 9 + s] : 0.f);
        return;
    }
    fi -= 64512;
    if (fi < 9216) {          // dcn frags: [k][nt][l][j], K-within = (l>>4)*8+j = ci = dg*4+cg
        int k = fi / 1024, r = fi - k * 1024;
        int nt = r >> 9, l = (r >> 3) & 63, j = r & 7;
        int o = nt * 16 + (l & 15);
        int ci = ((l >> 4) << 3) + j;
        frag[FRD_U + fi] = f2bf(wd[o * 288 + ci * 9 + k]);
        return;
    }
}

// ---------------- implicit-GEMM conv via MFMA (small convs) ----------------
// MODE 0: 1x1 conv, K=64 from two f32 ch-major sources (s==0 -> s0, s==1 -> s1)
// MODE 1: 3x3 conv pad 1, CIN=32, bf16 ch-last source [NPIX][32]
// Output: ch-last bf16 [NPIX][32]
// DUMP: in MODE 0, also write the s==1 (img) bf16 ch-last tile to `dump`.
template <int WM, int WN, int MF, int NF, int COUT, int NTILES, int KS, int MODE, bool CHL, bool DUMP>
__global__ __launch_bounds__(256) void conv_mfma_k(
    const void* __restrict__ s0v, const void* __restrict__ s1v,
    const u16* __restrict__ wfrag, const float* __restrict__ bias,
    u16* __restrict__ y, u16* __restrict__ dump)
{
    constexpr int M_BLK = WM * MF * 16;
    constexpr int ITERS = M_BLK / 64;
    const int tid = threadIdx.x, lane = tid & 63, wv = tid >> 6;
    const int wm = wv / WN, wn = wv % WN;
    const int m0 = blockIdx.x * M_BLK;
    const int b = m0 / HWc, hwb = m0 - b * HWc;
    const int rm = wm * MF * 16, cn = wn * NF * 16;

    __shared__ uint4 At4[M_BLK * 4];

    int pxA[ITERS], hA[ITERS], wA[ITERS], kgA[ITERS];
#pragma unroll
    for (int it = 0; it < ITERS; ++it) {
        int st = it * 256 + tid;
        int rowl = ((st >> 6) << 4) | (st & 15);
        kgA[it] = (st >> 4) & 3;
        pxA[it] = rowl;
        int hwp = hwb + rowl;
        hA[it] = hwp / Wc;
        wA[it] = hwp - hA[it] * Wc;
    }

    f32x4 acc[MF][NF];
#pragma unroll
    for (int mf = 0; mf < MF; ++mf)
#pragma unroll
        for (int nf = 0; nf < NF; ++nf)
            acc[mf][nf] = f32x4{0.f, 0.f, 0.f, 0.f};

    const u16* srcB = (const u16*)s0v;
    const float* f0 = (const float*)s0v;
    const float* f1 = (const float*)s1v;

    for (int s = 0; s < KS; ++s) {
        // ---- stage A tile ----
        if (MODE == 1) {
            int dy = s / 3 - 1, dx = s - (s / 3) * 3 - 1;
            int d = dy * Wc + dx;
#pragma unroll
            for (int it = 0; it < ITERS; ++it) {
                bool valid = ((unsigned)(hA[it] + dy) < (unsigned)Hc) &&
                             ((unsigned)(wA[it] + dx) < (unsigned)Wc);
                uint4 v = {0u, 0u, 0u, 0u};
                if (valid)
                    v = *(const uint4*)(srcB + ((size_t)(m0 + pxA[it] + d)) * 32 + kgA[it] * 8);
                At4[it * 256 + tid] = v;
            }
        } else {
            const float* fs = (s == 0) ? f0 : f1;
#pragma unroll
            for (int it = 0; it < ITERS; ++it) {
                const float* pl = fs + ((size_t)b * 32 + kgA[it] * 8) * HWc + (hwb + pxA[it]);
                u32 p0, p1, p2, p3;
                {
                    u32 a0 = f2bf(pl[0 * HWc]), a1 = f2bf(pl[1 * HWc]);
                    u32 a2 = f2bf(pl[2 * HWc]), a3 = f2bf(pl[3 * HWc]);
                    u32 a4 = f2bf(pl[4 * HWc]), a5 = f2bf(pl[5 * HWc]);
                    u32 a6 = f2bf(pl[6 * HWc]), a7 = f2bf(pl[7 * HWc]);
                    p0 = a0 | (a1 << 16); p1 = a2 | (a3 << 16);
                    p2 = a4 | (a5 << 16); p3 = a6 | (a7 << 16);
                }
                uint4 v = {p0, p1, p2, p3};
                if (DUMP && s == 1)
                    *(uint4*)(dump + ((size_t)(m0 + pxA[it])) * 32 + kgA[it] * 8) = v;
                At4[it * 256 + tid] = v;
            }
        }
        __syncthreads();

        // ---- fragments + MFMA ----
        bf16x8 aF[MF];
#pragma unroll
        for (int mf = 0; mf < MF; ++mf)
            aF[mf] = __builtin_bit_cast(bf16x8, At4[((rm >> 4) + mf) * 64 + lane]);
#pragma unroll
        for (int nf = 0; nf < NF; ++nf) {
            bf16x8 bF = __builtin_bit_cast(
                bf16x8,
                *(const uint4*)(wfrag + (((size_t)s * NTILES + wn * NF + nf) * 64 + lane) * 8));
#pragma unroll
            for (int mf = 0; mf < MF; ++mf)
                acc[mf][nf] = __builtin_amdgcn_mfma_f32_16x16x32_bf16(aF[mf], bF, acc[mf][nf], 0, 0, 0);
        }
        __syncthreads();
    }

    // ---- epilogue: bias + store ch-last ----
#pragma unroll
    for (int nf = 0; nf < NF; ++nf) {
        int o = cn + nf * 16 + (lane & 15);
        float bs = bias[o];
#pragma unroll
        for (int mf = 0; mf < MF; ++mf) {
#pragma unroll
            for (int r = 0; r < 4; ++r) {
                int m = m0 + rm + mf * 16 + ((lane >> 4) << 2) + r;
                float val = acc[mf][nf][r] + bs;
                y[(size_t)m * COUT + o] = f2bf(val);
            }
        }
    }
}

// ---------------- FUSED: offset conv (216ch -> LDS) + modulated deformable conv ----------------
// Block: 4 waves, 64 pixels.
// Phase 1: implicit-GEMM offset conv (9 taps, 2x2 waves, MF=2/NF=7) -> co_s[224][66] bf16 in LDS
//          (sigmoid fused on ch>=144). 1 barrier/tap via double-buffered A staging.
// Phase 2: DCNv2, barrier-free. Wave wv owns pixels wv*16+(0..15); lane l serves
//          pixel (l&15) with dg pair {2(l>>4), 2(l>>4)+1}. The 8 sampled values per
//          tap (K-slot = dg*4+cg = (l>>4)*8 + 4*dgi+cg) form the lane's A-fragment
//          directly in registers -> no LDS staging, no per-tap barrier, taps pipeline.
__global__ __launch_bounds__(256, 4) void offdcn_k(
    const u16* __restrict__ t0,     // [NPIX][32] bf16 ch-last (feat)
    const u16* __restrict__ imgc,   // [NPIX][32] bf16 ch-last
    const u16* __restrict__ wfragO, // [9][14][64][8]
    const u16* __restrict__ wfragD, // [9][2][64][8]
    const float* __restrict__ biasO,// 224
    const float* __restrict__ biasD,// 32
    float* __restrict__ out)        // [4][32][HW] f32
{
    const int tid = threadIdx.x, lane = tid & 63, wv = tid >> 6;
    const int m0 = blockIdx.x * 64;
    const int b = m0 / HWc, hwb = m0 - b * HWc;

    __shared__ uint4 At[2][256];      // 8 KB (phase-1 staging dbuf)
    __shared__ u16 co_s[224 * 66];    // 29.5 KB, [o][m] with +2 row pad

    // ===== phase 1: offset conv =====
    {
        const int wm = wv >> 1, wn = wv & 1;
        const int rm = wm * 32, cn = wn * 112;

        const int rowl = ((tid >> 6) << 4) | (tid & 15);
        const int kg = (tid >> 4) & 3;
        const int hwp = hwb + rowl;
        const int hh = hwp / Wc, ww = hwp - hh * Wc;

        f32x4 acc[2][7];
#pragma unroll
        for (int mf = 0; mf < 2; ++mf)
#pragma unroll
            for (int nf = 0; nf < 7; ++nf)
                acc[mf][nf] = f32x4{0.f, 0.f, 0.f, 0.f};

        for (int s = 0; s < 9; ++s) {
            const int dy = s / 3 - 1, dx = s - (s / 3) * 3 - 1;
            const int d = dy * Wc + dx;
            bool valid = ((unsigned)(hh + dy) < (unsigned)Hc) &&
                         ((unsigned)(ww + dx) < (unsigned)Wc);
            uint4 v = {0u, 0u, 0u, 0u};
            if (valid)
                v = *(const uint4*)(t0 + ((size_t)(m0 + rowl + d)) * 32 + kg * 8);
            At[s & 1][tid] = v;
            __syncthreads();

            bf16x8 aF0 = __builtin_bit_cast(bf16x8, At[s & 1][(wm * 2 + 0) * 64 + lane]);
            bf16x8 aF1 = __builtin_bit_cast(bf16x8, At[s & 1][(wm * 2 + 1) * 64 + lane]);
#pragma unroll
            for (int nf = 0; nf < 7; ++nf) {
                bf16x8 bF = __builtin_bit_cast(
                    bf16x8,
                    *(const uint4*)(wfragO + (((size_t)s * 14 + wn * 7 + nf) * 64 + lane) * 8));
                acc[0][nf] = __builtin_amdgcn_mfma_f32_16x16x32_bf16(aF0, bF, acc[0][nf], 0, 0, 0);
                acc[1][nf] = __builtin_amdgcn_mfma_f32_16x16x32_bf16(aF1, bF, acc[1][nf], 0, 0, 0);
            }
        }

        // epilogue -> LDS co_s[o][m], sigmoid on mask channels
#pragma unroll
        for (int nf = 0; nf < 7; ++nf) {
            const int o = cn + nf * 16 + (lane & 15);
            const float bs = biasO[o];
            const bool sig = (o >= 144);
#pragma unroll
            for (int mf = 0; mf < 2; ++mf) {
                const int mb = rm + mf * 16 + ((lane >> 4) << 2);
                float v0 = acc[mf][nf][0] + bs, v1 = acc[mf][nf][1] + bs;
                float v2 = acc[mf][nf][2] + bs, v3 = acc[mf][nf][3] + bs;
                if (sig) {
                    v0 = 1.f / (1.f + expf(-v0)); v1 = 1.f / (1.f + expf(-v1));
                    v2 = 1.f / (1.f + expf(-v2)); v3 = 1.f / (1.f + expf(-v3));
                }
                u32 lo = (u32)f2bf(v0) | ((u32)f2bf(v1) << 16);
                u32 hi = (u32)f2bf(v2) | ((u32)f2bf(v3) << 16);
                *(u32*)&co_s[o * 66 + mb]     = lo;
                *(u32*)&co_s[o * 66 + mb + 2] = hi;
            }
        }
        __syncthreads();
    }

    // ===== phase 2: DCN (barrier-free, in-register A-fragments) =====
    {
        const int kg = lane >> 4;          // dg pair {2kg, 2kg+1}
        const int pixb = wv * 16 + (lane & 15);   // pixel within block
        const int hw = hwb + pixb;
        const int hh = hw / Wc;
        const int wwp = hw - hh * Wc;

        const u16* xb = imgc + (size_t)b * HWc * 32;

        f32x4 acc0 = {0.f, 0.f, 0.f, 0.f};
        f32x4 acc1 = {0.f, 0.f, 0.f, 0.f};

#pragma unroll
        for (int k = 0; k < 9; ++k) {
            const int kyi = k / 3, kxi = k - kyi * 3;
            u32 pk[4];
#pragma unroll
            for (int dgi = 0; dgi < 2; ++dgi) {
                const int dg = 2 * kg + dgi;
                const int offch = dg * 9 + k;
                float dy = bf2f(co_s[offch * 66 + pixb]);
                float dx = bf2f(co_s[(72 + offch) * 66 + pixb]);
                float m  = bf2f(co_s[(144 + offch) * 66 + pixb]);

                float py = dy + (float)(hh + kyi - 1);
                float px = dx + (float)(wwp + kxi - 1);
                float y0f = floorf(py), x0f = floorf(px);
                float wy = py - y0f, wx = px - x0f;
                int y0 = (int)y0f, x0 = (int)x0f;
                int y1 = y0 + 1, x1 = x0 + 1;

                bool vy0 = (unsigned)y0 < (unsigned)Hc;
                bool vy1 = (unsigned)y1 < (unsigned)Hc;
                bool vx0 = (unsigned)x0 < (unsigned)Wc;
                bool vx1 = (unsigned)x1 < (unsigned)Wc;

                int y0c = min(max(y0, 0), Hc - 1);
                int y1c = min(max(y1, 0), Hc - 1);
                int x0c = min(max(x0, 0), Wc - 1);
                int x1c = min(max(x1, 0), Wc - 1);

                float w00 = (1.f - wy) * (1.f - wx);
                float w01 = (1.f - wy) * wx;
                float w10 = wy * (1.f - wx);
                float w11 = wy * wx;
                if (!(vy0 && vx0)) w00 = 0.f;
                if (!(vy0 && vx1)) w01 = 0.f;
                if (!(vy1 && vx0)) w10 = 0.f;
                if (!(vy1 && vx1)) w11 = 0.f;
                w00 *= m; w01 *= m; w10 *= m; w11 *= m;

                uint2 c00 = *(const uint2*)(xb + (size_t)(y0c * Wc + x0c) * 32 + dg * 4);
                uint2 c01 = *(const uint2*)(xb + (size_t)(y0c * Wc + x1c) * 32 + dg * 4);
                uint2 c10 = *(const uint2*)(xb + (size_t)(y1c * Wc + x0c) * 32 + dg * 4);
                uint2 c11 = *(const uint2*)(xb + (size_t)(y1c * Wc + x1c) * 32 + dg * 4);

                float s[4];
#pragma unroll
                for (int cg = 0; cg < 4; ++cg) {
                    u32 h00 = (cg < 2) ? c00.x : c00.y;
                    u32 h01 = (cg < 2) ? c01.x : c01.y;
                    u32 h10 = (cg < 2) ? c10.x : c10.y;
                    u32 h11 = (cg < 2) ? c11.x : c11.y;
                    int sh = (cg & 1) ? 16 : 0;
                    s[cg] = w00 * bf2f((u16)(h00 >> sh)) + w01 * bf2f((u16)(h01 >> sh))
                          + w10 * bf2f((u16)(h10 >> sh)) + w11 * bf2f((u16)(h11 >> sh));
                }
                pk[dgi * 2 + 0] = (u32)f2bf(s[0]) | ((u32)f2bf(s[1]) << 16);
                pk[dgi * 2 + 1] = (u32)f2bf(s[2]) | ((u32)f2bf(s[3]) << 16);
            }

            bf16x8 aF = __builtin_bit_cast(bf16x8, uint4{pk[0], pk[1], pk[2], pk[3]});
            bf16x8 bF0 = __builtin_bit_cast(bf16x8,
                *(const uint4*)(wfragD + ((size_t)(k * 2 + 0) * 64 + lane) * 8));
            bf16x8 bF1 = __builtin_bit_cast(bf16x8,
                *(const uint4*)(wfragD + ((size_t)(k * 2 + 1) * 64 + lane) * 8));
            acc0 = __builtin_amdgcn_mfma_f32_16x16x32_bf16(aF, bF0, acc0, 0, 0, 0);
            acc1 = __builtin_amdgcn_mfma_f32_16x16x32_bf16(aF, bF1, acc1, 0, 0, 0);
        }

        // epilogue: wave wv owns pixel rows [16wv,16wv+16); C row = (lane>>4)*4+r
        const int rbase = m0 + wv * 16 + ((lane >> 4) << 2);
        const int hw0 = rbase - b * HWc;
        float* ob = out + (size_t)b * 32 * HWc;
        const int oL = lane & 15;
        const float bs0 = biasD[oL], bs1 = biasD[16 + oL];
#pragma unroll
        for (int r = 0; r < 4; ++r) {
            ob[(size_t)oL * HWc + hw0 + r] = acc0[r] + bs0;
            ob[(size_t)(16 + oL) * HWc + hw0 + r] = acc1[r] + bs1;
        }
    }
}

extern "C" void kernel_launch(void* const* d_in, const int* in_sizes, int n_in,
                              void* d_out, int out_size, void* d_ws, size_t ws_size,
                              hipStream_t stream) {
    const float* img_ref  = (const float*)d_in[0];
    const float* img      = (const float*)d_in[1];
    const float* conv1_w  = (const float*)d_in[2];
    const float* conv1_b  = (const float*)d_in[3];
    const float* conv2a_w = (const float*)d_in[4];
    const float* conv2a_b = (const float*)d_in[5];
    const float* conv2b_w = (const float*)d_in[6];
    const float* conv2b_b = (const float*)d_in[7];
    const float* off_w    = (const float*)d_in[8];
    const float* off_b    = (const float*)d_in[9];
    const float* dcn_w    = (const float*)d_in[10];
    const float* dcn_b    = (const float*)d_in[11];

    float* wsf = (float*)d_ws;
    u16* frag = (u16*)((char*)d_ws + FRAG_BYTE);
    u16* t0   = (u16*)((char*)d_ws + T0_BYTE);
    u16* t1   = (u16*)((char*)d_ws + T1_BYTE);
    u16* imgc = (u16*)((char*)d_ws + IMG_BYTE);
    float* out = (float*)d_out;

    prep_k<<<370, 256, 0, stream>>>(conv1_w, conv1_b, conv2a_w, conv2a_b,
                                    conv2b_w, conv2b_b, off_w, off_b,
                                    dcn_w, dcn_b, wsf, frag);

    // conv1x1: [NPIX x 64] @ [64 x 32] -> t0 (ch-last); also dumps img as bf16 ch-last
    conv_mfma_k<4, 1, 2, 2, 32, 2, 2, 0, true, true>
        <<<NPIX / 128, 256, 0, stream>>>(img_ref, img, frag + FR1_U, wsf + WF_B1, t0, imgc);

    // conv2a: t0 -> t1
    conv_mfma_k<4, 1, 2, 2, 32, 2, 9, 1, true, false>
        <<<NPIX / 128, 256, 0, stream>>>(t0, nullptr, frag + FRA_U, wsf + WF_B2A, t1, nullptr);

    // conv2b: t1 -> t0
    conv_mfma_k<4, 1, 2, 2, 32, 2, 9, 1, true, false>
        <<<NPIX / 128, 256, 0, stream>>>(t1, nullptr, frag + FRB_U, wsf + WF_B2B, t0, nullptr);

    // fused offset conv + DCN
    offdcn_k<<<NPIX / 64, 256, 0, stream>>>(t0, imgc, frag + FRO_U, frag + FRD_U,
                                            wsf + WF_BO, wsf + WF_BD, out);
}

// Round 9
// 130.642 us; speedup vs baseline: 4.8839x; 1.1088x over previous
//
#include <hip/hip_runtime.h>

#define Hc   192
#define Wc   192
#define HWc  (Hc * Wc)          // 36864
#define NPIX (4 * HWc)          // 147456

typedef float f32x4 __attribute__((ext_vector_type(4)));
typedef __bf16 bf16x8 __attribute__((ext_vector_type(8)));
typedef unsigned short u16;
typedef unsigned int u32;

// ---- workspace layout ----
// f32 region (element offsets):
#define WF_BO    0      // 224 (offset-conv bias, padded 216->224)
#define WF_B1    224
#define WF_B2A   256
#define WF_B2B   288
#define WF_BD    320    // end 352 floats = 1408 B
// bf16 fragment region (u16 offsets from FRAG_BYTE):
#define FR1_U    0      // conv1   [2][2][64][8]   2048
#define FRA_U    2048   // conv2a  [9][2][64][8]   9216
#define FRB_U    11264  // conv2b  [9][2][64][8]   9216
#define FRO_U    20480  // offset  [9][14][64][8]  64512
#define FRD_U    84992  // dcn     [9][2][64][8]   9216  (K-within-32 = dg*4+cg)
#define FRAG_U_TOT 94208
#define FRAG_BYTE 1408
// buffers (byte offsets):
#define T0_BYTE  (FRAG_BYTE + FRAG_U_TOT * 2)        // [NPIX][32] bf16 ch-last
#define T1_BYTE  (T0_BYTE + NPIX * 32 * 2)
#define IMG_BYTE (T1_BYTE + NPIX * 32 * 2)           // [4][8][HW][4] bf16 dg-planar img

__device__ __forceinline__ u16 f2bf(float f) {
    u32 u = __float_as_uint(f);
    u32 r = u + 0x7fffu + ((u >> 16) & 1u);
    return (u16)(r >> 16);
}
__device__ __forceinline__ float bf2f(u16 v) {
    return __uint_as_float(((u32)v) << 16);
}

// ---------------- prep: biases (f32) + MFMA weight fragments (bf16) ----------------
__global__ __launch_bounds__(256) void prep_k(
    const float* __restrict__ w1,  const float* __restrict__ b1,
    const float* __restrict__ w2a, const float* __restrict__ b2a,
    const float* __restrict__ w2b, const float* __restrict__ b2b,
    const float* __restrict__ wo,  const float* __restrict__ bo,
    const float* __restrict__ wd,  const float* __restrict__ bd,
    float* __restrict__ wsf, u16* __restrict__ frag)
{
    int i = blockIdx.x * 256 + threadIdx.x;
    if (i < 224)      { wsf[WF_BO + i]  = (i < 216) ? bo[i] : 0.f; return; }
    if (i < 256)      { wsf[WF_B1  + i - 224] = b1[i - 224];  return; }
    if (i < 288)      { wsf[WF_B2A + i - 256] = b2a[i - 256]; return; }
    if (i < 320)      { wsf[WF_B2B + i - 288] = b2b[i - 288]; return; }
    if (i < 352)      { wsf[WF_BD  + i - 320] = bd[i - 320];  return; }
    int fi = i - 352;
    if (fi < 2048) {          // conv1 frags: [s][nt][l][j], ci = s*32 + (l>>4)*8 + j
        int s = fi >> 10, l = (fi >> 3) & 63, j = fi & 7;
        int nt = (fi >> 9) & 1;
        int o = nt * 16 + (l & 15);
        int ci = s * 32 + ((l >> 4) << 3) + j;
        frag[FR1_U + fi] = f2bf(w1[o * 64 + ci]);
        return;
    }
    fi -= 2048;
    if (fi < 9216) {          // conv2a frags: tap = s, ci = (l>>4)*8+j
        int s = fi / 1024, r = fi - s * 1024;
        int nt = r >> 9, l = (r >> 3) & 63, j = r & 7;
        int o = nt * 16 + (l & 15);
        int ci = ((l >> 4) << 3) + j;
        frag[FRA_U + fi] = f2bf(w2a[(o * 32 + ci) * 9 + s]);
        return;
    }
    fi -= 9216;
    if (fi < 9216) {          // conv2b frags
        int s = fi / 1024, r = fi - s * 1024;
        int nt = r >> 9, l = (r >> 3) & 63, j = r & 7;
        int o = nt * 16 + (l & 15);
        int ci = ((l >> 4) << 3) + j;
        frag[FRB_U + fi] = f2bf(w2b[(o * 32 + ci) * 9 + s]);
        return;
    }
    fi -= 9216;
    if (fi < 64512) {         // offset-conv frags, COUT padded to 224
        int s = fi / 7168, r = fi - s * 7168;
        int nt = r >> 9, l = (r >> 3) & 63, j = r & 7;
        int o = nt * 16 + (l & 15);
        int ci = ((l >> 4) << 3) + j;
        frag[FRO_U + fi] = f2bf((o < 216) ? wo[(o * 32 + ci) * 9 + s] : 0.f);
        return;
    }
    fi -= 64512;
    if (fi < 9216) {          // dcn frags: [k][nt][l][j], K-within = (l>>4)*8+j = ci = dg*4+cg
        int k = fi / 1024, r = fi - k * 1024;
        int nt = r >> 9, l = (r >> 3) & 63, j = r & 7;
        int o = nt * 16 + (l & 15);
        int ci = ((l >> 4) << 3) + j;
        frag[FRD_U + fi] = f2bf(wd[o * 288 + ci * 9 + k]);
        return;
    }
}

// ---------------- implicit-GEMM conv via MFMA (small convs) ----------------
// MODE 0: 1x1 conv, K=64 from two f32 ch-major sources (s==0 -> s0, s==1 -> s1)
// MODE 1: 3x3 conv pad 1, CIN=32, bf16 ch-last source [NPIX][32]
// Output: ch-last bf16 [NPIX][32]
// DUMP: in MODE 0, also write the s==1 (img) tile to `dump` in dg-planar [b][8][HW][4] form.
template <int WM, int WN, int MF, int NF, int COUT, int NTILES, int KS, int MODE, bool CHL, bool DUMP>
__global__ __launch_bounds__(256) void conv_mfma_k(
    const void* __restrict__ s0v, const void* __restrict__ s1v,
    const u16* __restrict__ wfrag, const float* __restrict__ bias,
    u16* __restrict__ y, u16* __restrict__ dump)
{
    constexpr int M_BLK = WM * MF * 16;
    constexpr int ITERS = M_BLK / 64;
    const int tid = threadIdx.x, lane = tid & 63, wv = tid >> 6;
    const int wm = wv / WN, wn = wv % WN;
    const int m0 = blockIdx.x * M_BLK;
    const int b = m0 / HWc, hwb = m0 - b * HWc;
    const int rm = wm * MF * 16, cn = wn * NF * 16;

    __shared__ uint4 At4[M_BLK * 4];

    int pxA[ITERS], hA[ITERS], wA[ITERS], kgA[ITERS];
#pragma unroll
    for (int it = 0; it < ITERS; ++it) {
        int st = it * 256 + tid;
        int rowl = ((st >> 6) << 4) | (st & 15);
        kgA[it] = (st >> 4) & 3;
        pxA[it] = rowl;
        int hwp = hwb + rowl;
        hA[it] = hwp / Wc;
        wA[it] = hwp - hA[it] * Wc;
    }

    f32x4 acc[MF][NF];
#pragma unroll
    for (int mf = 0; mf < MF; ++mf)
#pragma unroll
        for (int nf = 0; nf < NF; ++nf)
            acc[mf][nf] = f32x4{0.f, 0.f, 0.f, 0.f};

    const u16* srcB = (const u16*)s0v;
    const float* f0 = (const float*)s0v;
    const float* f1 = (const float*)s1v;

    for (int s = 0; s < KS; ++s) {
        // ---- stage A tile ----
        if (MODE == 1) {
            int dy = s / 3 - 1, dx = s - (s / 3) * 3 - 1;
            int d = dy * Wc + dx;
#pragma unroll
            for (int it = 0; it < ITERS; ++it) {
                bool valid = ((unsigned)(hA[it] + dy) < (unsigned)Hc) &&
                             ((unsigned)(wA[it] + dx) < (unsigned)Wc);
                uint4 v = {0u, 0u, 0u, 0u};
                if (valid)
                    v = *(const uint4*)(srcB + ((size_t)(m0 + pxA[it] + d)) * 32 + kgA[it] * 8);
                At4[it * 256 + tid] = v;
            }
        } else {
            const float* fs = (s == 0) ? f0 : f1;
#pragma unroll
            for (int it = 0; it < ITERS; ++it) {
                const float* pl = fs + ((size_t)b * 32 + kgA[it] * 8) * HWc + (hwb + pxA[it]);
                u32 p0, p1, p2, p3;
                {
                    u32 a0 = f2bf(pl[0 * HWc]), a1 = f2bf(pl[1 * HWc]);
                    u32 a2 = f2bf(pl[2 * HWc]), a3 = f2bf(pl[3 * HWc]);
                    u32 a4 = f2bf(pl[4 * HWc]), a5 = f2bf(pl[5 * HWc]);
                    u32 a6 = f2bf(pl[6 * HWc]), a7 = f2bf(pl[7 * HWc]);
                    p0 = a0 | (a1 << 16); p1 = a2 | (a3 << 16);
                    p2 = a4 | (a5 << 16); p3 = a6 | (a7 << 16);
                }
                uint4 v = {p0, p1, p2, p3};
                if (DUMP && s == 1) {
                    // dg-planar: ch kg*8..kg*8+3 -> plane 2kg; kg*8+4..7 -> plane 2kg+1
                    size_t base = ((size_t)(b * 8 + kgA[it] * 2) * HWc + (hwb + pxA[it])) * 4;
                    *(uint2*)(dump + base) = uint2{p0, p1};
                    *(uint2*)(dump + base + (size_t)HWc * 4) = uint2{p2, p3};
                }
                At4[it * 256 + tid] = v;
            }
        }
        __syncthreads();

        // ---- fragments + MFMA ----
        bf16x8 aF[MF];
#pragma unroll
        for (int mf = 0; mf < MF; ++mf)
            aF[mf] = __builtin_bit_cast(bf16x8, At4[((rm >> 4) + mf) * 64 + lane]);
#pragma unroll
        for (int nf = 0; nf < NF; ++nf) {
            bf16x8 bF = __builtin_bit_cast(
                bf16x8,
                *(const uint4*)(wfrag + (((size_t)s * NTILES + wn * NF + nf) * 64 + lane) * 8));
#pragma unroll
            for (int mf = 0; mf < MF; ++mf)
                acc[mf][nf] = __builtin_amdgcn_mfma_f32_16x16x32_bf16(aF[mf], bF, acc[mf][nf], 0, 0, 0);
        }
        __syncthreads();
    }

    // ---- epilogue: bias + store ch-last ----
#pragma unroll
    for (int nf = 0; nf < NF; ++nf) {
        int o = cn + nf * 16 + (lane & 15);
        float bs = bias[o];
#pragma unroll
        for (int mf = 0; mf < MF; ++mf) {
#pragma unroll
            for (int r = 0; r < 4; ++r) {
                int m = m0 + rm + mf * 16 + ((lane >> 4) << 2) + r;
                float val = acc[mf][nf][r] + bs;
                y[(size_t)m * COUT + o] = f2bf(val);
            }
        }
    }
}

// ---------------- FUSED: offset conv + modulated deformable conv ----------------
// Block: 4 waves, 64 pixels (one 64-wide row segment; 192%64==0 so no row spans).
// Stage 0: halo of t0 (3 rows x 66 px x 32ch = 12.7KB) -> LDS xt, ONE barrier.
// Phase 1: offset conv, 9 taps of pure ds_read_b128 + MFMA, NO per-tap barriers.
// Phase 1b: epilogue writes co_s[224][66] (re-using xt's LDS, barrier-fenced).
// Phase 2: DCNv2, barrier-free in-register A-fragments; gathers from dg-planar img.
__global__ __launch_bounds__(256, 5) void offdcn_k(
    const u16* __restrict__ t0,     // [NPIX][32] bf16 ch-last (feat)
    const u16* __restrict__ imgp,   // [4][8][HW][4] bf16 dg-planar
    const u16* __restrict__ wfragO, // [9][14][64][8]
    const u16* __restrict__ wfragD, // [9][2][64][8]
    const float* __restrict__ biasO,// 224
    const float* __restrict__ biasD,// 32
    float* __restrict__ out)        // [4][32][HW] f32
{
    const int tid = threadIdx.x, lane = tid & 63, wv = tid >> 6;
    const int m0 = blockIdx.x * 64;
    const int b = m0 / HWc, hwb = m0 - b * HWc;
    const int h0 = hwb / Wc, w0 = hwb - h0 * Wc;

    // union: xt[198 slices][32ch] (12672 B) then co_s[224][66] (29568 B)
    __shared__ u16 pool[224 * 66];

    // ===== stage 0: halo -> xt (linear uint4, coalesced, conflict-free) =====
    {
        u16* xt = pool;
#pragma unroll
        for (int it = 0; it < 4; ++it) {
            int t = it * 256 + tid;
            if (t < 792) {
                int s = t >> 2, c = t & 3;
                int ry = s / 66, cx = s - ry * 66;
                int row = h0 + ry - 1, col = w0 + cx - 1;
                uint4 v = {0u, 0u, 0u, 0u};
                if (((unsigned)row < (unsigned)Hc) && ((unsigned)col < (unsigned)Wc))
                    v = *(const uint4*)(t0 + ((size_t)(b * HWc + row * Wc + col)) * 32 + c * 8);
                *(uint4*)(xt + (size_t)t * 8) = v;
            }
        }
    }
    __syncthreads();

    // ===== phase 1: offset conv (no per-tap barriers) =====
    const int wm = wv >> 1, wn = wv & 1;
    const int rm = wm * 32, cn = wn * 112;
    f32x4 acc[2][7];
#pragma unroll
    for (int mf = 0; mf < 2; ++mf)
#pragma unroll
        for (int nf = 0; nf < 7; ++nf)
            acc[mf][nf] = f32x4{0.f, 0.f, 0.f, 0.f};
    {
        const u16* xt = pool;
        const int r0 = rm + (lane & 15);
        const int kg8 = (lane >> 4) * 8;
#pragma unroll
        for (int kyi = 0; kyi < 3; ++kyi) {
#pragma unroll
            for (int kxi = 0; kxi < 3; ++kxi) {
                const int s9 = kyi * 3 + kxi;
                bf16x8 aF0 = __builtin_bit_cast(bf16x8,
                    *(const uint4*)(xt + (size_t)(kyi * 66 + r0 + kxi) * 32 + kg8));
                bf16x8 aF1 = __builtin_bit_cast(bf16x8,
                    *(const uint4*)(xt + (size_t)(kyi * 66 + r0 + 16 + kxi) * 32 + kg8));
#pragma unroll
                for (int nf = 0; nf < 7; ++nf) {
                    bf16x8 bF = __builtin_bit_cast(
                        bf16x8,
                        *(const uint4*)(wfragO + (((size_t)s9 * 14 + wn * 7 + nf) * 64 + lane) * 8));
                    acc[0][nf] = __builtin_amdgcn_mfma_f32_16x16x32_bf16(aF0, bF, acc[0][nf], 0, 0, 0);
                    acc[1][nf] = __builtin_amdgcn_mfma_f32_16x16x32_bf16(aF1, bF, acc[1][nf], 0, 0, 0);
                }
            }
        }
    }
    __syncthreads();   // all xt reads done (all waves) before overwriting with co_s

    // ===== phase 1b: epilogue -> co_s (re-uses pool) =====
    u16* co_s = pool;
#pragma unroll
    for (int nf = 0; nf < 7; ++nf) {
        const int o = cn + nf * 16 + (lane & 15);
        const float bs = biasO[o];
        const bool sig = (o >= 144);
#pragma unroll
        for (int mf = 0; mf < 2; ++mf) {
            const int mb = rm + mf * 16 + ((lane >> 4) << 2);
            float v0 = acc[mf][nf][0] + bs, v1 = acc[mf][nf][1] + bs;
            float v2 = acc[mf][nf][2] + bs, v3 = acc[mf][nf][3] + bs;
            if (sig) {
                v0 = 1.f / (1.f + expf(-v0)); v1 = 1.f / (1.f + expf(-v1));
                v2 = 1.f / (1.f + expf(-v2)); v3 = 1.f / (1.f + expf(-v3));
            }
            u32 lo = (u32)f2bf(v0) | ((u32)f2bf(v1) << 16);
            u32 hi = (u32)f2bf(v2) | ((u32)f2bf(v3) << 16);
            *(u32*)&co_s[o * 66 + mb]     = lo;
            *(u32*)&co_s[o * 66 + mb + 2] = hi;
        }
    }
    __syncthreads();

    // ===== phase 2: DCN (barrier-free, in-register A-fragments, planar gathers) =====
    {
        const int kg = lane >> 4;                 // dg pair {2kg, 2kg+1}
        const int pixb = wv * 16 + (lane & 15);   // pixel within block
        const int hw = hwb + pixb;
        const int hh = hw / Wc;
        const int wwp = hw - hh * Wc;

        f32x4 acc0 = {0.f, 0.f, 0.f, 0.f};
        f32x4 acc1 = {0.f, 0.f, 0.f, 0.f};

#pragma unroll
        for (int k = 0; k < 9; ++k) {
            const int kyi = k / 3, kxi = k - kyi * 3;
            u32 pk[4];
#pragma unroll
            for (int dgi = 0; dgi < 2; ++dgi) {
                const int dg = 2 * kg + dgi;
                const int offch = dg * 9 + k;
                float dy = bf2f(co_s[offch * 66 + pixb]);
                float dx = bf2f(co_s[(72 + offch) * 66 + pixb]);
                float m  = bf2f(co_s[(144 + offch) * 66 + pixb]);

                float py = dy + (float)(hh + kyi - 1);
                float px = dx + (float)(wwp + kxi - 1);
                float y0f = floorf(py), x0f = floorf(px);
                float wy = py - y0f, wx = px - x0f;
                int y0 = (int)y0f, x0 = (int)x0f;
                int y1 = y0 + 1, x1 = x0 + 1;

                bool vy0 = (unsigned)y0 < (unsigned)Hc;
                bool vy1 = (unsigned)y1 < (unsigned)Hc;
                bool vx0 = (unsigned)x0 < (unsigned)Wc;
                bool vx1 = (unsigned)x1 < (unsigned)Wc;

                int y0c = min(max(y0, 0), Hc - 1);
                int y1c = min(max(y1, 0), Hc - 1);
                int x0c = min(max(x0, 0), Wc - 1);
                int x1c = min(max(x1, 0), Wc - 1);

                float w00 = (1.f - wy) * (1.f - wx);
                float w01 = (1.f - wy) * wx;
                float w10 = wy * (1.f - wx);
                float w11 = wy * wx;
                if (!(vy0 && vx0)) w00 = 0.f;
                if (!(vy0 && vx1)) w01 = 0.f;
                if (!(vy1 && vx0)) w10 = 0.f;
                if (!(vy1 && vx1)) w11 = 0.f;
                w00 *= m; w01 *= m; w10 *= m; w11 *= m;

                const u16* pp = imgp + ((size_t)(b * 8 + dg)) * HWc * 4;
                uint2 c00 = *(const uint2*)(pp + (size_t)(y0c * Wc + x0c) * 4);
                uint2 c01 = *(const uint2*)(pp + (size_t)(y0c * Wc + x1c) * 4);
                uint2 c10 = *(const uint2*)(pp + (size_t)(y1c * Wc + x0c) * 4);
                uint2 c11 = *(const uint2*)(pp + (size_t)(y1c * Wc + x1c) * 4);

                float s[4];
#pragma unroll
                for (int cg = 0; cg < 4; ++cg) {
                    u32 h00 = (cg < 2) ? c00.x : c00.y;
                    u32 h01 = (cg < 2) ? c01.x : c01.y;
                    u32 h10 = (cg < 2) ? c10.x : c10.y;
                    u32 h11 = (cg < 2) ? c11.x : c11.y;
                    int sh = (cg & 1) ? 16 : 0;
                    s[cg] = w00 * bf2f((u16)(h00 >> sh)) + w01 * bf2f((u16)(h01 >> sh))
                          + w10 * bf2f((u16)(h10 >> sh)) + w11 * bf2f((u16)(h11 >> sh));
                }
                pk[dgi * 2 + 0] = (u32)f2bf(s[0]) | ((u32)f2bf(s[1]) << 16);
                pk[dgi * 2 + 1] = (u32)f2bf(s[2]) | ((u32)f2bf(s[3]) << 16);
            }

            bf16x8 aF = __builtin_bit_cast(bf16x8, uint4{pk[0], pk[1], pk[2], pk[3]});
            bf16x8 bF0 = __builtin_bit_cast(bf16x8,
                *(const uint4*)(wfragD + ((size_t)(k * 2 + 0) * 64 + lane) * 8));
            bf16x8 bF1 = __builtin_bit_cast(bf16x8,
                *(const uint4*)(wfragD + ((size_t)(k * 2 + 1) * 64 + lane) * 8));
            acc0 = __builtin_amdgcn_mfma_f32_16x16x32_bf16(aF, bF0, acc0, 0, 0, 0);
            acc1 = __builtin_amdgcn_mfma_f32_16x16x32_bf16(aF, bF1, acc1, 0, 0, 0);
        }

        // epilogue: wave wv owns pixel rows [16wv,16wv+16); C row = (lane>>4)*4+r
        const int rbase = m0 + wv * 16 + ((lane >> 4) << 2);
        const int hw0 = rbase - b * HWc;
        float* ob = out + (size_t)b * 32 * HWc;
        const int oL = lane & 15;
        const float bs0 = biasD[oL], bs1 = biasD[16 + oL];
#pragma unroll
        for (int r = 0; r < 4; ++r) {
            ob[(size_t)oL * HWc + hw0 + r] = acc0[r] + bs0;
            ob[(size_t)(16 + oL) * HWc + hw0 + r] = acc1[r] + bs1;
        }
    }
}

extern "C" void kernel_launch(void* const* d_in, const int* in_sizes, int n_in,
                              void* d_out, int out_size, void* d_ws, size_t ws_size,
                              hipStream_t stream) {
    const float* img_ref  = (const float*)d_in[0];
    const float* img      = (const float*)d_in[1];
    const float* conv1_w  = (const float*)d_in[2];
    const float* conv1_b  = (const float*)d_in[3];
    const float* conv2a_w = (const float*)d_in[4];
    const float* conv2a_b = (const float*)d_in[5];
    const float* conv2b_w = (const float*)d_in[6];
    const float* conv2b_b = (const float*)d_in[7];
    const float* off_w    = (const float*)d_in[8];
    const float* off_b    = (const float*)d_in[9];
    const float* dcn_w    = (const float*)d_in[10];
    const float* dcn_b    = (const float*)d_in[11];

    float* wsf = (float*)d_ws;
    u16* frag = (u16*)((char*)d_ws + FRAG_BYTE);
    u16* t0   = (u16*)((char*)d_ws + T0_BYTE);
    u16* t1   = (u16*)((char*)d_ws + T1_BYTE);
    u16* imgp = (u16*)((char*)d_ws + IMG_BYTE);
    float* out = (float*)d_out;

    prep_k<<<370, 256, 0, stream>>>(conv1_w, conv1_b, conv2a_w, conv2a_b,
                                    conv2b_w, conv2b_b, off_w, off_b,
                                    dcn_w, dcn_b, wsf, frag);

    // conv1x1: [NPIX x 64] @ [64 x 32] -> t0 (ch-last); also dumps img dg-planar
    conv_mfma_k<4, 1, 2, 2, 32, 2, 2, 0, true, true>
        <<<NPIX / 128, 256, 0, stream>>>(img_ref, img, frag + FR1_U, wsf + WF_B1, t0, imgp);

    // conv2a: t0 -> t1
    conv_mfma_k<4, 1, 2, 2, 32, 2, 9, 1, true, false>
        <<<NPIX / 128, 256, 0, stream>>>(t0, nullptr, frag + FRA_U, wsf + WF_B2A, t1, nullptr);

    // conv2b: t1 -> t0
    conv_mfma_k<4, 1, 2, 2, 32, 2, 9, 1, true, false>
        <<<NPIX / 128, 256, 0, stream>>>(t1, nullptr, frag + FRB_U, wsf + WF_B2B, t0, nullptr);

    // fused offset conv + DCN
    offdcn_k<<<NPIX / 64, 256, 0, stream>>>(t0, imgp, frag + FRO_U, frag + FRD_U,
                                            wsf + WF_BO, wsf + WF_BD, out);
}

// Round 10
// 118.336 us; speedup vs baseline: 5.3918x; 1.1040x over previous
//
#include <hip/hip_runtime.h>

#define Hc   192
#define Wc   192
#define HWc  (Hc * Wc)          // 36864
#define NPIX (4 * HWc)          // 147456

typedef float f32x4 __attribute__((ext_vector_type(4)));
typedef __bf16 bf16x8 __attribute__((ext_vector_type(8)));
typedef unsigned short u16;
typedef unsigned int u32;

// ---- workspace layout ----
// f32 region (element offsets):
#define WF_BO    0      // 224 (offset-conv bias, padded 216->224)
#define WF_B1    224
#define WF_B2A   256
#define WF_B2B   288
#define WF_BD    320    // end 352 floats = 1408 B
// bf16 fragment region (u16 offsets from FRAG_BYTE):
#define FR1_U    0      // conv1   [2][2][64][8]   2048
#define FRA_U    2048   // conv2a  [9][2][64][8]   9216
#define FRB_U    11264  // conv2b  [9][2][64][8]   9216
#define FRO_U    20480  // offset  [9][14][64][8]  64512
#define FRD_U    84992  // dcn     [9][2][64][8]   9216  (K-within-32 = dg*4+cg)
#define FRAG_U_TOT 94208
#define FRAG_BYTE 1408
// buffers (byte offsets):
#define T0_BYTE  (FRAG_BYTE + FRAG_U_TOT * 2)        // [NPIX][32] bf16 ch-last
#define T1_BYTE  (T0_BYTE + NPIX * 32 * 2)
#define IMG_BYTE (T1_BYTE + NPIX * 32 * 2)           // [4][8][HW][4] bf16 dg-planar img

__device__ __forceinline__ u16 f2bf(float f) {
    u32 u = __float_as_uint(f);
    u32 r = u + 0x7fffu + ((u >> 16) & 1u);
    return (u16)(r >> 16);
}
__device__ __forceinline__ float bf2f(u16 v) {
    return __uint_as_float(((u32)v) << 16);
}

// ---------------- prep: biases (f32) + MFMA weight fragments (bf16) ----------------
__global__ __launch_bounds__(256) void prep_k(
    const float* __restrict__ w1,  const float* __restrict__ b1,
    const float* __restrict__ w2a, const float* __restrict__ b2a,
    const float* __restrict__ w2b, const float* __restrict__ b2b,
    const float* __restrict__ wo,  const float* __restrict__ bo,
    const float* __restrict__ wd,  const float* __restrict__ bd,
    float* __restrict__ wsf, u16* __restrict__ frag)
{
    int i = blockIdx.x * 256 + threadIdx.x;
    if (i < 224)      { wsf[WF_BO + i]  = (i < 216) ? bo[i] : 0.f; return; }
    if (i < 256)      { wsf[WF_B1  + i - 224] = b1[i - 224];  return; }
    if (i < 288)      { wsf[WF_B2A + i - 256] = b2a[i - 256]; return; }
    if (i < 320)      { wsf[WF_B2B + i - 288] = b2b[i - 288]; return; }
    if (i < 352)      { wsf[WF_BD  + i - 320] = bd[i - 320];  return; }
    int fi = i - 352;
    if (fi < 2048) {          // conv1 frags: [s][nt][l][j], ci = s*32 + (l>>4)*8 + j
        int s = fi >> 10, l = (fi >> 3) & 63, j = fi & 7;
        int nt = (fi >> 9) & 1;
        int o = nt * 16 + (l & 15);
        int ci = s * 32 + ((l >> 4) << 3) + j;
        frag[FR1_U + fi] = f2bf(w1[o * 64 + ci]);
        return;
    }
    fi -= 2048;
    if (fi < 9216) {          // conv2a frags: tap = s, ci = (l>>4)*8+j
        int s = fi / 1024, r = fi - s * 1024;
        int nt = r >> 9, l = (r >> 3) & 63, j = r & 7;
        int o = nt * 16 + (l & 15);
        int ci = ((l >> 4) << 3) + j;
        frag[FRA_U + fi] = f2bf(w2a[(o * 32 + ci) * 9 + s]);
        return;
    }
    fi -= 9216;
    if (fi < 9216) {          // conv2b frags
        int s = fi / 1024, r = fi - s * 1024;
        int nt = r >> 9, l = (r >> 3) & 63, j = r & 7;
        int o = nt * 16 + (l & 15);
        int ci = ((l >> 4) << 3) + j;
        frag[FRB_U + fi] = f2bf(w2b[(o * 32 + ci) * 9 + s]);
        return;
    }
    fi -= 9216;
    if (fi < 64512) {         // offset-conv frags, COUT padded to 224
        int s = fi / 7168, r = fi - s * 7168;
        int nt = r >> 9, l = (r >> 3) & 63, j = r & 7;
        int o = nt * 16 + (l & 15);
        int ci = ((l >> 4) << 3) + j;
        frag[FRO_U + fi] = f2bf((o < 216) ? wo[(o * 32 + ci) * 9 + s] : 0.f);
        return;
    }
    fi -= 64512;
    if (fi < 9216) {          // dcn frags: [k][nt][l][j], K-within = (l>>4)*8+j = ci = dg*4+cg
        int k = fi / 1024, r = fi - k * 1024;
        int nt = r >> 9, l = (r >> 3) & 63, j = r & 7;
        int o = nt * 16 + (l & 15);
        int ci = ((l >> 4) << 3) + j;
        frag[FRD_U + fi] = f2bf(wd[o * 288 + ci * 9 + k]);
        return;
    }
}

// ---------------- implicit-GEMM conv via MFMA (small convs) ----------------
template <int WM, int WN, int MF, int NF, int COUT, int NTILES, int KS, int MODE, bool CHL, bool DUMP>
__global__ __launch_bounds__(256) void conv_mfma_k(
    const void* __restrict__ s0v, const void* __restrict__ s1v,
    const u16* __restrict__ wfrag, const float* __restrict__ bias,
    u16* __restrict__ y, u16* __restrict__ dump)
{
    constexpr int M_BLK = WM * MF * 16;
    constexpr int ITERS = M_BLK / 64;
    const int tid = threadIdx.x, lane = tid & 63, wv = tid >> 6;
    const int wm = wv / WN, wn = wv % WN;
    const int m0 = blockIdx.x * M_BLK;
    const int b = m0 / HWc, hwb = m0 - b * HWc;
    const int rm = wm * MF * 16, cn = wn * NF * 16;

    __shared__ uint4 At4[M_BLK * 4];

    int pxA[ITERS], hA[ITERS], wA[ITERS], kgA[ITERS];
#pragma unroll
    for (int it = 0; it < ITERS; ++it) {
        int st = it * 256 + tid;
        int rowl = ((st >> 6) << 4) | (st & 15);
        kgA[it] = (st >> 4) & 3;
        pxA[it] = rowl;
        int hwp = hwb + rowl;
        hA[it] = hwp / Wc;
        wA[it] = hwp - hA[it] * Wc;
    }

    f32x4 acc[MF][NF];
#pragma unroll
    for (int mf = 0; mf < MF; ++mf)
#pragma unroll
        for (int nf = 0; nf < NF; ++nf)
            acc[mf][nf] = f32x4{0.f, 0.f, 0.f, 0.f};

    const u16* srcB = (const u16*)s0v;
    const float* f0 = (const float*)s0v;
    const float* f1 = (const float*)s1v;

    for (int s = 0; s < KS; ++s) {
        // ---- stage A tile ----
        if (MODE == 1) {
            int dy = s / 3 - 1, dx = s - (s / 3) * 3 - 1;
            int d = dy * Wc + dx;
#pragma unroll
            for (int it = 0; it < ITERS; ++it) {
                bool valid = ((unsigned)(hA[it] + dy) < (unsigned)Hc) &&
                             ((unsigned)(wA[it] + dx) < (unsigned)Wc);
                uint4 v = {0u, 0u, 0u, 0u};
                if (valid)
                    v = *(const uint4*)(srcB + ((size_t)(m0 + pxA[it] + d)) * 32 + kgA[it] * 8);
                At4[it * 256 + tid] = v;
            }
        } else {
            const float* fs = (s == 0) ? f0 : f1;
#pragma unroll
            for (int it = 0; it < ITERS; ++it) {
                const float* pl = fs + ((size_t)b * 32 + kgA[it] * 8) * HWc + (hwb + pxA[it]);
                u32 p0, p1, p2, p3;
                {
                    u32 a0 = f2bf(pl[0 * HWc]), a1 = f2bf(pl[1 * HWc]);
                    u32 a2 = f2bf(pl[2 * HWc]), a3 = f2bf(pl[3 * HWc]);
                    u32 a4 = f2bf(pl[4 * HWc]), a5 = f2bf(pl[5 * HWc]);
                    u32 a6 = f2bf(pl[6 * HWc]), a7 = f2bf(pl[7 * HWc]);
                    p0 = a0 | (a1 << 16); p1 = a2 | (a3 << 16);
                    p2 = a4 | (a5 << 16); p3 = a6 | (a7 << 16);
                }
                uint4 v = {p0, p1, p2, p3};
                if (DUMP && s == 1) {
                    size_t base = ((size_t)(b * 8 + kgA[it] * 2) * HWc + (hwb + pxA[it])) * 4;
                    *(uint2*)(dump + base) = uint2{p0, p1};
                    *(uint2*)(dump + base + (size_t)HWc * 4) = uint2{p2, p3};
                }
                At4[it * 256 + tid] = v;
            }
        }
        __syncthreads();

        // ---- fragments + MFMA ----
        bf16x8 aF[MF];
#pragma unroll
        for (int mf = 0; mf < MF; ++mf)
            aF[mf] = __builtin_bit_cast(bf16x8, At4[((rm >> 4) + mf) * 64 + lane]);
#pragma unroll
        for (int nf = 0; nf < NF; ++nf) {
            bf16x8 bF = __builtin_bit_cast(
                bf16x8,
                *(const uint4*)(wfrag + (((size_t)s * NTILES + wn * NF + nf) * 64 + lane) * 8));
#pragma unroll
            for (int mf = 0; mf < MF; ++mf)
                acc[mf][nf] = __builtin_amdgcn_mfma_f32_16x16x32_bf16(aF[mf], bF, acc[mf][nf], 0, 0, 0);
        }
        __syncthreads();
    }

    // ---- epilogue: bias + store ch-last ----
#pragma unroll
    for (int nf = 0; nf < NF; ++nf) {
        int o = cn + nf * 16 + (lane & 15);
        float bs = bias[o];
#pragma unroll
        for (int mf = 0; mf < MF; ++mf) {
#pragma unroll
            for (int r = 0; r < 4; ++r) {
                int m = m0 + rm + mf * 16 + ((lane >> 4) << 2) + r;
                float val = acc[mf][nf][r] + bs;
                y[(size_t)m * COUT + o] = f2bf(val);
            }
        }
    }
}

// ---------------- FUSED: offset conv + modulated deformable conv ----------------
// XCD-swizzled grid (2304 % 8 == 0 -> bijective): each XCD owns a contiguous
// half-image pixel range -> t0 halo + imgp working set ~2.4MB, L2-resident.
// Stage 0: halo of t0 -> LDS xt, one barrier.
// Phase 1: offset conv, 9 taps pure ds_read+MFMA, no per-tap barriers.
// Phase 1b: epilogue -> co_s[224][66] (LDS pool re-use).
// Phase 2: DCN, 3-tap batches: issue all 18 co_s reads + 24 corner gathers
//          per batch before consuming (MLP), then 6 MFMAs. float4 out stores.
__global__ __launch_bounds__(256, 4) void offdcn_k(
    const u16* __restrict__ t0,     // [NPIX][32] bf16 ch-last (feat)
    const u16* __restrict__ imgp,   // [4][8][HW][4] bf16 dg-planar
    const u16* __restrict__ wfragO, // [9][14][64][8]
    const u16* __restrict__ wfragD, // [9][2][64][8]
    const float* __restrict__ biasO,// 224
    const float* __restrict__ biasD,// 32
    float* __restrict__ out)        // [4][32][HW] f32
{
    const int tid = threadIdx.x, lane = tid & 63, wv = tid >> 6;
    const int bid = blockIdx.x;
    const int swz = (bid & 7) * 288 + (bid >> 3);   // XCD-contiguous chunks
    const int m0 = swz * 64;
    const int b = m0 / HWc, hwb = m0 - b * HWc;
    const int h0 = hwb / Wc, w0 = hwb - h0 * Wc;

    // union: xt[198 slices][32ch] (12672 B) then co_s[224][66] (29568 B)
    __shared__ u16 pool[224 * 66];

    // ===== stage 0: halo -> xt =====
    {
        u16* xt = pool;
#pragma unroll
        for (int it = 0; it < 4; ++it) {
            int t = it * 256 + tid;
            if (t < 792) {
                int s = t >> 2, c = t & 3;
                int ry = s / 66, cx = s - ry * 66;
                int row = h0 + ry - 1, col = w0 + cx - 1;
                uint4 v = {0u, 0u, 0u, 0u};
                if (((unsigned)row < (unsigned)Hc) && ((unsigned)col < (unsigned)Wc))
                    v = *(const uint4*)(t0 + ((size_t)(b * HWc + row * Wc + col)) * 32 + c * 8);
                *(uint4*)(xt + (size_t)t * 8) = v;
            }
        }
    }
    __syncthreads();

    // ===== phase 1: offset conv (no per-tap barriers) =====
    const int wm = wv >> 1, wn = wv & 1;
    const int rm = wm * 32, cn = wn * 112;
    f32x4 acc[2][7];
#pragma unroll
    for (int mf = 0; mf < 2; ++mf)
#pragma unroll
        for (int nf = 0; nf < 7; ++nf)
            acc[mf][nf] = f32x4{0.f, 0.f, 0.f, 0.f};
    {
        const u16* xt = pool;
        const int r0 = rm + (lane & 15);
        const int kg8 = (lane >> 4) * 8;
#pragma unroll
        for (int kyi = 0; kyi < 3; ++kyi) {
#pragma unroll
            for (int kxi = 0; kxi < 3; ++kxi) {
                const int s9 = kyi * 3 + kxi;
                bf16x8 aF0 = __builtin_bit_cast(bf16x8,
                    *(const uint4*)(xt + (size_t)(kyi * 66 + r0 + kxi) * 32 + kg8));
                bf16x8 aF1 = __builtin_bit_cast(bf16x8,
                    *(const uint4*)(xt + (size_t)(kyi * 66 + r0 + 16 + kxi) * 32 + kg8));
#pragma unroll
                for (int nf = 0; nf < 7; ++nf) {
                    bf16x8 bF = __builtin_bit_cast(
                        bf16x8,
                        *(const uint4*)(wfragO + (((size_t)s9 * 14 + wn * 7 + nf) * 64 + lane) * 8));
                    acc[0][nf] = __builtin_amdgcn_mfma_f32_16x16x32_bf16(aF0, bF, acc[0][nf], 0, 0, 0);
                    acc[1][nf] = __builtin_amdgcn_mfma_f32_16x16x32_bf16(aF1, bF, acc[1][nf], 0, 0, 0);
                }
            }
        }
    }
    __syncthreads();   // all xt reads done before co_s overwrites the pool

    // ===== phase 1b: epilogue -> co_s =====
    u16* co_s = pool;
#pragma unroll
    for (int nf = 0; nf < 7; ++nf) {
        const int o = cn + nf * 16 + (lane & 15);
        const float bs = biasO[o];
        const bool sig = (o >= 144);
#pragma unroll
        for (int mf = 0; mf < 2; ++mf) {
            const int mb = rm + mf * 16 + ((lane >> 4) << 2);
            float v0 = acc[mf][nf][0] + bs, v1 = acc[mf][nf][1] + bs;
            float v2 = acc[mf][nf][2] + bs, v3 = acc[mf][nf][3] + bs;
            if (sig) {
                v0 = 1.f / (1.f + expf(-v0)); v1 = 1.f / (1.f + expf(-v1));
                v2 = 1.f / (1.f + expf(-v2)); v3 = 1.f / (1.f + expf(-v3));
            }
            u32 lo = (u32)f2bf(v0) | ((u32)f2bf(v1) << 16);
            u32 hi = (u32)f2bf(v2) | ((u32)f2bf(v3) << 16);
            *(u32*)&co_s[o * 66 + mb]     = lo;
            *(u32*)&co_s[o * 66 + mb + 2] = hi;
        }
    }
    __syncthreads();

    // ===== phase 2: DCN, 3-tap batches for gather MLP =====
    {
        const int kg = lane >> 4;                 // dg pair {2kg, 2kg+1}
        const int pixb = wv * 16 + (lane & 15);   // pixel within block
        const int hw = hwb + pixb;
        const int hh = hw / Wc;
        const int wwp = hw - hh * Wc;

        f32x4 acc0 = {0.f, 0.f, 0.f, 0.f};
        f32x4 acc1 = {0.f, 0.f, 0.f, 0.f};

#pragma unroll 1
        for (int kb = 0; kb < 9; kb += 3) {
            float w4[3][2][4];
            uint2 cc[3][2][4];

            // ---- stage A: co_s reads + addresses + issue ALL 24 gathers ----
#pragma unroll
            for (int t = 0; t < 3; ++t) {
                const int k = kb + t;
                const int kyi = k / 3, kxi = k - kyi * 3;
#pragma unroll
                for (int dgi = 0; dgi < 2; ++dgi) {
                    const int dg = 2 * kg + dgi;
                    const int offch = dg * 9 + k;
                    float dy = bf2f(co_s[offch * 66 + pixb]);
                    float dx = bf2f(co_s[(72 + offch) * 66 + pixb]);
                    float m  = bf2f(co_s[(144 + offch) * 66 + pixb]);

                    float py = dy + (float)(hh + kyi - 1);
                    float px = dx + (float)(wwp + kxi - 1);
                    float y0f = floorf(py), x0f = floorf(px);
                    float wy = py - y0f, wx = px - x0f;
                    int y0 = (int)y0f, x0 = (int)x0f;
                    int y1 = y0 + 1, x1 = x0 + 1;

                    bool vy0 = (unsigned)y0 < (unsigned)Hc;
                    bool vy1 = (unsigned)y1 < (unsigned)Hc;
                    bool vx0 = (unsigned)x0 < (unsigned)Wc;
                    bool vx1 = (unsigned)x1 < (unsigned)Wc;

                    int y0c = min(max(y0, 0), Hc - 1);
                    int y1c = min(max(y1, 0), Hc - 1);
                    int x0c = min(max(x0, 0), Wc - 1);
                    int x1c = min(max(x1, 0), Wc - 1);

                    float w00 = (1.f - wy) * (1.f - wx);
                    float w01 = (1.f - wy) * wx;
                    float w10 = wy * (1.f - wx);
                    float w11 = wy * wx;
                    if (!(vy0 && vx0)) w00 = 0.f;
                    if (!(vy0 && vx1)) w01 = 0.f;
                    if (!(vy1 && vx0)) w10 = 0.f;
                    if (!(vy1 && vx1)) w11 = 0.f;
                    w4[t][dgi][0] = w00 * m;
                    w4[t][dgi][1] = w01 * m;
                    w4[t][dgi][2] = w10 * m;
                    w4[t][dgi][3] = w11 * m;

                    const u16* pp = imgp + ((size_t)(b * 8 + dg)) * HWc * 4;
                    cc[t][dgi][0] = *(const uint2*)(pp + (size_t)(y0c * Wc + x0c) * 4);
                    cc[t][dgi][1] = *(const uint2*)(pp + (size_t)(y0c * Wc + x1c) * 4);
                    cc[t][dgi][2] = *(const uint2*)(pp + (size_t)(y1c * Wc + x0c) * 4);
                    cc[t][dgi][3] = *(const uint2*)(pp + (size_t)(y1c * Wc + x1c) * 4);
                }
            }

            // ---- stage B: bilinear + pack + MFMA ----
#pragma unroll
            for (int t = 0; t < 3; ++t) {
                const int k = kb + t;
                u32 pk[4];
#pragma unroll
                for (int dgi = 0; dgi < 2; ++dgi) {
                    float s[4];
#pragma unroll
                    for (int cg = 0; cg < 4; ++cg) {
                        u32 h00 = (cg < 2) ? cc[t][dgi][0].x : cc[t][dgi][0].y;
                        u32 h01 = (cg < 2) ? cc[t][dgi][1].x : cc[t][dgi][1].y;
                        u32 h10 = (cg < 2) ? cc[t][dgi][2].x : cc[t][dgi][2].y;
                        u32 h11 = (cg < 2) ? cc[t][dgi][3].x : cc[t][dgi][3].y;
                        int sh = (cg & 1) ? 16 : 0;
                        s[cg] = w4[t][dgi][0] * bf2f((u16)(h00 >> sh))
                              + w4[t][dgi][1] * bf2f((u16)(h01 >> sh))
                              + w4[t][dgi][2] * bf2f((u16)(h10 >> sh))
                              + w4[t][dgi][3] * bf2f((u16)(h11 >> sh));
                    }
                    pk[dgi * 2 + 0] = (u32)f2bf(s[0]) | ((u32)f2bf(s[1]) << 16);
                    pk[dgi * 2 + 1] = (u32)f2bf(s[2]) | ((u32)f2bf(s[3]) << 16);
                }

                bf16x8 aF = __builtin_bit_cast(bf16x8, uint4{pk[0], pk[1], pk[2], pk[3]});
                bf16x8 bF0 = __builtin_bit_cast(bf16x8,
                    *(const uint4*)(wfragD + ((size_t)(k * 2 + 0) * 64 + lane) * 8));
                bf16x8 bF1 = __builtin_bit_cast(bf16x8,
                    *(const uint4*)(wfragD + ((size_t)(k * 2 + 1) * 64 + lane) * 8));
                acc0 = __builtin_amdgcn_mfma_f32_16x16x32_bf16(aF, bF0, acc0, 0, 0, 0);
                acc1 = __builtin_amdgcn_mfma_f32_16x16x32_bf16(aF, bF1, acc1, 0, 0, 0);
            }
        }

        // epilogue: acc0[0..3] = 4 consecutive pixels -> one f32x4 store per row
        const int hw0 = hwb + wv * 16 + ((lane >> 4) << 2);
        float* ob = out + (size_t)b * 32 * HWc;
        const int oL = lane & 15;
        const float bs0 = biasD[oL], bs1 = biasD[16 + oL];
        f32x4 o0 = {acc0[0] + bs0, acc0[1] + bs0, acc0[2] + bs0, acc0[3] + bs0};
        f32x4 o1 = {acc1[0] + bs1, acc1[1] + bs1, acc1[2] + bs1, acc1[3] + bs1};
        *(f32x4*)(ob + (size_t)oL * HWc + hw0) = o0;
        *(f32x4*)(ob + (size_t)(16 + oL) * HWc + hw0) = o1;
    }
}

extern "C" void kernel_launch(void* const* d_in, const int* in_sizes, int n_in,
                              void* d_out, int out_size, void* d_ws, size_t ws_size,
                              hipStream_t stream) {
    const float* img_ref  = (const float*)d_in[0];
    const float* img      = (const float*)d_in[1];
    const float* conv1_w  = (const float*)d_in[2];
    const float* conv1_b  = (const float*)d_in[3];
    const float* conv2a_w = (const float*)d_in[4];
    const float* conv2a_b = (const float*)d_in[5];
    const float* conv2b_w = (const float*)d_in[6];
    const float* conv2b_b = (const float*)d_in[7];
    const float* off_w    = (const float*)d_in[8];
    const float* off_b    = (const float*)d_in[9];
    const float* dcn_w    = (const float*)d_in[10];
    const float* dcn_b    = (const float*)d_in[11];

    float* wsf = (float*)d_ws;
    u16* frag = (u16*)((char*)d_ws + FRAG_BYTE);
    u16* t0   = (u16*)((char*)d_ws + T0_BYTE);
    u16* t1   = (u16*)((char*)d_ws + T1_BYTE);
    u16* imgp = (u16*)((char*)d_ws + IMG_BYTE);
    float* out = (float*)d_out;

    prep_k<<<370, 256, 0, stream>>>(conv1_w, conv1_b, conv2a_w, conv2a_b,
                                    conv2b_w, conv2b_b, off_w, off_b,
                                    dcn_w, dcn_b, wsf, frag);

    // conv1x1: [NPIX x 64] @ [64 x 32] -> t0 (ch-last); also dumps img dg-planar
    conv_mfma_k<4, 1, 2, 2, 32, 2, 2, 0, true, true>
        <<<NPIX / 128, 256, 0, stream>>>(img_ref, img, frag + FR1_U, wsf + WF_B1, t0, imgp);

    // conv2a: t0 -> t1
    conv_mfma_k<4, 1, 2, 2, 32, 2, 9, 1, true, false>
        <<<NPIX / 128, 256, 0, stream>>>(t0, nullptr, frag + FRA_U, wsf + WF_B2A, t1, nullptr);

    // conv2b: t1 -> t0
    conv_mfma_k<4, 1, 2, 2, 32, 2, 9, 1, true, false>
        <<<NPIX / 128, 256, 0, stream>>>(t1, nullptr, frag + FRB_U, wsf + WF_B2B, t0, nullptr);

    // fused offset conv + DCN (XCD-swizzled inside kernel)
    offdcn_k<<<NPIX / 64, 256, 0, stream>>>(t0, imgp, frag + FRO_U, frag + FRD_U,
                                            wsf + WF_BO, wsf + WF_BD, out);
}

// Round 11
// 111.776 us; speedup vs baseline: 5.7082x; 1.0587x over previous
//
#include <hip/hip_runtime.h>

#define Hc   192
#define Wc   192
#define HWc  (Hc * Wc)          // 36864
#define NPIX (4 * HWc)          // 147456
#define Hp   194                // padded rows: y+1 in [0,193]
#define Wp   256                // padded cols (shift-addressable), data at x+1 in [0,193]
#define PLANE (Hp * Wp)         // px-slots per (b,dg) plane, 4 ch each

typedef float f32x4 __attribute__((ext_vector_type(4)));
typedef float f32x2 __attribute__((ext_vector_type(2)));
typedef __bf16 bf16x8 __attribute__((ext_vector_type(8)));
typedef unsigned short u16;
typedef unsigned int u32;

// ---- workspace layout ----
// f32 region (element offsets):
#define WF_BO    0      // 224 (offset-conv bias, padded 216->224)
#define WF_B1    224
#define WF_B2A   256
#define WF_B2B   288
#define WF_BD    320    // end 352 floats = 1408 B
// bf16 fragment region (u16 offsets from FRAG_BYTE):
#define FR1_U    0      // conv1   [2][2][64][8]   2048
#define FRA_U    2048   // conv2a  [9][2][64][8]   9216
#define FRB_U    11264  // conv2b  [9][2][64][8]   9216
#define FRO_U    20480  // offset  [9][14][64][8]  64512
#define FRD_U    84992  // dcn     [9][2][64][8]   9216  (K-within-32 = dg*4+cg)
#define FRAG_U_TOT 94208
#define FRAG_BYTE 1408
// buffers (byte offsets):
#define T0_BYTE  (FRAG_BYTE + FRAG_U_TOT * 2)        // [NPIX][32] bf16 ch-last
#define T1_BYTE  (T0_BYTE + NPIX * 32 * 2)
#define IMG_BYTE (T1_BYTE + NPIX * 32 * 2)           // [4][8][Hp][Wp][4] bf16 zero-padded
#define IMG_SZ   ((size_t)4 * 8 * PLANE * 4 * 2)     // 12,713,984 B

__device__ __forceinline__ u16 f2bf(float f) {
    u32 u = __float_as_uint(f);
    u32 r = u + 0x7fffu + ((u >> 16) & 1u);
    return (u16)(r >> 16);
}
__device__ __forceinline__ float bf2f(u16 v) {
    return __uint_as_float(((u32)v) << 16);
}
__device__ __forceinline__ u32 cvtpk(float a, float b) {
    u32 r;
    asm("v_cvt_pk_bf16_f32 %0, %1, %2" : "=v"(r) : "v"(a), "v"(b));
    return r;
}
__device__ __forceinline__ f32x2 unpk(u32 h) {
    return f32x2{__uint_as_float(h << 16), __uint_as_float(h & 0xffff0000u)};
}

// ---------------- prep: biases (f32) + MFMA weight fragments (bf16) ----------------
__global__ __launch_bounds__(256) void prep_k(
    const float* __restrict__ w1,  const float* __restrict__ b1,
    const float* __restrict__ w2a, const float* __restrict__ b2a,
    const float* __restrict__ w2b, const float* __restrict__ b2b,
    const float* __restrict__ wo,  const float* __restrict__ bo,
    const float* __restrict__ wd,  const float* __restrict__ bd,
    float* __restrict__ wsf, u16* __restrict__ frag)
{
    int i = blockIdx.x * 256 + threadIdx.x;
    if (i < 224)      { wsf[WF_BO + i]  = (i < 216) ? bo[i] : 0.f; return; }
    if (i < 256)      { wsf[WF_B1  + i - 224] = b1[i - 224];  return; }
    if (i < 288)      { wsf[WF_B2A + i - 256] = b2a[i - 256]; return; }
    if (i < 320)      { wsf[WF_B2B + i - 288] = b2b[i - 288]; return; }
    if (i < 352)      { wsf[WF_BD  + i - 320] = bd[i - 320];  return; }
    int fi = i - 352;
    if (fi < 2048) {          // conv1 frags: [s][nt][l][j], ci = s*32 + (l>>4)*8 + j
        int s = fi >> 10, l = (fi >> 3) & 63, j = fi & 7;
        int nt = (fi >> 9) & 1;
        int o = nt * 16 + (l & 15);
        int ci = s * 32 + ((l >> 4) << 3) + j;
        frag[FR1_U + fi] = f2bf(w1[o * 64 + ci]);
        return;
    }
    fi -= 2048;
    if (fi < 9216) {          // conv2a frags: tap = s, ci = (l>>4)*8+j
        int s = fi / 1024, r = fi - s * 1024;
        int nt = r >> 9, l = (r >> 3) & 63, j = r & 7;
        int o = nt * 16 + (l & 15);
        int ci = ((l >> 4) << 3) + j;
        frag[FRA_U + fi] = f2bf(w2a[(o * 32 + ci) * 9 + s]);
        return;
    }
    fi -= 9216;
    if (fi < 9216) {          // conv2b frags
        int s = fi / 1024, r = fi - s * 1024;
        int nt = r >> 9, l = (r >> 3) & 63, j = r & 7;
        int o = nt * 16 + (l & 15);
        int ci = ((l >> 4) << 3) + j;
        frag[FRB_U + fi] = f2bf(w2b[(o * 32 + ci) * 9 + s]);
        return;
    }
    fi -= 9216;
    if (fi < 64512) {         // offset-conv frags, COUT padded to 224
        int s = fi / 7168, r = fi - s * 7168;
        int nt = r >> 9, l = (r >> 3) & 63, j = r & 7;
        int o = nt * 16 + (l & 15);
        int ci = ((l >> 4) << 3) + j;
        frag[FRO_U + fi] = f2bf((o < 216) ? wo[(o * 32 + ci) * 9 + s] : 0.f);
        return;
    }
    fi -= 64512;
    if (fi < 9216) {          // dcn frags: [k][nt][l][j], K-within = (l>>4)*8+j = ci = dg*4+cg
        int k = fi / 1024, r = fi - k * 1024;
        int nt = r >> 9, l = (r >> 3) & 63, j = r & 7;
        int o = nt * 16 + (l & 15);
        int ci = ((l >> 4) << 3) + j;
        frag[FRD_U + fi] = f2bf(wd[o * 288 + ci * 9 + k]);
        return;
    }
}

// ---------------- implicit-GEMM conv via MFMA (small convs) ----------------
template <int WM, int WN, int MF, int NF, int COUT, int NTILES, int KS, int MODE, bool CHL, bool DUMP>
__global__ __launch_bounds__(256) void conv_mfma_k(
    const void* __restrict__ s0v, const void* __restrict__ s1v,
    const u16* __restrict__ wfrag, const float* __restrict__ bias,
    u16* __restrict__ y, u16* __restrict__ dump)
{
    constexpr int M_BLK = WM * MF * 16;
    constexpr int ITERS = M_BLK / 64;
    const int tid = threadIdx.x, lane = tid & 63, wv = tid >> 6;
    const int wm = wv / WN, wn = wv % WN;
    const int m0 = blockIdx.x * M_BLK;
    const int b = m0 / HWc, hwb = m0 - b * HWc;
    const int rm = wm * MF * 16, cn = wn * NF * 16;

    __shared__ uint4 At4[M_BLK * 4];

    int pxA[ITERS], hA[ITERS], wA[ITERS], kgA[ITERS];
#pragma unroll
    for (int it = 0; it < ITERS; ++it) {
        int st = it * 256 + tid;
        int rowl = ((st >> 6) << 4) | (st & 15);
        kgA[it] = (st >> 4) & 3;
        pxA[it] = rowl;
        int hwp = hwb + rowl;
        hA[it] = hwp / Wc;
        wA[it] = hwp - hA[it] * Wc;
    }

    f32x4 acc[MF][NF];
#pragma unroll
    for (int mf = 0; mf < MF; ++mf)
#pragma unroll
        for (int nf = 0; nf < NF; ++nf)
            acc[mf][nf] = f32x4{0.f, 0.f, 0.f, 0.f};

    const u16* srcB = (const u16*)s0v;
    const float* f0 = (const float*)s0v;
    const float* f1 = (const float*)s1v;

    for (int s = 0; s < KS; ++s) {
        // ---- stage A tile ----
        if (MODE == 1) {
            int dy = s / 3 - 1, dx = s - (s / 3) * 3 - 1;
            int d = dy * Wc + dx;
#pragma unroll
            for (int it = 0; it < ITERS; ++it) {
                bool valid = ((unsigned)(hA[it] + dy) < (unsigned)Hc) &&
                             ((unsigned)(wA[it] + dx) < (unsigned)Wc);
                uint4 v = {0u, 0u, 0u, 0u};
                if (valid)
                    v = *(const uint4*)(srcB + ((size_t)(m0 + pxA[it] + d)) * 32 + kgA[it] * 8);
                At4[it * 256 + tid] = v;
            }
        } else {
            const float* fs = (s == 0) ? f0 : f1;
#pragma unroll
            for (int it = 0; it < ITERS; ++it) {
                const float* pl = fs + ((size_t)b * 32 + kgA[it] * 8) * HWc + (hwb + pxA[it]);
                u32 p0, p1, p2, p3;
                {
                    u32 a0 = f2bf(pl[0 * HWc]), a1 = f2bf(pl[1 * HWc]);
                    u32 a2 = f2bf(pl[2 * HWc]), a3 = f2bf(pl[3 * HWc]);
                    u32 a4 = f2bf(pl[4 * HWc]), a5 = f2bf(pl[5 * HWc]);
                    u32 a6 = f2bf(pl[6 * HWc]), a7 = f2bf(pl[7 * HWc]);
                    p0 = a0 | (a1 << 16); p1 = a2 | (a3 << 16);
                    p2 = a4 | (a5 << 16); p3 = a6 | (a7 << 16);
                }
                uint4 v = {p0, p1, p2, p3};
                if (DUMP && s == 1) {
                    // zero-padded dg-planar: plane 2kg gets ch 0..3, plane 2kg+1 gets ch 4..7
                    size_t base = (((size_t)(b * 8 + kgA[it] * 2)) * PLANE
                                   + (size_t)(hA[it] + 1) * Wp + (wA[it] + 1)) * 4;
                    *(uint2*)(dump + base) = uint2{p0, p1};
                    *(uint2*)(dump + base + (size_t)PLANE * 4) = uint2{p2, p3};
                }
                At4[it * 256 + tid] = v;
            }
        }
        __syncthreads();

        // ---- fragments + MFMA ----
        bf16x8 aF[MF];
#pragma unroll
        for (int mf = 0; mf < MF; ++mf)
            aF[mf] = __builtin_bit_cast(bf16x8, At4[((rm >> 4) + mf) * 64 + lane]);
#pragma unroll
        for (int nf = 0; nf < NF; ++nf) {
            bf16x8 bF = __builtin_bit_cast(
                bf16x8,
                *(const uint4*)(wfrag + (((size_t)s * NTILES + wn * NF + nf) * 64 + lane) * 8));
#pragma unroll
            for (int mf = 0; mf < MF; ++mf)
                acc[mf][nf] = __builtin_amdgcn_mfma_f32_16x16x32_bf16(aF[mf], bF, acc[mf][nf], 0, 0, 0);
        }
        __syncthreads();
    }

    // ---- epilogue: bias + store ch-last ----
#pragma unroll
    for (int nf = 0; nf < NF; ++nf) {
        int o = cn + nf * 16 + (lane & 15);
        float bs = bias[o];
#pragma unroll
        for (int mf = 0; mf < MF; ++mf) {
#pragma unroll
            for (int r = 0; r < 4; ++r) {
                int m = m0 + rm + mf * 16 + ((lane >> 4) << 2) + r;
                float val = acc[mf][nf][r] + bs;
                y[(size_t)m * COUT + o] = f2bf(val);
            }
        }
    }
}

// ---------------- FUSED: offset conv + modulated deformable conv ----------------
// XCD-swizzled grid; stage 0 halo -> LDS; phase 1 offset conv (no per-tap barriers);
// phase 1b -> co_s; phase 2 DCN with zero-padded planes (no validity masks),
// packed-f32 bilinear, cvt_pk_bf16 packing, 3-tap gather batches, f32x4 stores.
__global__ __launch_bounds__(256, 4) void offdcn_k(
    const u16* __restrict__ t0,     // [NPIX][32] bf16 ch-last (feat)
    const u16* __restrict__ imgp,   // [4][8][Hp][Wp][4] bf16 zero-padded
    const u16* __restrict__ wfragO, // [9][14][64][8]
    const u16* __restrict__ wfragD, // [9][2][64][8]
    const float* __restrict__ biasO,// 224
    const float* __restrict__ biasD,// 32
    float* __restrict__ out)        // [4][32][HW] f32
{
    const int tid = threadIdx.x, lane = tid & 63, wv = tid >> 6;
    const int bid = blockIdx.x;
    const int swz = (bid & 7) * 288 + (bid >> 3);   // XCD-contiguous chunks
    const int m0 = swz * 64;
    const int b = m0 / HWc, hwb = m0 - b * HWc;
    const int h0 = hwb / Wc, w0 = hwb - h0 * Wc;

    // union: xt[198 slices][32ch] (12672 B) then co_s[224][66] (29568 B)
    __shared__ u16 pool[224 * 66];

    // ===== stage 0: halo -> xt =====
    {
        u16* xt = pool;
#pragma unroll
        for (int it = 0; it < 4; ++it) {
            int t = it * 256 + tid;
            if (t < 792) {
                int s = t >> 2, c = t & 3;
                int ry = s / 66, cx = s - ry * 66;
                int row = h0 + ry - 1, col = w0 + cx - 1;
                uint4 v = {0u, 0u, 0u, 0u};
                if (((unsigned)row < (unsigned)Hc) && ((unsigned)col < (unsigned)Wc))
                    v = *(const uint4*)(t0 + ((size_t)(b * HWc + row * Wc + col)) * 32 + c * 8);
                *(uint4*)(xt + (size_t)t * 8) = v;
            }
        }
    }
    __syncthreads();

    // ===== phase 1: offset conv (no per-tap barriers) =====
    const int wm = wv >> 1, wn = wv & 1;
    const int rm = wm * 32, cn = wn * 112;
    f32x4 acc[2][7];
#pragma unroll
    for (int mf = 0; mf < 2; ++mf)
#pragma unroll
        for (int nf = 0; nf < 7; ++nf)
            acc[mf][nf] = f32x4{0.f, 0.f, 0.f, 0.f};
    {
        const u16* xt = pool;
        const int r0 = rm + (lane & 15);
        const int kg8 = (lane >> 4) * 8;
#pragma unroll
        for (int kyi = 0; kyi < 3; ++kyi) {
#pragma unroll
            for (int kxi = 0; kxi < 3; ++kxi) {
                const int s9 = kyi * 3 + kxi;
                bf16x8 aF0 = __builtin_bit_cast(bf16x8,
                    *(const uint4*)(xt + (size_t)(kyi * 66 + r0 + kxi) * 32 + kg8));
                bf16x8 aF1 = __builtin_bit_cast(bf16x8,
                    *(const uint4*)(xt + (size_t)(kyi * 66 + r0 + 16 + kxi) * 32 + kg8));
#pragma unroll
                for (int nf = 0; nf < 7; ++nf) {
                    bf16x8 bF = __builtin_bit_cast(
                        bf16x8,
                        *(const uint4*)(wfragO + (((size_t)s9 * 14 + wn * 7 + nf) * 64 + lane) * 8));
                    acc[0][nf] = __builtin_amdgcn_mfma_f32_16x16x32_bf16(aF0, bF, acc[0][nf], 0, 0, 0);
                    acc[1][nf] = __builtin_amdgcn_mfma_f32_16x16x32_bf16(aF1, bF, acc[1][nf], 0, 0, 0);
                }
            }
        }
    }
    __syncthreads();   // all xt reads done before co_s overwrites the pool

    // ===== phase 1b: epilogue -> co_s =====
    u16* co_s = pool;
#pragma unroll
    for (int nf = 0; nf < 7; ++nf) {
        const int o = cn + nf * 16 + (lane & 15);
        const float bs = biasO[o];
        const bool sig = (o >= 144);
#pragma unroll
        for (int mf = 0; mf < 2; ++mf) {
            const int mb = rm + mf * 16 + ((lane >> 4) << 2);
            float v0 = acc[mf][nf][0] + bs, v1 = acc[mf][nf][1] + bs;
            float v2 = acc[mf][nf][2] + bs, v3 = acc[mf][nf][3] + bs;
            if (sig) {
                v0 = __builtin_amdgcn_rcpf(1.f + __builtin_amdgcn_exp2f(-v0 * 1.44269504f));
                v1 = __builtin_amdgcn_rcpf(1.f + __builtin_amdgcn_exp2f(-v1 * 1.44269504f));
                v2 = __builtin_amdgcn_rcpf(1.f + __builtin_amdgcn_exp2f(-v2 * 1.44269504f));
                v3 = __builtin_amdgcn_rcpf(1.f + __builtin_amdgcn_exp2f(-v3 * 1.44269504f));
            }
            *(u32*)&co_s[o * 66 + mb]     = cvtpk(v0, v1);
            *(u32*)&co_s[o * 66 + mb + 2] = cvtpk(v2, v3);
        }
    }
    __syncthreads();

    // ===== phase 2: DCN, 3-tap batches, zero-padded planes =====
    {
        const int kg = lane >> 4;                 // dg pair {2kg, 2kg+1}
        const int pixb = wv * 16 + (lane & 15);   // pixel within block
        const int hw = hwb + pixb;
        const int hh = hw / Wc;
        const int wwp = hw - hh * Wc;

        f32x4 acc0 = {0.f, 0.f, 0.f, 0.f};
        f32x4 acc1 = {0.f, 0.f, 0.f, 0.f};

#pragma unroll 1
        for (int kb = 0; kb < 9; kb += 3) {
            float w4[3][2][4];
            uint2 cc[3][2][4];

            // ---- stage A: co_s reads + padded addresses + issue ALL 24 gathers ----
#pragma unroll
            for (int t = 0; t < 3; ++t) {
                const int k = kb + t;
                const int kyi = k / 3, kxi = k - kyi * 3;
#pragma unroll
                for (int dgi = 0; dgi < 2; ++dgi) {
                    const int dg = 2 * kg + dgi;
                    const int offch = dg * 9 + k;
                    float dy = bf2f(co_s[offch * 66 + pixb]);
                    float dx = bf2f(co_s[(72 + offch) * 66 + pixb]);
                    float m  = bf2f(co_s[(144 + offch) * 66 + pixb]);

                    float py = dy + (float)(hh + kyi - 1);
                    float px = dx + (float)(wwp + kxi - 1);
                    float y0f = floorf(py), x0f = floorf(px);
                    float wy = py - y0f, wx = px - x0f;
                    int y0 = (int)y0f, x0 = (int)x0f;

                    // padded coords: valid range [0,193]; pad rows/cols are zeros
                    int yA = min(max(y0 + 1, 0), 193);
                    int yB = min(max(y0 + 2, 0), 193);
                    int xA = min(max(x0 + 1, 0), 193);
                    int xB = min(max(x0 + 2, 0), 193);

                    float w1y = 1.f - wy, w1x = 1.f - wx;
                    w4[t][dgi][0] = w1y * w1x * m;
                    w4[t][dgi][1] = w1y * wx  * m;
                    w4[t][dgi][2] = wy  * w1x * m;
                    w4[t][dgi][3] = wy  * wx  * m;

                    const u16* pp = imgp + ((size_t)(b * 8 + dg)) * PLANE * 4;
                    cc[t][dgi][0] = *(const uint2*)(pp + (size_t)((yA << 8) + xA) * 4);
                    cc[t][dgi][1] = *(const uint2*)(pp + (size_t)((yA << 8) + xB) * 4);
                    cc[t][dgi][2] = *(const uint2*)(pp + (size_t)((yB << 8) + xA) * 4);
                    cc[t][dgi][3] = *(const uint2*)(pp + (size_t)((yB << 8) + xB) * 4);
                }
            }

            // ---- stage B: packed bilinear + cvt_pk + MFMA ----
#pragma unroll
            for (int t = 0; t < 3; ++t) {
                const int k = kb + t;
                u32 pk[4];
#pragma unroll
                for (int dgi = 0; dgi < 2; ++dgi) {
                    f32x2 sA = unpk(cc[t][dgi][0].x) * w4[t][dgi][0]
                             + unpk(cc[t][dgi][1].x) * w4[t][dgi][1]
                             + unpk(cc[t][dgi][2].x) * w4[t][dgi][2]
                             + unpk(cc[t][dgi][3].x) * w4[t][dgi][3];
                    f32x2 sB = unpk(cc[t][dgi][0].y) * w4[t][dgi][0]
                             + unpk(cc[t][dgi][1].y) * w4[t][dgi][1]
                             + unpk(cc[t][dgi][2].y) * w4[t][dgi][2]
                             + unpk(cc[t][dgi][3].y) * w4[t][dgi][3];
                    pk[dgi * 2 + 0] = cvtpk(sA.x, sA.y);
                    pk[dgi * 2 + 1] = cvtpk(sB.x, sB.y);
                }

                bf16x8 aF = __builtin_bit_cast(bf16x8, uint4{pk[0], pk[1], pk[2], pk[3]});
                bf16x8 bF0 = __builtin_bit_cast(bf16x8,
                    *(const uint4*)(wfragD + ((size_t)(k * 2 + 0) * 64 + lane) * 8));
                bf16x8 bF1 = __builtin_bit_cast(bf16x8,
                    *(const uint4*)(wfragD + ((size_t)(k * 2 + 1) * 64 + lane) * 8));
                acc0 = __builtin_amdgcn_mfma_f32_16x16x32_bf16(aF, bF0, acc0, 0, 0, 0);
                acc1 = __builtin_amdgcn_mfma_f32_16x16x32_bf16(aF, bF1, acc1, 0, 0, 0);
            }
        }

        // epilogue: acc0[0..3] = 4 consecutive pixels -> one f32x4 store per row
        const int hw0 = hwb + wv * 16 + ((lane >> 4) << 2);
        float* ob = out + (size_t)b * 32 * HWc;
        const int oL = lane & 15;
        const float bs0 = biasD[oL], bs1 = biasD[16 + oL];
        f32x4 o0 = {acc0[0] + bs0, acc0[1] + bs0, acc0[2] + bs0, acc0[3] + bs0};
        f32x4 o1 = {acc1[0] + bs1, acc1[1] + bs1, acc1[2] + bs1, acc1[3] + bs1};
        *(f32x4*)(ob + (size_t)oL * HWc + hw0) = o0;
        *(f32x4*)(ob + (size_t)(16 + oL) * HWc + hw0) = o1;
    }
}

extern "C" void kernel_launch(void* const* d_in, const int* in_sizes, int n_in,
                              void* d_out, int out_size, void* d_ws, size_t ws_size,
                              hipStream_t stream) {
    const float* img_ref  = (const float*)d_in[0];
    const float* img      = (const float*)d_in[1];
    const float* conv1_w  = (const float*)d_in[2];
    const float* conv1_b  = (const float*)d_in[3];
    const float* conv2a_w = (const float*)d_in[4];
    const float* conv2a_b = (const float*)d_in[5];
    const float* conv2b_w = (const float*)d_in[6];
    const float* conv2b_b = (const float*)d_in[7];
    const float* off_w    = (const float*)d_in[8];
    const float* off_b    = (const float*)d_in[9];
    const float* dcn_w    = (const float*)d_in[10];
    const float* dcn_b    = (const float*)d_in[11];

    float* wsf = (float*)d_ws;
    u16* frag = (u16*)((char*)d_ws + FRAG_BYTE);
    u16* t0   = (u16*)((char*)d_ws + T0_BYTE);
    u16* t1   = (u16*)((char*)d_ws + T1_BYTE);
    u16* imgp = (u16*)((char*)d_ws + IMG_BYTE);
    float* out = (float*)d_out;

    // zero the padded gather planes (border must be 0; interior overwritten below)
    hipMemsetAsync(imgp, 0, IMG_SZ, stream);

    prep_k<<<370, 256, 0, stream>>>(conv1_w, conv1_b, conv2a_w, conv2a_b,
                                    conv2b_w, conv2b_b, off_w, off_b,
                                    dcn_w, dcn_b, wsf, frag);

    // conv1x1: [NPIX x 64] @ [64 x 32] -> t0 (ch-last); also dumps img into padded planes
    conv_mfma_k<4, 1, 2, 2, 32, 2, 2, 0, true, true>
        <<<NPIX / 128, 256, 0, stream>>>(img_ref, img, frag + FR1_U, wsf + WF_B1, t0, imgp);

    // conv2a: t0 -> t1
    conv_mfma_k<4, 1, 2, 2, 32, 2, 9, 1, true, false>
        <<<NPIX / 128, 256, 0, stream>>>(t0, nullptr, frag + FRA_U, wsf + WF_B2A, t1, nullptr);

    // conv2b: t1 -> t0
    conv_mfma_k<4, 1, 2, 2, 32, 2, 9, 1, true, false>
        <<<NPIX / 128, 256, 0, stream>>>(t1, nullptr, frag + FRB_U, wsf + WF_B2B, t0, nullptr);

    // fused offset conv + DCN (XCD-swizzled inside kernel)
    offdcn_k<<<NPIX / 64, 256, 0, stream>>>(t0, imgp, frag + FRO_U, frag + FRD_U,
                                            wsf + WF_BO, wsf + WF_BD, out);
}

// Round 12
// 107.421 us; speedup vs baseline: 5.9397x; 1.0405x over previous
//
#include <hip/hip_runtime.h>

#define Hc   192
#define Wc   192
#define HWc  (Hc * Wc)          // 36864
#define NPIX (4 * HWc)          // 147456
#define Hp   194                // padded rows: y+1 in [0,193]
#define Wp   256                // padded cols (shift-addressable)
#define PLANE (Hp * Wp)         // px-slots per (b,dg) plane, 4 ch each

typedef float f32x4 __attribute__((ext_vector_type(4)));
typedef float f32x2 __attribute__((ext_vector_type(2)));
typedef __bf16 bf16x8 __attribute__((ext_vector_type(8)));
typedef unsigned short u16;
typedef unsigned int u32;

// ---- workspace layout ----
#define WF_BO    0      // 224 (offset-conv bias, padded 216->224)
#define WF_B1    224
#define WF_B2A   256
#define WF_B2B   288
#define WF_BD    320    // end 352 floats = 1408 B
#define FR1_U    0      // conv1   [2][2][64][8]   2048
#define FRA_U    2048   // conv2a  [9][2][64][8]   9216
#define FRB_U    11264  // conv2b  [9][2][64][8]   9216
#define FRO_U    20480  // offset  [9][14][64][8]  64512
#define FRD_U    84992  // dcn     [9][2][64][8]   9216  (K-within-32 = dg*4+cg)
#define FRAG_U_TOT 94208
#define FRAG_BYTE 1408
#define T0_BYTE  (FRAG_BYTE + FRAG_U_TOT * 2)        // [NPIX][32] bf16 ch-last
#define T1_BYTE  (T0_BYTE + NPIX * 32 * 2)
#define IMG_BYTE (T1_BYTE + NPIX * 32 * 2)           // [4][8][Hp][Wp][4] bf16 zero-padded
#define IMG_SZ   ((size_t)4 * 8 * PLANE * 4 * 2)

__device__ __forceinline__ u16 f2bf(float f) {
    u32 u = __float_as_uint(f);
    u32 r = u + 0x7fffu + ((u >> 16) & 1u);
    return (u16)(r >> 16);
}
__device__ __forceinline__ float bf2f(u16 v) {
    return __uint_as_float(((u32)v) << 16);
}
__device__ __forceinline__ u32 cvtpk(float a, float b) {
    u32 r;
    asm("v_cvt_pk_bf16_f32 %0, %1, %2" : "=v"(r) : "v"(a), "v"(b));
    return r;
}
__device__ __forceinline__ f32x2 unpk(u32 h) {
    return f32x2{__uint_as_float(h << 16), __uint_as_float(h & 0xffff0000u)};
}

// ---------------- prep: biases (f32) + MFMA weight fragments (bf16) ----------------
__global__ __launch_bounds__(256) void prep_k(
    const float* __restrict__ w1,  const float* __restrict__ b1,
    const float* __restrict__ w2a, const float* __restrict__ b2a,
    const float* __restrict__ w2b, const float* __restrict__ b2b,
    const float* __restrict__ wo,  const float* __restrict__ bo,
    const float* __restrict__ wd,  const float* __restrict__ bd,
    float* __restrict__ wsf, u16* __restrict__ frag)
{
    int i = blockIdx.x * 256 + threadIdx.x;
    if (i < 224)      { wsf[WF_BO + i]  = (i < 216) ? bo[i] : 0.f; return; }
    if (i < 256)      { wsf[WF_B1  + i - 224] = b1[i - 224];  return; }
    if (i < 288)      { wsf[WF_B2A + i - 256] = b2a[i - 256]; return; }
    if (i < 320)      { wsf[WF_B2B + i - 288] = b2b[i - 288]; return; }
    if (i < 352)      { wsf[WF_BD  + i - 320] = bd[i - 320];  return; }
    int fi = i - 352;
    if (fi < 2048) {          // conv1 frags
        int s = fi >> 10, l = (fi >> 3) & 63, j = fi & 7;
        int nt = (fi >> 9) & 1;
        int o = nt * 16 + (l & 15);
        int ci = s * 32 + ((l >> 4) << 3) + j;
        frag[FR1_U + fi] = f2bf(w1[o * 64 + ci]);
        return;
    }
    fi -= 2048;
    if (fi < 9216) {          // conv2a frags
        int s = fi / 1024, r = fi - s * 1024;
        int nt = r >> 9, l = (r >> 3) & 63, j = r & 7;
        int o = nt * 16 + (l & 15);
        int ci = ((l >> 4) << 3) + j;
        frag[FRA_U + fi] = f2bf(w2a[(o * 32 + ci) * 9 + s]);
        return;
    }
    fi -= 9216;
    if (fi < 9216) {          // conv2b frags
        int s = fi / 1024, r = fi - s * 1024;
        int nt = r >> 9, l = (r >> 3) & 63, j = r & 7;
        int o = nt * 16 + (l & 15);
        int ci = ((l >> 4) << 3) + j;
        frag[FRB_U + fi] = f2bf(w2b[(o * 32 + ci) * 9 + s]);
        return;
    }
    fi -= 9216;
    if (fi < 64512) {         // offset-conv frags, COUT padded to 224
        int s = fi / 7168, r = fi - s * 7168;
        int nt = r >> 9, l = (r >> 3) & 63, j = r & 7;
        int o = nt * 16 + (l & 15);
        int ci = ((l >> 4) << 3) + j;
        frag[FRO_U + fi] = f2bf((o < 216) ? wo[(o * 32 + ci) * 9 + s] : 0.f);
        return;
    }
    fi -= 64512;
    if (fi < 9216) {          // dcn frags
        int k = fi / 1024, r = fi - k * 1024;
        int nt = r >> 9, l = (r >> 3) & 63, j = r & 7;
        int o = nt * 16 + (l & 15);
        int ci = ((l >> 4) << 3) + j;
        frag[FRD_U + fi] = f2bf(wd[o * 288 + ci * 9 + k]);
        return;
    }
}

// ---------------- conv1x1 via MFMA (MODE 0 only) ----------------
__global__ __launch_bounds__(256) void conv1x1_mfma_k(
    const float* __restrict__ f0, const float* __restrict__ f1,
    const u16* __restrict__ wfrag, const float* __restrict__ bias,
    u16* __restrict__ y, u16* __restrict__ dump)
{
    constexpr int M_BLK = 128;
    const int tid = threadIdx.x, lane = tid & 63, wv = tid >> 6;
    const int bid = blockIdx.x;
    const int swz = (bid & 7) * (gridDim.x >> 3) + (bid >> 3);
    const int m0 = swz * M_BLK;
    const int b = m0 / HWc, hwb = m0 - b * HWc;
    const int rm = wv * 32;

    __shared__ uint4 At4[512];

    int pxA[2], hA[2], wA[2], kgA[2];
#pragma unroll
    for (int it = 0; it < 2; ++it) {
        int st = it * 256 + tid;
        int rowl = ((st >> 6) << 4) | (st & 15);
        kgA[it] = (st >> 4) & 3;
        pxA[it] = rowl;
        int hwp = hwb + rowl;
        hA[it] = hwp / Wc;
        wA[it] = hwp - hA[it] * Wc;
    }

    f32x4 acc[2][2];
#pragma unroll
    for (int mf = 0; mf < 2; ++mf)
#pragma unroll
        for (int nf = 0; nf < 2; ++nf)
            acc[mf][nf] = f32x4{0.f, 0.f, 0.f, 0.f};

    for (int s = 0; s < 2; ++s) {
        const float* fs = (s == 0) ? f0 : f1;
#pragma unroll
        for (int it = 0; it < 2; ++it) {
            const float* pl = fs + ((size_t)b * 32 + kgA[it] * 8) * HWc + (hwb + pxA[it]);
            u32 p0, p1, p2, p3;
            {
                u32 a0 = f2bf(pl[0 * HWc]), a1 = f2bf(pl[1 * HWc]);
                u32 a2 = f2bf(pl[2 * HWc]), a3 = f2bf(pl[3 * HWc]);
                u32 a4 = f2bf(pl[4 * HWc]), a5 = f2bf(pl[5 * HWc]);
                u32 a6 = f2bf(pl[6 * HWc]), a7 = f2bf(pl[7 * HWc]);
                p0 = a0 | (a1 << 16); p1 = a2 | (a3 << 16);
                p2 = a4 | (a5 << 16); p3 = a6 | (a7 << 16);
            }
            uint4 v = {p0, p1, p2, p3};
            if (s == 1) {
                // zero-padded dg-planar dump of img
                size_t base = (((size_t)(b * 8 + kgA[it] * 2)) * PLANE
                               + (size_t)(hA[it] + 1) * Wp + (wA[it] + 1)) * 4;
                *(uint2*)(dump + base) = uint2{p0, p1};
                *(uint2*)(dump + base + (size_t)PLANE * 4) = uint2{p2, p3};
            }
            At4[it * 256 + tid] = v;
        }
        __syncthreads();

        bf16x8 aF[2];
#pragma unroll
        for (int mf = 0; mf < 2; ++mf)
            aF[mf] = __builtin_bit_cast(bf16x8, At4[((rm >> 4) + mf) * 64 + lane]);
#pragma unroll
        for (int nf = 0; nf < 2; ++nf) {
            bf16x8 bF = __builtin_bit_cast(
                bf16x8, *(const uint4*)(wfrag + (((size_t)s * 2 + nf) * 64 + lane) * 8));
#pragma unroll
            for (int mf = 0; mf < 2; ++mf)
                acc[mf][nf] = __builtin_amdgcn_mfma_f32_16x16x32_bf16(aF[mf], bF, acc[mf][nf], 0, 0, 0);
        }
        __syncthreads();
    }

#pragma unroll
    for (int nf = 0; nf < 2; ++nf) {
        int o = nf * 16 + (lane & 15);
        float bs = bias[o];
#pragma unroll
        for (int mf = 0; mf < 2; ++mf) {
#pragma unroll
            for (int r = 0; r < 4; ++r) {
                int m = m0 + rm + mf * 16 + ((lane >> 4) << 2) + r;
                y[(size_t)m * 32 + o] = f2bf(acc[mf][nf][r] + bs);
            }
        }
    }
}

// ---------------- 3x3 conv, halo-LDS single-barrier structure ----------------
// Block = 64 px (one row segment). Stage 3x66 halo once -> 9 taps of pure
// ds_read_b128 + MFMA, no per-tap barriers. Wave wv owns rows wv*16..+15.
__global__ __launch_bounds__(256, 4) void conv3x3h_k(
    const u16* __restrict__ src,   // [NPIX][32] bf16 ch-last
    const u16* __restrict__ wfrag, // [9][2][64][8]
    const float* __restrict__ bias,
    u16* __restrict__ dst)         // [NPIX][32]
{
    const int tid = threadIdx.x, lane = tid & 63, wv = tid >> 6;
    const int bid = blockIdx.x;
    const int swz = (bid & 7) * (gridDim.x >> 3) + (bid >> 3);
    const int m0 = swz * 64;
    const int b = m0 / HWc, hwb = m0 - b * HWc;
    const int h0 = hwb / Wc, w0 = hwb - h0 * Wc;

    __shared__ u16 xt[198 * 32];   // 12672 B

#pragma unroll
    for (int it = 0; it < 4; ++it) {
        int t = it * 256 + tid;
        if (t < 792) {
            int s = t >> 2, c = t & 3;
            int ry = s / 66, cx = s - ry * 66;
            int row = h0 + ry - 1, col = w0 + cx - 1;
            uint4 v = {0u, 0u, 0u, 0u};
            if (((unsigned)row < (unsigned)Hc) && ((unsigned)col < (unsigned)Wc))
                v = *(const uint4*)(src + ((size_t)(b * HWc + row * Wc + col)) * 32 + c * 8);
            *(uint4*)(xt + (size_t)t * 8) = v;
        }
    }
    __syncthreads();

    f32x4 acc0 = {0.f, 0.f, 0.f, 0.f};
    f32x4 acc1 = {0.f, 0.f, 0.f, 0.f};
    const int r0 = wv * 16 + (lane & 15);
    const int kg8 = (lane >> 4) * 8;
#pragma unroll
    for (int kyi = 0; kyi < 3; ++kyi) {
#pragma unroll
        for (int kxi = 0; kxi < 3; ++kxi) {
            const int s9 = kyi * 3 + kxi;
            bf16x8 aF = __builtin_bit_cast(bf16x8,
                *(const uint4*)(xt + (size_t)(kyi * 66 + r0 + kxi) * 32 + kg8));
            bf16x8 bF0 = __builtin_bit_cast(bf16x8,
                *(const uint4*)(wfrag + (((size_t)s9 * 2 + 0) * 64 + lane) * 8));
            bf16x8 bF1 = __builtin_bit_cast(bf16x8,
                *(const uint4*)(wfrag + (((size_t)s9 * 2 + 1) * 64 + lane) * 8));
            acc0 = __builtin_amdgcn_mfma_f32_16x16x32_bf16(aF, bF0, acc0, 0, 0, 0);
            acc1 = __builtin_amdgcn_mfma_f32_16x16x32_bf16(aF, bF1, acc1, 0, 0, 0);
        }
    }

    const int oL = lane & 15;
    const float bs0 = bias[oL], bs1 = bias[16 + oL];
    u16* dp = dst + (size_t)(m0 + wv * 16 + ((lane >> 4) << 2)) * 32;
#pragma unroll
    for (int r = 0; r < 4; ++r) {
        dp[r * 32 + oL]      = f2bf(acc0[r] + bs0);
        dp[r * 32 + 16 + oL] = f2bf(acc1[r] + bs1);
    }
}

// ---------------- FUSED: offset conv + modulated deformable conv ----------------
__global__ __launch_bounds__(256, 4) void offdcn_k(
    const u16* __restrict__ t0,     // [NPIX][32] bf16 ch-last (feat)
    const u16* __restrict__ imgp,   // [4][8][Hp][Wp][4] bf16 zero-padded
    const u16* __restrict__ wfragO, // [9][14][64][8]
    const u16* __restrict__ wfragD, // [9][2][64][8]
    const float* __restrict__ biasO,// 224
    const float* __restrict__ biasD,// 32
    float* __restrict__ out)        // [4][32][HW] f32
{
    const int tid = threadIdx.x, lane = tid & 63, wv = tid >> 6;
    const int bid = blockIdx.x;
    const int swz = (bid & 7) * (gridDim.x >> 3) + (bid >> 3);
    const int m0 = swz * 64;
    const int b = m0 / HWc, hwb = m0 - b * HWc;
    const int h0 = hwb / Wc, w0 = hwb - h0 * Wc;

    // union: xt[198][32] (12672 B) then co_s[224][66] (29568 B)
    __shared__ u16 pool[224 * 66];

    // ===== stage 0: halo -> xt =====
    {
        u16* xt = pool;
#pragma unroll
        for (int it = 0; it < 4; ++it) {
            int t = it * 256 + tid;
            if (t < 792) {
                int s = t >> 2, c = t & 3;
                int ry = s / 66, cx = s - ry * 66;
                int row = h0 + ry - 1, col = w0 + cx - 1;
                uint4 v = {0u, 0u, 0u, 0u};
                if (((unsigned)row < (unsigned)Hc) && ((unsigned)col < (unsigned)Wc))
                    v = *(const uint4*)(t0 + ((size_t)(b * HWc + row * Wc + col)) * 32 + c * 8);
                *(uint4*)(xt + (size_t)t * 8) = v;
            }
        }
    }
    __syncthreads();

    // ===== phase 1: offset conv (no per-tap barriers) =====
    const int wm = wv >> 1, wn = wv & 1;
    const int rm = wm * 32, cn = wn * 112;
    f32x4 acc[2][7];
#pragma unroll
    for (int mf = 0; mf < 2; ++mf)
#pragma unroll
        for (int nf = 0; nf < 7; ++nf)
            acc[mf][nf] = f32x4{0.f, 0.f, 0.f, 0.f};
    {
        const u16* xt = pool;
        const int r0 = rm + (lane & 15);
        const int kg8 = (lane >> 4) * 8;
#pragma unroll
        for (int kyi = 0; kyi < 3; ++kyi) {
#pragma unroll
            for (int kxi = 0; kxi < 3; ++kxi) {
                const int s9 = kyi * 3 + kxi;
                bf16x8 aF0 = __builtin_bit_cast(bf16x8,
                    *(const uint4*)(xt + (size_t)(kyi * 66 + r0 + kxi) * 32 + kg8));
                bf16x8 aF1 = __builtin_bit_cast(bf16x8,
                    *(const uint4*)(xt + (size_t)(kyi * 66 + r0 + 16 + kxi) * 32 + kg8));
#pragma unroll
                for (int nf = 0; nf < 7; ++nf) {
                    bf16x8 bF = __builtin_bit_cast(
                        bf16x8,
                        *(const uint4*)(wfragO + (((size_t)s9 * 14 + wn * 7 + nf) * 64 + lane) * 8));
                    acc[0][nf] = __builtin_amdgcn_mfma_f32_16x16x32_bf16(aF0, bF, acc[0][nf], 0, 0, 0);
                    acc[1][nf] = __builtin_amdgcn_mfma_f32_16x16x32_bf16(aF1, bF, acc[1][nf], 0, 0, 0);
                }
            }
        }
    }
    __syncthreads();   // all xt reads done before co_s overwrites the pool

    // ===== phase 1b: epilogue -> co_s =====
    u16* co_s = pool;
#pragma unroll
    for (int nf = 0; nf < 7; ++nf) {
        const int o = cn + nf * 16 + (lane & 15);
        const float bs = biasO[o];
        const bool sig = (o >= 144);
#pragma unroll
        for (int mf = 0; mf < 2; ++mf) {
            const int mb = rm + mf * 16 + ((lane >> 4) << 2);
            float v0 = acc[mf][nf][0] + bs, v1 = acc[mf][nf][1] + bs;
            float v2 = acc[mf][nf][2] + bs, v3 = acc[mf][nf][3] + bs;
            if (sig) {
                v0 = __builtin_amdgcn_rcpf(1.f + __builtin_amdgcn_exp2f(-v0 * 1.44269504f));
                v1 = __builtin_amdgcn_rcpf(1.f + __builtin_amdgcn_exp2f(-v1 * 1.44269504f));
                v2 = __builtin_amdgcn_rcpf(1.f + __builtin_amdgcn_exp2f(-v2 * 1.44269504f));
                v3 = __builtin_amdgcn_rcpf(1.f + __builtin_amdgcn_exp2f(-v3 * 1.44269504f));
            }
            *(u32*)&co_s[o * 66 + mb]     = cvtpk(v0, v1);
            *(u32*)&co_s[o * 66 + mb + 2] = cvtpk(v2, v3);
        }
    }
    __syncthreads();

    // ===== phase 2: DCN, 3-tap batches, zero-padded planes, saddr gathers =====
    {
        const int kg = lane >> 4;                 // dg pair {2kg, 2kg+1}
        const int pixb = wv * 16 + (lane & 15);   // pixel within block
        const int hw = hwb + pixb;
        const int hh = hw / Wc;
        const int wwp = hw - hh * Wc;
        const float fh = (float)(hh - 1);         // lane-constant parts
        const float fw = (float)(wwp - 1);

        // uniform base + per-lane 32-bit element offsets -> saddr-form loads
        const u16* gb = imgp + (size_t)b * 8 * PLANE * 4;
        const u32 dgp[2] = {(u32)((2 * kg + 0) * (PLANE * 4)),
                            (u32)((2 * kg + 1) * (PLANE * 4))};

        f32x4 acc0 = {0.f, 0.f, 0.f, 0.f};
        f32x4 acc1 = {0.f, 0.f, 0.f, 0.f};

#pragma unroll 1
        for (int kb = 0; kb < 9; kb += 3) {
            float w4[3][2][4];
            uint2 cc[3][2][4];

            // ---- stage A: co_s reads + addresses + issue ALL 24 gathers ----
#pragma unroll
            for (int t = 0; t < 3; ++t) {
                const int k = kb + t;
                const int kyi = k / 3, kxi = k - kyi * 3;
#pragma unroll
                for (int dgi = 0; dgi < 2; ++dgi) {
                    const int offch = (2 * kg + dgi) * 9 + k;
                    float dy = bf2f(co_s[offch * 66 + pixb]);
                    float dx = bf2f(co_s[(72 + offch) * 66 + pixb]);
                    float m  = bf2f(co_s[(144 + offch) * 66 + pixb]);

                    float py = dy + (fh + (float)kyi);
                    float px = dx + (fw + (float)kxi);
                    float y0f = floorf(py), x0f = floorf(px);
                    float wy = py - y0f, wx = px - x0f;
                    int y0 = (int)y0f, x0 = (int)x0f;

                    int yA = min(max(y0 + 1, 0), 193);
                    int yB = min(max(y0 + 2, 0), 193);
                    int xA = min(max(x0 + 1, 0), 193);
                    int xB = min(max(x0 + 2, 0), 193);

                    float w1y = 1.f - wy, w1x = 1.f - wx;
                    w4[t][dgi][0] = w1y * w1x * m;
                    w4[t][dgi][1] = w1y * wx  * m;
                    w4[t][dgi][2] = wy  * w1x * m;
                    w4[t][dgi][3] = wy  * wx  * m;

                    u32 rA = dgp[dgi] + ((u32)yA << 10);
                    u32 rB = dgp[dgi] + ((u32)yB << 10);
                    u32 xA4 = (u32)xA << 2, xB4 = (u32)xB << 2;
                    cc[t][dgi][0] = *(const uint2*)(gb + (rA + xA4));
                    cc[t][dgi][1] = *(const uint2*)(gb + (rA + xB4));
                    cc[t][dgi][2] = *(const uint2*)(gb + (rB + xA4));
                    cc[t][dgi][3] = *(const uint2*)(gb + (rB + xB4));
                }
            }

            // ---- stage B: packed bilinear + cvt_pk + MFMA ----
#pragma unroll
            for (int t = 0; t < 3; ++t) {
                const int k = kb + t;
                u32 pk[4];
#pragma unroll
                for (int dgi = 0; dgi < 2; ++dgi) {
                    f32x2 sA = unpk(cc[t][dgi][0].x) * w4[t][dgi][0]
                             + unpk(cc[t][dgi][1].x) * w4[t][dgi][1]
                             + unpk(cc[t][dgi][2].x) * w4[t][dgi][2]
                             + unpk(cc[t][dgi][3].x) * w4[t][dgi][3];
                    f32x2 sB = unpk(cc[t][dgi][0].y) * w4[t][dgi][0]
                             + unpk(cc[t][dgi][1].y) * w4[t][dgi][1]
                             + unpk(cc[t][dgi][2].y) * w4[t][dgi][2]
                             + unpk(cc[t][dgi][3].y) * w4[t][dgi][3];
                    pk[dgi * 2 + 0] = cvtpk(sA.x, sA.y);
                    pk[dgi * 2 + 1] = cvtpk(sB.x, sB.y);
                }

                bf16x8 aF = __builtin_bit_cast(bf16x8, uint4{pk[0], pk[1], pk[2], pk[3]});
                bf16x8 bF0 = __builtin_bit_cast(bf16x8,
                    *(const uint4*)(wfragD + ((size_t)(k * 2 + 0) * 64 + lane) * 8));
                bf16x8 bF1 = __builtin_bit_cast(bf16x8,
                    *(const uint4*)(wfragD + ((size_t)(k * 2 + 1) * 64 + lane) * 8));
                acc0 = __builtin_amdgcn_mfma_f32_16x16x32_bf16(aF, bF0, acc0, 0, 0, 0);
                acc1 = __builtin_amdgcn_mfma_f32_16x16x32_bf16(aF, bF1, acc1, 0, 0, 0);
            }
        }

        // epilogue: f32x4 stores (4 consecutive pixels per acc)
        const int hw0 = hwb + wv * 16 + ((lane >> 4) << 2);
        float* ob = out + (size_t)b * 32 * HWc;
        const int oL = lane & 15;
        const float bs0 = biasD[oL], bs1 = biasD[16 + oL];
        f32x4 o0 = {acc0[0] + bs0, acc0[1] + bs0, acc0[2] + bs0, acc0[3] + bs0};
        f32x4 o1 = {acc1[0] + bs1, acc1[1] + bs1, acc1[2] + bs1, acc1[3] + bs1};
        *(f32x4*)(ob + (size_t)oL * HWc + hw0) = o0;
        *(f32x4*)(ob + (size_t)(16 + oL) * HWc + hw0) = o1;
    }
}

extern "C" void kernel_launch(void* const* d_in, const int* in_sizes, int n_in,
                              void* d_out, int out_size, void* d_ws, size_t ws_size,
                              hipStream_t stream) {
    const float* img_ref  = (const float*)d_in[0];
    const float* img      = (const float*)d_in[1];
    const float* conv1_w  = (const float*)d_in[2];
    const float* conv1_b  = (const float*)d_in[3];
    const float* conv2a_w = (const float*)d_in[4];
    const float* conv2a_b = (const float*)d_in[5];
    const float* conv2b_w = (const float*)d_in[6];
    const float* conv2b_b = (const float*)d_in[7];
    const float* off_w    = (const float*)d_in[8];
    const float* off_b    = (const float*)d_in[9];
    const float* dcn_w    = (const float*)d_in[10];
    const float* dcn_b    = (const float*)d_in[11];

    float* wsf = (float*)d_ws;
    u16* frag = (u16*)((char*)d_ws + FRAG_BYTE);
    u16* t0   = (u16*)((char*)d_ws + T0_BYTE);
    u16* t1   = (u16*)((char*)d_ws + T1_BYTE);
    u16* imgp = (u16*)((char*)d_ws + IMG_BYTE);
    float* out = (float*)d_out;

    // zero the padded gather planes (border must be 0; interior overwritten below)
    hipMemsetAsync(imgp, 0, IMG_SZ, stream);

    prep_k<<<370, 256, 0, stream>>>(conv1_w, conv1_b, conv2a_w, conv2a_b,
                                    conv2b_w, conv2b_b, off_w, off_b,
                                    dcn_w, dcn_b, wsf, frag);

    // conv1x1 -> t0 (ch-last) + padded dg-planar img dump
    conv1x1_mfma_k<<<NPIX / 128, 256, 0, stream>>>(
        img_ref, img, frag + FR1_U, wsf + WF_B1, t0, imgp);

    // conv2a: t0 -> t1 (halo single-barrier)
    conv3x3h_k<<<NPIX / 64, 256, 0, stream>>>(t0, frag + FRA_U, wsf + WF_B2A, t1);

    // conv2b: t1 -> t0
    conv3x3h_k<<<NPIX / 64, 256, 0, stream>>>(t1, frag + FRB_U, wsf + WF_B2B, t0);

    // fused offset conv + DCN
    offdcn_k<<<NPIX / 64, 256, 0, stream>>>(t0, imgp, frag + FRO_U, frag + FRD_U,
                                            wsf + WF_BO, wsf + WF_BD, out);
}

// Round 13
// 97.958 us; speedup vs baseline: 6.5134x; 1.0966x over previous
//
#include <hip/hip_runtime.h>

#define Hc   192
#define Wc   192
#define HWc  (Hc * Wc)          // 36864
#define NPIX (4 * HWc)          // 147456
#define Hp   194                // padded rows: data at y+1 in [1,192]; rows 0,193 zero
#define Wp   256                // padded cols: data at x+2 in [2,193]; cols 0,1,194..255 zero
#define PLANE (Hp * Wp)         // px-slots per (b,dg) plane, 4 ch each

typedef float f32x4 __attribute__((ext_vector_type(4)));
typedef float f32x2 __attribute__((ext_vector_type(2)));
typedef __bf16 bf16x8 __attribute__((ext_vector_type(8)));
typedef unsigned short u16;
typedef unsigned int u32;

// ---- workspace layout ----
#define WF_BO    0      // 224 (offset-conv bias, padded 216->224)
#define WF_B1    224
#define WF_B2A   256
#define WF_B2B   288
#define WF_BD    320    // end 352 floats = 1408 B
#define FR1_U    0      // conv1   [2][2][64][8]   2048
#define FRA_U    2048   // conv2a  [9][2][64][8]   9216
#define FRB_U    11264  // conv2b  [9][2][64][8]   9216
#define FRO_U    20480  // offset  [9][14][64][8]  64512
#define FRD_U    84992  // dcn     [9][2][64][8]   9216  (K-within-32 = dg*4+cg)
#define FRAG_U_TOT 94208
#define FRAG_BYTE 1408
#define T0_BYTE  (FRAG_BYTE + FRAG_U_TOT * 2)        // [NPIX][32] bf16 ch-last
#define T1_BYTE  (T0_BYTE + NPIX * 32 * 2)
#define IMG_BYTE (T1_BYTE + NPIX * 32 * 2)           // [4][8][Hp][Wp][4] bf16 zero-padded
#define IMG_SZ   ((size_t)4 * 8 * PLANE * 4 * 2)

__device__ __forceinline__ u16 f2bf(float f) {
    u32 u = __float_as_uint(f);
    u32 r = u + 0x7fffu + ((u >> 16) & 1u);
    return (u16)(r >> 16);
}
__device__ __forceinline__ float bf2f(u16 v) {
    return __uint_as_float(((u32)v) << 16);
}
__device__ __forceinline__ u32 cvtpk(float a, float b) {
    u32 r;
    asm("v_cvt_pk_bf16_f32 %0, %1, %2" : "=v"(r) : "v"(a), "v"(b));
    return r;
}
__device__ __forceinline__ f32x2 unpk(u32 h) {
    return f32x2{__uint_as_float(h << 16), __uint_as_float(h & 0xffff0000u)};
}

// ---------------- prep: biases (f32) + MFMA weight fragments (bf16) ----------------
__global__ __launch_bounds__(256) void prep_k(
    const float* __restrict__ w1,  const float* __restrict__ b1,
    const float* __restrict__ w2a, const float* __restrict__ b2a,
    const float* __restrict__ w2b, const float* __restrict__ b2b,
    const float* __restrict__ wo,  const float* __restrict__ bo,
    const float* __restrict__ wd,  const float* __restrict__ bd,
    float* __restrict__ wsf, u16* __restrict__ frag)
{
    int i = blockIdx.x * 256 + threadIdx.x;
    if (i < 224)      { wsf[WF_BO + i]  = (i < 216) ? bo[i] : 0.f; return; }
    if (i < 256)      { wsf[WF_B1  + i - 224] = b1[i - 224];  return; }
    if (i < 288)      { wsf[WF_B2A + i - 256] = b2a[i - 256]; return; }
    if (i < 320)      { wsf[WF_B2B + i - 288] = b2b[i - 288]; return; }
    if (i < 352)      { wsf[WF_BD  + i - 320] = bd[i - 320];  return; }
    int fi = i - 352;
    if (fi < 2048) {          // conv1 frags
        int s = fi >> 10, l = (fi >> 3) & 63, j = fi & 7;
        int nt = (fi >> 9) & 1;
        int o = nt * 16 + (l & 15);
        int ci = s * 32 + ((l >> 4) << 3) + j;
        frag[FR1_U + fi] = f2bf(w1[o * 64 + ci]);
        return;
    }
    fi -= 2048;
    if (fi < 9216) {          // conv2a frags
        int s = fi / 1024, r = fi - s * 1024;
        int nt = r >> 9, l = (r >> 3) & 63, j = r & 7;
        int o = nt * 16 + (l & 15);
        int ci = ((l >> 4) << 3) + j;
        frag[FRA_U + fi] = f2bf(w2a[(o * 32 + ci) * 9 + s]);
        return;
    }
    fi -= 9216;
    if (fi < 9216) {          // conv2b frags
        int s = fi / 1024, r = fi - s * 1024;
        int nt = r >> 9, l = (r >> 3) & 63, j = r & 7;
        int o = nt * 16 + (l & 15);
        int ci = ((l >> 4) << 3) + j;
        frag[FRB_U + fi] = f2bf(w2b[(o * 32 + ci) * 9 + s]);
        return;
    }
    fi -= 9216;
    if (fi < 64512) {         // offset-conv frags, COUT padded to 224
        int s = fi / 7168, r = fi - s * 7168;
        int nt = r >> 9, l = (r >> 3) & 63, j = r & 7;
        int o = nt * 16 + (l & 15);
        int ci = ((l >> 4) << 3) + j;
        frag[FRO_U + fi] = f2bf((o < 216) ? wo[(o * 32 + ci) * 9 + s] : 0.f);
        return;
    }
    fi -= 64512;
    if (fi < 9216) {          // dcn frags
        int k = fi / 1024, r = fi - k * 1024;
        int nt = r >> 9, l = (r >> 3) & 63, j = r & 7;
        int o = nt * 16 + (l & 15);
        int ci = ((l >> 4) << 3) + j;
        frag[FRD_U + fi] = f2bf(wd[o * 288 + ci * 9 + k]);
        return;
    }
}

// ---------------- conv1x1 via MFMA ----------------
__global__ __launch_bounds__(256) void conv1x1_mfma_k(
    const float* __restrict__ f0, const float* __restrict__ f1,
    const u16* __restrict__ wfrag, const float* __restrict__ bias,
    u16* __restrict__ y, u16* __restrict__ dump)
{
    constexpr int M_BLK = 128;
    const int tid = threadIdx.x, lane = tid & 63, wv = tid >> 6;
    const int bid = blockIdx.x;
    const int swz = (bid & 7) * (gridDim.x >> 3) + (bid >> 3);
    const int m0 = swz * M_BLK;
    const int b = m0 / HWc, hwb = m0 - b * HWc;
    const int rm = wv * 32;

    __shared__ uint4 At4[512];

    int pxA[2], hA[2], wA[2], kgA[2];
#pragma unroll
    for (int it = 0; it < 2; ++it) {
        int st = it * 256 + tid;
        int rowl = ((st >> 6) << 4) | (st & 15);
        kgA[it] = (st >> 4) & 3;
        pxA[it] = rowl;
        int hwp = hwb + rowl;
        hA[it] = hwp / Wc;
        wA[it] = hwp - hA[it] * Wc;
    }

    f32x4 acc[2][2];
#pragma unroll
    for (int mf = 0; mf < 2; ++mf)
#pragma unroll
        for (int nf = 0; nf < 2; ++nf)
            acc[mf][nf] = f32x4{0.f, 0.f, 0.f, 0.f};

    for (int s = 0; s < 2; ++s) {
        const float* fs = (s == 0) ? f0 : f1;
#pragma unroll
        for (int it = 0; it < 2; ++it) {
            const float* pl = fs + ((size_t)b * 32 + kgA[it] * 8) * HWc + (hwb + pxA[it]);
            u32 p0, p1, p2, p3;
            {
                u32 a0 = f2bf(pl[0 * HWc]), a1 = f2bf(pl[1 * HWc]);
                u32 a2 = f2bf(pl[2 * HWc]), a3 = f2bf(pl[3 * HWc]);
                u32 a4 = f2bf(pl[4 * HWc]), a5 = f2bf(pl[5 * HWc]);
                u32 a6 = f2bf(pl[6 * HWc]), a7 = f2bf(pl[7 * HWc]);
                p0 = a0 | (a1 << 16); p1 = a2 | (a3 << 16);
                p2 = a4 | (a5 << 16); p3 = a6 | (a7 << 16);
            }
            uint4 v = {p0, p1, p2, p3};
            if (s == 1) {
                // zero-padded dg-planar dump: row = h+1, col = w+2
                size_t base = (((size_t)(b * 8 + kgA[it] * 2)) * PLANE
                               + (size_t)(hA[it] + 1) * Wp + (wA[it] + 2)) * 4;
                *(uint2*)(dump + base) = uint2{p0, p1};
                *(uint2*)(dump + base + (size_t)PLANE * 4) = uint2{p2, p3};
            }
            At4[it * 256 + tid] = v;
        }
        __syncthreads();

        bf16x8 aF[2];
#pragma unroll
        for (int mf = 0; mf < 2; ++mf)
            aF[mf] = __builtin_bit_cast(bf16x8, At4[((rm >> 4) + mf) * 64 + lane]);
#pragma unroll
        for (int nf = 0; nf < 2; ++nf) {
            bf16x8 bF = __builtin_bit_cast(
                bf16x8, *(const uint4*)(wfrag + (((size_t)s * 2 + nf) * 64 + lane) * 8));
#pragma unroll
            for (int mf = 0; mf < 2; ++mf)
                acc[mf][nf] = __builtin_amdgcn_mfma_f32_16x16x32_bf16(aF[mf], bF, acc[mf][nf], 0, 0, 0);
        }
        __syncthreads();
    }

#pragma unroll
    for (int nf = 0; nf < 2; ++nf) {
        int o = nf * 16 + (lane & 15);
        float bs = bias[o];
#pragma unroll
        for (int mf = 0; mf < 2; ++mf) {
#pragma unroll
            for (int r = 0; r < 4; ++r) {
                int m = m0 + rm + mf * 16 + ((lane >> 4) << 2) + r;
                y[(size_t)m * 32 + o] = f2bf(acc[mf][nf][r] + bs);
            }
        }
    }
}

// ---------------- 3x3 conv, halo-LDS single-barrier structure ----------------
__global__ __launch_bounds__(256, 4) void conv3x3h_k(
    const u16* __restrict__ src,   // [NPIX][32] bf16 ch-last
    const u16* __restrict__ wfrag, // [9][2][64][8]
    const float* __restrict__ bias,
    u16* __restrict__ dst)         // [NPIX][32]
{
    const int tid = threadIdx.x, lane = tid & 63, wv = tid >> 6;
    const int bid = blockIdx.x;
    const int swz = (bid & 7) * (gridDim.x >> 3) + (bid >> 3);
    const int m0 = swz * 64;
    const int b = m0 / HWc, hwb = m0 - b * HWc;
    const int h0 = hwb / Wc, w0 = hwb - h0 * Wc;

    __shared__ u16 xt[198 * 32];   // 12672 B

#pragma unroll
    for (int it = 0; it < 4; ++it) {
        int t = it * 256 + tid;
        if (t < 792) {
            int s = t >> 2, c = t & 3;
            int ry = s / 66, cx = s - ry * 66;
            int row = h0 + ry - 1, col = w0 + cx - 1;
            uint4 v = {0u, 0u, 0u, 0u};
            if (((unsigned)row < (unsigned)Hc) && ((unsigned)col < (unsigned)Wc))
                v = *(const uint4*)(src + ((size_t)(b * HWc + row * Wc + col)) * 32 + c * 8);
            *(uint4*)(xt + (size_t)t * 8) = v;
        }
    }
    __syncthreads();

    f32x4 acc0 = {0.f, 0.f, 0.f, 0.f};
    f32x4 acc1 = {0.f, 0.f, 0.f, 0.f};
    const int r0 = wv * 16 + (lane & 15);
    const int kg8 = (lane >> 4) * 8;
#pragma unroll
    for (int kyi = 0; kyi < 3; ++kyi) {
#pragma unroll
        for (int kxi = 0; kxi < 3; ++kxi) {
            const int s9 = kyi * 3 + kxi;
            bf16x8 aF = __builtin_bit_cast(bf16x8,
                *(const uint4*)(xt + (size_t)(kyi * 66 + r0 + kxi) * 32 + kg8));
            bf16x8 bF0 = __builtin_bit_cast(bf16x8,
                *(const uint4*)(wfrag + (((size_t)s9 * 2 + 0) * 64 + lane) * 8));
            bf16x8 bF1 = __builtin_bit_cast(bf16x8,
                *(const uint4*)(wfrag + (((size_t)s9 * 2 + 1) * 64 + lane) * 8));
            acc0 = __builtin_amdgcn_mfma_f32_16x16x32_bf16(aF, bF0, acc0, 0, 0, 0);
            acc1 = __builtin_amdgcn_mfma_f32_16x16x32_bf16(aF, bF1, acc1, 0, 0, 0);
        }
    }

    const int oL = lane & 15;
    const float bs0 = bias[oL], bs1 = bias[16 + oL];
    u16* dp = dst + (size_t)(m0 + wv * 16 + ((lane >> 4) << 2)) * 32;
#pragma unroll
    for (int r = 0; r < 4; ++r) {
        dp[r * 32 + oL]      = f2bf(acc0[r] + bs0);
        dp[r * 32 + 16 + oL] = f2bf(acc1[r] + bs1);
    }
}

// ---------------- FUSED: offset conv + modulated deformable conv ----------------
__global__ __launch_bounds__(256, 4) void offdcn_k(
    const u16* __restrict__ t0,     // [NPIX][32] bf16 ch-last (feat)
    const u16* __restrict__ imgp,   // [4][8][Hp][Wp][4] bf16 zero-padded (col shift +2)
    const u16* __restrict__ wfragO, // [9][14][64][8]
    const u16* __restrict__ wfragD, // [9][2][64][8]
    const float* __restrict__ biasO,// 224
    const float* __restrict__ biasD,// 32
    float* __restrict__ out)        // [4][32][HW] f32
{
    const int tid = threadIdx.x, lane = tid & 63, wv = tid >> 6;
    const int bid = blockIdx.x;
    const int swz = (bid & 7) * (gridDim.x >> 3) + (bid >> 3);
    const int m0 = swz * 64;
    const int b = m0 / HWc, hwb = m0 - b * HWc;
    const int h0 = hwb / Wc, w0 = hwb - h0 * Wc;

    // union: xt[198][32] (12672 B) then co_s[224][66] (29568 B)
    __shared__ u16 pool[224 * 66];

    // ===== stage 0: halo -> xt =====
    {
        u16* xt = pool;
#pragma unroll
        for (int it = 0; it < 4; ++it) {
            int t = it * 256 + tid;
            if (t < 792) {
                int s = t >> 2, c = t & 3;
                int ry = s / 66, cx = s - ry * 66;
                int row = h0 + ry - 1, col = w0 + cx - 1;
                uint4 v = {0u, 0u, 0u, 0u};
                if (((unsigned)row < (unsigned)Hc) && ((unsigned)col < (unsigned)Wc))
                    v = *(const uint4*)(t0 + ((size_t)(b * HWc + row * Wc + col)) * 32 + c * 8);
                *(uint4*)(xt + (size_t)t * 8) = v;
            }
        }
    }
    __syncthreads();

    // ===== phase 1: offset conv (no per-tap barriers) =====
    const int wm = wv >> 1, wn = wv & 1;
    const int rm = wm * 32, cn = wn * 112;
    f32x4 acc[2][7];
#pragma unroll
    for (int mf = 0; mf < 2; ++mf)
#pragma unroll
        for (int nf = 0; nf < 7; ++nf)
            acc[mf][nf] = f32x4{0.f, 0.f, 0.f, 0.f};
    {
        const u16* xt = pool;
        const int r0 = rm + (lane & 15);
        const int kg8 = (lane >> 4) * 8;
#pragma unroll
        for (int kyi = 0; kyi < 3; ++kyi) {
#pragma unroll
            for (int kxi = 0; kxi < 3; ++kxi) {
                const int s9 = kyi * 3 + kxi;
                bf16x8 aF0 = __builtin_bit_cast(bf16x8,
                    *(const uint4*)(xt + (size_t)(kyi * 66 + r0 + kxi) * 32 + kg8));
                bf16x8 aF1 = __builtin_bit_cast(bf16x8,
                    *(const uint4*)(xt + (size_t)(kyi * 66 + r0 + 16 + kxi) * 32 + kg8));
#pragma unroll
                for (int nf = 0; nf < 7; ++nf) {
                    bf16x8 bF = __builtin_bit_cast(
                        bf16x8,
                        *(const uint4*)(wfragO + (((size_t)s9 * 14 + wn * 7 + nf) * 64 + lane) * 8));
                    acc[0][nf] = __builtin_amdgcn_mfma_f32_16x16x32_bf16(aF0, bF, acc[0][nf], 0, 0, 0);
                    acc[1][nf] = __builtin_amdgcn_mfma_f32_16x16x32_bf16(aF1, bF, acc[1][nf], 0, 0, 0);
                }
            }
        }
    }
    __syncthreads();   // all xt reads done before co_s overwrites the pool

    // ===== phase 1b: epilogue -> co_s =====
    u16* co_s = pool;
#pragma unroll
    for (int nf = 0; nf < 7; ++nf) {
        const int o = cn + nf * 16 + (lane & 15);
        const float bs = biasO[o];
        const bool sig = (o >= 144);
#pragma unroll
        for (int mf = 0; mf < 2; ++mf) {
            const int mb = rm + mf * 16 + ((lane >> 4) << 2);
            float v0 = acc[mf][nf][0] + bs, v1 = acc[mf][nf][1] + bs;
            float v2 = acc[mf][nf][2] + bs, v3 = acc[mf][nf][3] + bs;
            if (sig) {
                v0 = __builtin_amdgcn_rcpf(1.f + __builtin_amdgcn_exp2f(-v0 * 1.44269504f));
                v1 = __builtin_amdgcn_rcpf(1.f + __builtin_amdgcn_exp2f(-v1 * 1.44269504f));
                v2 = __builtin_amdgcn_rcpf(1.f + __builtin_amdgcn_exp2f(-v2 * 1.44269504f));
                v3 = __builtin_amdgcn_rcpf(1.f + __builtin_amdgcn_exp2f(-v3 * 1.44269504f));
            }
            *(u32*)&co_s[o * 66 + mb]     = cvtpk(v0, v1);
            *(u32*)&co_s[o * 66 + mb + 2] = cvtpk(v2, v3);
        }
    }
    __syncthreads();

    // ===== phase 2: DCN, 3-tap batches, x-paired uint4 gathers =====
    {
        const int kg = lane >> 4;                 // dg pair {2kg, 2kg+1}
        const int pixb = wv * 16 + (lane & 15);   // pixel within block
        const int hw = hwb + pixb;
        const int hh = hw / Wc;
        const int wwp = hw - hh * Wc;
        const float fh = (float)(hh - 1);
        const float fw = (float)(wwp - 1);

        const u16* gb = imgp + (size_t)b * 8 * PLANE * 4;
        const u32 dgp[2] = {(u32)((2 * kg + 0) * (PLANE * 4)),
                            (u32)((2 * kg + 1) * (PLANE * 4))};

        f32x4 acc0 = {0.f, 0.f, 0.f, 0.f};
        f32x4 acc1 = {0.f, 0.f, 0.f, 0.f};

#pragma unroll 1
        for (int kb = 0; kb < 9; kb += 3) {
            float w4[3][2][4];            // w1x, wx, w1y*m, wy*m
            uint4 cc[3][2][2];            // [t][dgi][row]: 2 x-corners x 4ch in one uint4

            // ---- stage A: co_s reads + addresses + issue ALL 12 paired gathers ----
#pragma unroll
            for (int t = 0; t < 3; ++t) {
                const int k = kb + t;
                const int kyi = k / 3, kxi = k - kyi * 3;
#pragma unroll
                for (int dgi = 0; dgi < 2; ++dgi) {
                    const int offch = (2 * kg + dgi) * 9 + k;
                    float dy = bf2f(co_s[offch * 66 + pixb]);
                    float dx = bf2f(co_s[(72 + offch) * 66 + pixb]);
                    float m  = bf2f(co_s[(144 + offch) * 66 + pixb]);

                    float py = dy + (fh + (float)kyi);
                    float px = dx + (fw + (float)kxi);
                    float y0f = floorf(py), x0f = floorf(px);
                    float wy = py - y0f, wx = px - x0f;
                    int y0 = (int)y0f, x0 = (int)x0f;

                    int yA = min(max(y0 + 1, 0), 193);
                    int yB = min(max(y0 + 2, 0), 193);
                    int xc = min(max(x0 + 2, 0), 254);  // uint4 covers cols xc, xc+1

                    float wym = wy * m;
                    w4[t][dgi][0] = 1.f - wx;
                    w4[t][dgi][1] = wx;
                    w4[t][dgi][2] = m - wym;            // (1-wy)*m
                    w4[t][dgi][3] = wym;

                    u32 rA = dgp[dgi] + ((u32)yA << 10);
                    u32 rB = dgp[dgi] + ((u32)yB << 10);
                    u32 xc4 = (u32)xc << 2;
                    cc[t][dgi][0] = *(const uint4*)(gb + (rA + xc4));
                    cc[t][dgi][1] = *(const uint4*)(gb + (rB + xc4));
                }
            }

            // ---- stage B: x-interp then y-interp (packed), cvt_pk, MFMA ----
#pragma unroll
            for (int t = 0; t < 3; ++t) {
                const int k = kb + t;
                u32 pk[4];
#pragma unroll
                for (int dgi = 0; dgi < 2; ++dgi) {
                    const float w1x = w4[t][dgi][0], wxs = w4[t][dgi][1];
                    const float w1ym = w4[t][dgi][2], wym = w4[t][dgi][3];
                    uint4 tp = cc[t][dgi][0], bt = cc[t][dgi][1];
                    f32x2 t01 = unpk(tp.x) * w1x + unpk(tp.z) * wxs;
                    f32x2 t23 = unpk(tp.y) * w1x + unpk(tp.w) * wxs;
                    f32x2 b01 = unpk(bt.x) * w1x + unpk(bt.z) * wxs;
                    f32x2 b23 = unpk(bt.y) * w1x + unpk(bt.w) * wxs;
                    f32x2 s01 = t01 * w1ym + b01 * wym;
                    f32x2 s23 = t23 * w1ym + b23 * wym;
                    pk[dgi * 2 + 0] = cvtpk(s01.x, s01.y);
                    pk[dgi * 2 + 1] = cvtpk(s23.x, s23.y);
                }

                bf16x8 aF = __builtin_bit_cast(bf16x8, uint4{pk[0], pk[1], pk[2], pk[3]});
                bf16x8 bF0 = __builtin_bit_cast(bf16x8,
                    *(const uint4*)(wfragD + ((size_t)(k * 2 + 0) * 64 + lane) * 8));
                bf16x8 bF1 = __builtin_bit_cast(bf16x8,
                    *(const uint4*)(wfragD + ((size_t)(k * 2 + 1) * 64 + lane) * 8));
                acc0 = __builtin_amdgcn_mfma_f32_16x16x32_bf16(aF, bF0, acc0, 0, 0, 0);
                acc1 = __builtin_amdgcn_mfma_f32_16x16x32_bf16(aF, bF1, acc1, 0, 0, 0);
            }
        }

        // epilogue: f32x4 stores (4 consecutive pixels per acc)
        const int hw0 = hwb + wv * 16 + ((lane >> 4) << 2);
        float* ob = out + (size_t)b * 32 * HWc;
        const int oL = lane & 15;
        const float bs0 = biasD[oL], bs1 = biasD[16 + oL];
        f32x4 o0 = {acc0[0] + bs0, acc0[1] + bs0, acc0[2] + bs0, acc0[3] + bs0};
        f32x4 o1 = {acc1[0] + bs1, acc1[1] + bs1, acc1[2] + bs1, acc1[3] + bs1};
        *(f32x4*)(ob + (size_t)oL * HWc + hw0) = o0;
        *(f32x4*)(ob + (size_t)(16 + oL) * HWc + hw0) = o1;
    }
}

extern "C" void kernel_launch(void* const* d_in, const int* in_sizes, int n_in,
                              void* d_out, int out_size, void* d_ws, size_t ws_size,
                              hipStream_t stream) {
    const float* img_ref  = (const float*)d_in[0];
    const float* img      = (const float*)d_in[1];
    const float* conv1_w  = (const float*)d_in[2];
    const float* conv1_b  = (const float*)d_in[3];
    const float* conv2a_w = (const float*)d_in[4];
    const float* conv2a_b = (const float*)d_in[5];
    const float* conv2b_w = (const float*)d_in[6];
    const float* conv2b_b = (const float*)d_in[7];
    const float* off_w    = (const float*)d_in[8];
    const float* off_b    = (const float*)d_in[9];
    const float* dcn_w    = (const float*)d_in[10];
    const float* dcn_b    = (const float*)d_in[11];

    float* wsf = (float*)d_ws;
    u16* frag = (u16*)((char*)d_ws + FRAG_BYTE);
    u16* t0   = (u16*)((char*)d_ws + T0_BYTE);
    u16* t1   = (u16*)((char*)d_ws + T1_BYTE);
    u16* imgp = (u16*)((char*)d_ws + IMG_BYTE);
    float* out = (float*)d_out;

    // zero the padded gather planes (margins must be 0; interior overwritten below)
    hipMemsetAsync(imgp, 0, IMG_SZ, stream);

    prep_k<<<370, 256, 0, stream>>>(conv1_w, conv1_b, conv2a_w, conv2a_b,
                                    conv2b_w, conv2b_b, off_w, off_b,
                                    dcn_w, dcn_b, wsf, frag);

    // conv1x1 -> t0 (ch-last) + padded dg-planar img dump
    conv1x1_mfma_k<<<NPIX / 128, 256, 0, stream>>>(
        img_ref, img, frag + FR1_U, wsf + WF_B1, t0, imgp);

    // conv2a: t0 -> t1 (halo single-barrier)
    conv3x3h_k<<<NPIX / 64, 256, 0, stream>>>(t0, frag + FRA_U, wsf + WF_B2A, t1);

    // conv2b: t1 -> t0
    conv3x3h_k<<<NPIX / 64, 256, 0, stream>>>(t1, frag + FRB_U, wsf + WF_B2B, t0);

    // fused offset conv + DCN
    offdcn_k<<<NPIX / 64, 256, 0, stream>>>(t0, imgp, frag + FRO_U, frag + FRD_U,
                                            wsf + WF_BO, wsf + WF_BD, out);
}